// Round 4
// baseline (394.366 us; speedup 1.0000x reference)
//
#include <hip/hip_runtime.h>

#define S_LEN 2048
#define D_DIM 2048
#define NHEAD 32
#define NKVH  8
#define HDIM  64
#define NBT   3200   // 2048 q + 512 k + 512 v + 16 fiber + 64 w1h + 48 pad

typedef __attribute__((ext_vector_type(4))) float f32x4;
typedef __attribute__((ext_vector_type(8))) short bf16x8;

__device__ __forceinline__ unsigned short f2bf(float x) {
    union { float f; unsigned u; } v; v.f = x;
    unsigned r = v.u + 0x7FFFu + ((v.u >> 16) & 1u);
    return (unsigned short)(r >> 16);
}

// async global->LDS 16B: dest = wave-uniform base + lane*16
#define GLD(gsrc, ldst) __builtin_amdgcn_global_load_lds( \
    (const __attribute__((address_space(1))) unsigned int*)(const void*)(gsrc), \
    (__attribute__((address_space(3))) unsigned int*)(void*)(ldst), 16, 0, 0)

#define SWZ(r) (((r) & 7) << 4)

// ---------------- h -> bf16 ----------------
__global__ void k_cvt_h(const float* __restrict__ h, unsigned short* __restrict__ hb) {
    int i = (blockIdx.x * 256 + threadIdx.x) * 4;
    float4 v = *(const float4*)(h + i);
    ushort4 o;
    o.x = f2bf(v.x); o.y = f2bf(v.y); o.z = f2bf(v.z); o.w = f2bf(v.w);
    *(ushort4*)(hb + i) = o;
}

// ------------- transpose W [2048][N] f32 -> WT [N][2048] bf16 -------------
__global__ void k_transpose(const float* __restrict__ W, unsigned short* __restrict__ WT, int N) {
    __shared__ unsigned short L[64][65];
    int k0 = blockIdx.x * 64, n0 = blockIdx.y * 64;
    int t = threadIdx.x;
    for (int it = 0; it < 16; ++it) {
        int e = it * 256 + t;
        int r = e >> 6, c = e & 63;
        L[c][r] = f2bf(W[(size_t)(k0 + r) * N + n0 + c]);
    }
    __syncthreads();
    for (int it = 0; it < 16; ++it) {
        int e = it * 256 + t;
        int n = e >> 6, kk = e & 63;
        WT[(size_t)(n0 + n) * 2048 + k0 + kk] = L[n][kk];
    }
}

// ------------- transpose Wf [2048][16] f32 -> WT [16][2048] bf16 -------------
__global__ void k_transpose16(const float* __restrict__ W, unsigned short* __restrict__ WT) {
    __shared__ unsigned short L[16][65];
    int k0 = blockIdx.x * 64;
    int t = threadIdx.x;
    for (int it = 0; it < 4; ++it) {
        int e = it * 256 + t;
        int r = e >> 4, c = e & 15;
        L[c][r] = f2bf(W[(size_t)(k0 + r) * 16 + c]);
    }
    __syncthreads();
    for (int it = 0; it < 4; ++it) {
        int e = it * 256 + t;
        int c = e >> 6, kk = e & 63;
        WT[(size_t)c * 2048 + k0 + kk] = L[c][kk];
    }
}

// ------------- transpose V slice of qkv -> vt [NKVH][64][S] bf16 -------------
__global__ void k_vtrans(const float* __restrict__ qkv, unsigned short* __restrict__ vt) {
    __shared__ unsigned short L[64][65];
    int s0 = blockIdx.x * 64, hk = blockIdx.y;
    int t = threadIdx.x;
    for (int it = 0; it < 16; ++it) {
        int e = it * 256 + t;
        int r = e >> 6, c = e & 63;
        L[c][r] = f2bf(qkv[(size_t)(s0 + r) * NBT + 2560 + hk * 64 + c]);
    }
    __syncthreads();
    for (int it = 0; it < 16; ++it) {
        int e = it * 256 + t;
        int c = e >> 6, kk = e & 63;
        vt[((size_t)hk * 64 + c) * S_LEN + s0 + kk] = L[c][kk];
    }
}

// ---- fuse: field[s] from fused GEMM cols (fiber 3072..3087, w1h 3088..3151) ----
__global__ __launch_bounds__(256) void k_fuse(const float* __restrict__ qkv,
                        const float* __restrict__ W1, const float* __restrict__ b1,
                        const float* __restrict__ W2, const float* __restrict__ b2,
                        float* __restrict__ field) {
    int wv = threadIdx.x >> 6, l = threadIdx.x & 63;
    int s = blockIdx.x * 4 + wv;
    const float* row = qkv + (size_t)s * NBT;
    float x = row[3088 + l] + b1[l];
#pragma unroll
    for (int f = 0; f < 16; ++f) x += row[3072 + f] * W1[(size_t)(2048 + f) * 64 + l];
    float hm = 0.5f * x * (1.f + erff(x * 0.70710678118654752f));
    float p = hm * W2[l];
    for (int m = 32; m; m >>= 1) p += __shfl_xor(p, m);
    if (l == 0) field[s] = 0.005f * (p + b2[0]);
}

// ---------------- gate = (field - mean)/(std_ddof1 + 1e-6) ----------------
__global__ void k_gate(const float* __restrict__ field, float* __restrict__ gate) {
    __shared__ float red[256];
    int t = threadIdx.x;
    float s = 0.f;
    for (int i = t; i < S_LEN; i += 256) s += field[i];
    red[t] = s; __syncthreads();
    for (int w = 128; w; w >>= 1) { if (t < w) red[t] += red[t + w]; __syncthreads(); }
    float mean = red[0] / (float)S_LEN;
    __syncthreads();
    float v = 0.f;
    for (int i = t; i < S_LEN; i += 256) { float d = field[i] - mean; v += d * d; }
    red[t] = v; __syncthreads();
    for (int w = 128; w; w >>= 1) { if (t < w) red[t] += red[t + w]; __syncthreads(); }
    float stdv = sqrtf(red[0] / (float)(S_LEN - 1)) + 1e-6f;
    for (int i = t; i < S_LEN; i += 256) gate[i] = (field[i] - mean) / stdv;
}

// ------- bf16 MFMA GEMM (m97 structure): C[M][N] = A[M][K] * BT[N][K]^T -------
__global__ __launch_bounds__(256) void k_gemm(const unsigned short* __restrict__ A,
                                              const unsigned short* __restrict__ BT,
                                              float* __restrict__ C, int M, int N, int K) {
    __shared__ __align__(16) char As[8192];
    __shared__ __align__(16) char Bs[8192];
    int m0 = blockIdx.y * 128, n0 = blockIdx.x * 128;
    int t = threadIdx.x;
    int wv = t >> 6, ln = t & 63;
    int wr = (wv >> 1) * 64, wc = (wv & 1) * 64;
    int lr = ln & 15, lkb = (ln >> 4) * 16;
    f32x4 acc[4][4] = {};
    const unsigned short* Ap = A + (size_t)(m0 + (t >> 2)) * K + (t & 3) * 8;
    const unsigned short* Bp = BT + (size_t)(n0 + (t >> 2)) * K + (t & 3) * 8;
    char* lA = As + wv * 1024;
    char* lB = Bs + wv * 1024;
    int nk = K / 32;
    GLD(Ap, lA); GLD(Ap + (size_t)64 * K, lA + 4096);
    GLD(Bp, lB); GLD(Bp + (size_t)64 * K, lB + 4096);
    for (int kt = 0; kt < nk; ++kt) {
        __syncthreads();
        bf16x8 af[4], bfv[4];
#pragma unroll
        for (int i = 0; i < 4; ++i) af[i]  = *(const bf16x8*)(As + (wr + i * 16 + lr) * 64 + lkb);
#pragma unroll
        for (int j = 0; j < 4; ++j) bfv[j] = *(const bf16x8*)(Bs + (wc + j * 16 + lr) * 64 + lkb);
#pragma unroll
        for (int i = 0; i < 4; ++i)
#pragma unroll
            for (int j = 0; j < 4; ++j)
                acc[i][j] = __builtin_amdgcn_mfma_f32_16x16x32_bf16(af[i], bfv[j], acc[i][j], 0, 0, 0);
        __syncthreads();
        if (kt + 1 < nk) {
            const unsigned short* Ak = Ap + (size_t)(kt + 1) * 32;
            const unsigned short* Bk = Bp + (size_t)(kt + 1) * 32;
            GLD(Ak, lA); GLD(Ak + (size_t)64 * K, lA + 4096);
            GLD(Bk, lB); GLD(Bk + (size_t)64 * K, lB + 4096);
        }
    }
    int orow = (ln >> 4) * 4;
#pragma unroll
    for (int i = 0; i < 4; ++i)
#pragma unroll
        for (int j = 0; j < 4; ++j) {
            float* Cp = C + (size_t)(m0 + wr + i * 16 + orow) * N + n0 + wc + j * 16 + lr;
            for (int r = 0; r < 4; ++r) Cp[(size_t)r * N] = acc[i][j][r];
        }
}

// ---------------- RoPE for q,k only (q prescaled by 1/8) ----------------
__global__ void k_rope(const float* __restrict__ qkv, const float* __restrict__ cs,
                       const float* __restrict__ sn,
                       unsigned short* __restrict__ qb, unsigned short* __restrict__ kb) {
    int s = blockIdx.x;
    const float* row = qkv + (size_t)s * NBT;
    int t = threadIdx.x;
    for (int e = t; e < 2560; e += 256) {
        int d = e & 63;
        float val = row[e];
        float c = cs[s * 64 + d], si = sn[s * 64 + d];
        float partner = (d < 32) ? -row[e + 32] : row[e - 32];
        float out = val * c + partner * si;
        if (e < 2048) {
            qb[((size_t)(e >> 6) * S_LEN + s) * 64 + d] = f2bf(out * 0.125f);
        } else {
            kb[((size_t)((e - 2048) >> 6) * S_LEN + s) * 64 + d] = f2bf(out);
        }
    }
}

// ---- flash attention: barrier-free, 4 indep waves x 16 q-rows, K/V from L2 ----
__global__ __launch_bounds__(256, 4) void k_attn(const unsigned short* __restrict__ qb,
                                                 const unsigned short* __restrict__ kb,
                                                 const unsigned short* __restrict__ vt,
                                                 const float* __restrict__ gate,
                                                 const float* __restrict__ gs_p,
                                                 unsigned short* __restrict__ attnout) {
    __shared__ __align__(16) char Pl[4][2048];   // per-wave [16 q x 128B], swizzled
    int qbi = 31 - blockIdx.x;                   // descending: big blocks first
    int h = blockIdx.y, hk = h >> 2;
    int t = threadIdx.x, wv = t >> 6, l = t & 63;
    int lr = l & 15, lg = l >> 4;
    float gs = gs_p[0];
    int q0 = qbi * 64 + wv * 16;
    const unsigned short* qbase = qb + ((size_t)h * S_LEN + q0) * 64;
    bf16x8 aq[2];
#pragma unroll
    for (int hf = 0; hf < 2; ++hf)
        aq[hf] = *(const bf16x8*)(qbase + lr * 64 + hf * 32 + lg * 8);
    f32x4 o[4] = {};
    float m_[4], ls_[4];
#pragma unroll
    for (int r = 0; r < 4; ++r) { m_[r] = -INFINITY; ls_[r] = 0.f; }
    const unsigned short* kg = kb + (size_t)hk * S_LEN * 64;
    const unsigned short* vg = vt + (size_t)hk * 64 * S_LEN;
    char* Pb = Pl[wv];
    int nkt = qbi + 1;
    for (int kt = 0; kt < nkt; ++kt) {
        int k0 = kt * 64;
        // ---- QK^T: K fragments straight from global (L2-resident) ----
        f32x4 sc[4] = {};
#pragma unroll
        for (int ct = 0; ct < 4; ++ct) {
            const unsigned short* krow = kg + (size_t)(k0 + ct * 16 + lr) * 64;
#pragma unroll
            for (int hf = 0; hf < 2; ++hf) {
                bf16x8 bk = *(const bf16x8*)(krow + hf * 32 + lg * 8);
                sc[ct] = __builtin_amdgcn_mfma_f32_16x16x32_bf16(aq[hf], bk, sc[ct], 0, 0, 0);
            }
        }
        float gb[4]; int kp[4];
#pragma unroll
        for (int ct = 0; ct < 4; ++ct) {
            kp[ct] = k0 + ct * 16 + lr;
            gb[ct] = gs * gate[kp[ct]];
        }
        // ---- online softmax ----
#pragma unroll
        for (int r = 0; r < 4; ++r) {
            int q = q0 + lg * 4 + r;
            float pv[4], vmax = -INFINITY;
#pragma unroll
            for (int ct = 0; ct < 4; ++ct) {
                float val = sc[ct][r] + gb[ct];
                if (kp[ct] > q) val -= 1e9f;
                pv[ct] = val;
                vmax = fmaxf(vmax, val);
            }
            vmax = fmaxf(vmax, __shfl_xor(vmax, 1));
            vmax = fmaxf(vmax, __shfl_xor(vmax, 2));
            vmax = fmaxf(vmax, __shfl_xor(vmax, 4));
            vmax = fmaxf(vmax, __shfl_xor(vmax, 8));
            float mn = fmaxf(m_[r], vmax);
            float scl = __expf(m_[r] - mn);
            float rs = 0.f;
#pragma unroll
            for (int ct = 0; ct < 4; ++ct) {
                float p = __expf(pv[ct] - mn);
                pv[ct] = p; rs += p;
            }
            rs += __shfl_xor(rs, 1); rs += __shfl_xor(rs, 2);
            rs += __shfl_xor(rs, 4); rs += __shfl_xor(rs, 8);
            ls_[r] = ls_[r] * scl + rs;
            m_[r] = mn;
#pragma unroll
            for (int dt = 0; dt < 4; ++dt) o[dt][r] *= scl;
            int qloc = lg * 4 + r;
#pragma unroll
            for (int ct = 0; ct < 4; ++ct)
                *(unsigned short*)(Pb + qloc * 128 + (((ct * 16 + lr) * 2) ^ SWZ(qloc))) = f2bf(pv[ct]);
        }
        // ---- PV: P from per-wave LDS (same-wave ordering), V from global ----
#pragma unroll
        for (int ks = 0; ks < 2; ++ks) {
            bf16x8 pa = *(const bf16x8*)(Pb + lr * 128 + ((ks * 64 + lg * 16) ^ SWZ(lr)));
#pragma unroll
            for (int dt = 0; dt < 4; ++dt) {
                const unsigned short* vrow = vg + (size_t)(dt * 16 + lr) * S_LEN + k0 + ks * 32;
                bf16x8 bv = *(const bf16x8*)(vrow + lg * 8);
                o[dt] = __builtin_amdgcn_mfma_f32_16x16x32_bf16(pa, bv, o[dt], 0, 0, 0);
            }
        }
    }
    // epilogue
#pragma unroll
    for (int r = 0; r < 4; ++r) {
        float inv = 1.f / ls_[r];
        unsigned short* orow = attnout + (size_t)(q0 + lg * 4 + r) * 2048 + h * 64;
#pragma unroll
        for (int dt = 0; dt < 4; ++dt) orow[dt * 16 + lr] = f2bf(o[dt][r] * inv);
    }
}

extern "C" void kernel_launch(void* const* d_in, const int* in_sizes, int n_in,
                              void* d_out, int out_size, void* d_ws, size_t ws_size,
                              hipStream_t stream) {
    const float* h    = (const float*)d_in[0];
    const float* cosT = (const float*)d_in[2];
    const float* sinT = (const float*)d_in[3];
    const float* Wf   = (const float*)d_in[4];
    const float* W1   = (const float*)d_in[5];
    const float* b1   = (const float*)d_in[6];
    const float* W2   = (const float*)d_in[7];
    const float* b2   = (const float*)d_in[8];
    const float* gs   = (const float*)d_in[9];
    const float* Wq   = (const float*)d_in[10];
    const float* Wk   = (const float*)d_in[11];
    const float* Wv   = (const float*)d_in[12];
    const float* Wo   = (const float*)d_in[13];
    float* out = (float*)d_out;

    char* ws = (char*)d_ws;
    unsigned short* hb    = (unsigned short*)(ws);                 // 0 .. 8 MiB            [dead after gemm1]
    unsigned short* bt    = (unsigned short*)(ws + 8388608);       // 8388608 .. 21495808   [dead after gemm1]
    float*          qkv   = (float*)(ws + 21495808);               // 21495808 .. 47710208  [dead after rope/vtrans/fuse]
    float*          field = (float*)(ws + 47710208);
    float*          gate  = (float*)(ws + 47718400);
    unsigned short* qbuf    = (unsigned short*)(ws + 8388608);     // over bt
    unsigned short* kbuf    = (unsigned short*)(ws + 16777216);
    unsigned short* vt      = (unsigned short*)(ws + 18874368);
    unsigned short* wot     = (unsigned short*)(ws + 21495808);    // over qkv head
    unsigned short* attnout = (unsigned short*)(ws);               // over hb

    k_cvt_h<<<dim3(4096), dim3(256), 0, stream>>>(h, hb);
    k_transpose<<<dim3(32, 32), dim3(256), 0, stream>>>(Wq, bt, 2048);
    k_transpose<<<dim3(32, 8),  dim3(256), 0, stream>>>(Wk, bt + (size_t)2048 * 2048, 512);
    k_transpose<<<dim3(32, 8),  dim3(256), 0, stream>>>(Wv, bt + (size_t)2560 * 2048, 512);
    k_transpose16<<<dim3(32), dim3(256), 0, stream>>>(Wf, bt + (size_t)3072 * 2048);
    k_transpose<<<dim3(32, 1),  dim3(256), 0, stream>>>(W1, bt + (size_t)3088 * 2048, 64);
    hipMemsetAsync(ws + 8388608 + (size_t)3152 * 4096, 0, (size_t)48 * 4096, stream);
    k_gemm<<<dim3(25, 16), dim3(256), 0, stream>>>(hb, bt, qkv, 2048, NBT, 2048);
    k_rope<<<dim3(2048), dim3(256), 0, stream>>>(qkv, cosT, sinT, qbuf, kbuf);
    k_vtrans<<<dim3(32, 8), dim3(256), 0, stream>>>(qkv, vt);
    k_fuse<<<dim3(512), dim3(256), 0, stream>>>(qkv, W1, b1, W2, b2, field);
    k_gate<<<dim3(1), dim3(256), 0, stream>>>(field, gate);
    k_transpose<<<dim3(32, 32), dim3(256), 0, stream>>>(Wo, wot, 2048);
    k_attn<<<dim3(32, 32), dim3(256), 0, stream>>>(qbuf, kbuf, vt, gate, gs, attnout);
    k_gemm<<<dim3(16, 16), dim3(256), 0, stream>>>(attnout, wot, out, 2048, 2048, 2048);
}

// Round 5
// 309.521 us; speedup vs baseline: 1.2741x; 1.2741x over previous
//
#include <hip/hip_runtime.h>

#define S_LEN 2048
#define D_DIM 2048
#define NHEAD 32
#define NKVH  8
#define HDIM  64
#define NBT   3200   // 2048 q + 512 k + 512 v + 16 fiber + 64 w1h + 48 pad

typedef __attribute__((ext_vector_type(4))) float f32x4;
typedef __attribute__((ext_vector_type(8))) short bf16x8;

__device__ __forceinline__ unsigned short f2bf(float x) {
    union { float f; unsigned u; } v; v.f = x;
    unsigned r = v.u + 0x7FFFu + ((v.u >> 16) & 1u);
    return (unsigned short)(r >> 16);
}

// async global->LDS 16B: dest = wave-uniform base + lane*16
#define GLD(gsrc, ldst) __builtin_amdgcn_global_load_lds( \
    (const __attribute__((address_space(1))) unsigned int*)(const void*)(gsrc), \
    (__attribute__((address_space(3))) unsigned int*)(void*)(ldst), 16, 0, 0)

#define SWZ(r) (((r) & 7) << 4)

// ---------------- h -> bf16 ----------------
__global__ void k_cvt_h(const float* __restrict__ h, unsigned short* __restrict__ hb) {
    int i = (blockIdx.x * 256 + threadIdx.x) * 4;
    float4 v = *(const float4*)(h + i);
    ushort4 o;
    o.x = f2bf(v.x); o.y = f2bf(v.y); o.z = f2bf(v.z); o.w = f2bf(v.w);
    *(ushort4*)(hb + i) = o;
}

// ------------- transpose W [2048][N] f32 -> WT [N][2048] bf16 -------------
__global__ void k_transpose(const float* __restrict__ W, unsigned short* __restrict__ WT, int N) {
    __shared__ unsigned short L[64][65];
    int k0 = blockIdx.x * 64, n0 = blockIdx.y * 64;
    int t = threadIdx.x;
    for (int it = 0; it < 16; ++it) {
        int e = it * 256 + t;
        int r = e >> 6, c = e & 63;
        L[c][r] = f2bf(W[(size_t)(k0 + r) * N + n0 + c]);
    }
    __syncthreads();
    for (int it = 0; it < 16; ++it) {
        int e = it * 256 + t;
        int n = e >> 6, kk = e & 63;
        WT[(size_t)(n0 + n) * 2048 + k0 + kk] = L[n][kk];
    }
}

// ------------- transpose Wf [2048][16] f32 -> WT [16][2048] bf16 -------------
__global__ void k_transpose16(const float* __restrict__ W, unsigned short* __restrict__ WT) {
    __shared__ unsigned short L[16][65];
    int k0 = blockIdx.x * 64;
    int t = threadIdx.x;
    for (int it = 0; it < 4; ++it) {
        int e = it * 256 + t;
        int r = e >> 4, c = e & 15;
        L[c][r] = f2bf(W[(size_t)(k0 + r) * 16 + c]);
    }
    __syncthreads();
    for (int it = 0; it < 4; ++it) {
        int e = it * 256 + t;
        int c = e >> 6, kk = e & 63;
        WT[(size_t)c * 2048 + k0 + kk] = L[c][kk];
    }
}

// ---- transpose V slice of qkv -> vt [NKVH][64][S] bf16, k-permuted within 64 ----
// pi(kk) = 2*(kk&15) + ((kk>>4)&1) + 32*(kk>>5): pairs P-columns for cvt_pk packing
__global__ void k_vtrans(const float* __restrict__ qkv, unsigned short* __restrict__ vt) {
    __shared__ unsigned short L[64][65];
    int s0 = blockIdx.x * 64, hk = blockIdx.y;
    int t = threadIdx.x;
    for (int it = 0; it < 16; ++it) {
        int e = it * 256 + t;
        int r = e >> 6, c = e & 63;
        L[c][r] = f2bf(qkv[(size_t)(s0 + r) * NBT + 2560 + hk * 64 + c]);
    }
    __syncthreads();
    for (int it = 0; it < 16; ++it) {
        int e = it * 256 + t;
        int c = e >> 6, kk = e & 63;
        int pos = ((kk & 15) << 1) | ((kk >> 4) & 1) | ((kk >> 5) << 5);
        vt[((size_t)hk * 64 + c) * S_LEN + s0 + pos] = L[c][kk];
    }
}

// ---- fuse: field[s] from fused GEMM cols (fiber 3072..3087, w1h 3088..3151) ----
__global__ __launch_bounds__(256) void k_fuse(const float* __restrict__ qkv,
                        const float* __restrict__ W1, const float* __restrict__ b1,
                        const float* __restrict__ W2, const float* __restrict__ b2,
                        float* __restrict__ field) {
    int wv = threadIdx.x >> 6, l = threadIdx.x & 63;
    int s = blockIdx.x * 4 + wv;
    const float* row = qkv + (size_t)s * NBT;
    float x = row[3088 + l] + b1[l];
#pragma unroll
    for (int f = 0; f < 16; ++f) x += row[3072 + f] * W1[(size_t)(2048 + f) * 64 + l];
    float hm = 0.5f * x * (1.f + erff(x * 0.70710678118654752f));
    float p = hm * W2[l];
    for (int m = 32; m; m >>= 1) p += __shfl_xor(p, m);
    if (l == 0) field[s] = 0.005f * (p + b2[0]);
}

// ---------------- gate = (field - mean)/(std_ddof1 + 1e-6) ----------------
__global__ void k_gate(const float* __restrict__ field, float* __restrict__ gate) {
    __shared__ float red[256];
    int t = threadIdx.x;
    float s = 0.f;
    for (int i = t; i < S_LEN; i += 256) s += field[i];
    red[t] = s; __syncthreads();
    for (int w = 128; w; w >>= 1) { if (t < w) red[t] += red[t + w]; __syncthreads(); }
    float mean = red[0] / (float)S_LEN;
    __syncthreads();
    float v = 0.f;
    for (int i = t; i < S_LEN; i += 256) { float d = field[i] - mean; v += d * d; }
    red[t] = v; __syncthreads();
    for (int w = 128; w; w >>= 1) { if (t < w) red[t] += red[t + w]; __syncthreads(); }
    float stdv = sqrtf(red[0] / (float)(S_LEN - 1)) + 1e-6f;
    for (int i = t; i < S_LEN; i += 256) gate[i] = (field[i] - mean) / stdv;
}

// ------- bf16 MFMA GEMM (m97 structure): C[M][N] = A[M][K] * BT[N][K]^T -------
__global__ __launch_bounds__(256) void k_gemm(const unsigned short* __restrict__ A,
                                              const unsigned short* __restrict__ BT,
                                              float* __restrict__ C, int M, int N, int K) {
    __shared__ __align__(16) char As[8192];
    __shared__ __align__(16) char Bs[8192];
    int m0 = blockIdx.y * 128, n0 = blockIdx.x * 128;
    int t = threadIdx.x;
    int wv = t >> 6, ln = t & 63;
    int wr = (wv >> 1) * 64, wc = (wv & 1) * 64;
    int lr = ln & 15, lkb = (ln >> 4) * 16;
    f32x4 acc[4][4] = {};
    const unsigned short* Ap = A + (size_t)(m0 + (t >> 2)) * K + (t & 3) * 8;
    const unsigned short* Bp = BT + (size_t)(n0 + (t >> 2)) * K + (t & 3) * 8;
    char* lA = As + wv * 1024;
    char* lB = Bs + wv * 1024;
    int nk = K / 32;
    GLD(Ap, lA); GLD(Ap + (size_t)64 * K, lA + 4096);
    GLD(Bp, lB); GLD(Bp + (size_t)64 * K, lB + 4096);
    for (int kt = 0; kt < nk; ++kt) {
        __syncthreads();
        bf16x8 af[4], bfv[4];
#pragma unroll
        for (int i = 0; i < 4; ++i) af[i]  = *(const bf16x8*)(As + (wr + i * 16 + lr) * 64 + lkb);
#pragma unroll
        for (int j = 0; j < 4; ++j) bfv[j] = *(const bf16x8*)(Bs + (wc + j * 16 + lr) * 64 + lkb);
#pragma unroll
        for (int i = 0; i < 4; ++i)
#pragma unroll
            for (int j = 0; j < 4; ++j)
                acc[i][j] = __builtin_amdgcn_mfma_f32_16x16x32_bf16(af[i], bfv[j], acc[i][j], 0, 0, 0);
        __syncthreads();
        if (kt + 1 < nk) {
            const unsigned short* Ak = Ap + (size_t)(kt + 1) * 32;
            const unsigned short* Bk = Bp + (size_t)(kt + 1) * 32;
            GLD(Ak, lA); GLD(Ak + (size_t)64 * K, lA + 4096);
            GLD(Bk, lB); GLD(Bk + (size_t)64 * K, lB + 4096);
        }
    }
    int orow = (ln >> 4) * 4;
#pragma unroll
    for (int i = 0; i < 4; ++i)
#pragma unroll
        for (int j = 0; j < 4; ++j) {
            float* Cp = C + (size_t)(m0 + wr + i * 16 + orow) * N + n0 + wc + j * 16 + lr;
            for (int r = 0; r < 4; ++r) Cp[(size_t)r * N] = acc[i][j][r];
        }
}

// ---------------- RoPE for q,k only (q prescaled by 1/8) ----------------
__global__ void k_rope(const float* __restrict__ qkv, const float* __restrict__ cs,
                       const float* __restrict__ sn,
                       unsigned short* __restrict__ qb, unsigned short* __restrict__ kb) {
    int s = blockIdx.x;
    const float* row = qkv + (size_t)s * NBT;
    int t = threadIdx.x;
    for (int e = t; e < 2560; e += 256) {
        int d = e & 63;
        float val = row[e];
        float c = cs[s * 64 + d], si = sn[s * 64 + d];
        float partner = (d < 32) ? -row[e + 32] : row[e - 32];
        float out = val * c + partner * si;
        if (e < 2048) {
            qb[((size_t)(e >> 6) * S_LEN + s) * 64 + d] = f2bf(out * 0.125f);
        } else {
            kb[((size_t)((e - 2048) >> 6) * S_LEN + s) * 64 + d] = f2bf(out);
        }
    }
}

// --- flash attention: 8 waves = 4 q-heads x {hi,lo} complementary q-tiles ---
// block j: q-tiles (63-j) and j (32 rows each), kv-head blockIdx.y.
// K/V staged dbuf LDS (shared by all 8 waves); balanced: every block ~33 wave-kt.
__global__ __launch_bounds__(512, 4) void k_attn(const unsigned short* __restrict__ qb,
                                                 const unsigned short* __restrict__ kb,
                                                 const unsigned short* __restrict__ vt,
                                                 const float* __restrict__ gate,
                                                 const float* __restrict__ gs_p,
                                                 unsigned short* __restrict__ attnout) {
    __shared__ __align__(16) char Kl[2][8192];   // [buf][64 k rows x 128B], read-swizzled
    __shared__ __align__(16) char Vl[2][8192];   // [buf][64 d rows x 128B]
    __shared__ __align__(16) char Pl[8][4096];   // per-wave [32 q x 128B]
    int j = blockIdx.x;
    int hk = blockIdx.y;
    int t = threadIdx.x, wv = t >> 6, l = t & 63;
    int lr = l & 15, lg = l >> 4;
    int h = hk * 4 + (wv & 3);
    int qt = (wv >> 2) ? j : (63 - j);
    int q0 = qt * 32;
    float gs = gs_p[0];
    // Q fragments (32 rows/wave)
    const unsigned short* qbase = qb + ((size_t)h * S_LEN + q0) * 64;
    bf16x8 aq[2][2];
#pragma unroll
    for (int rt = 0; rt < 2; ++rt)
#pragma unroll
        for (int hf = 0; hf < 2; ++hf)
            aq[rt][hf] = *(const bf16x8*)(qbase + (rt * 16 + lr) * 64 + hf * 32 + lg * 8);
    f32x4 o[2][4] = {};
    float m_[2][4], ls_[2][4];
#pragma unroll
    for (int rt = 0; rt < 2; ++rt)
        for (int r = 0; r < 4; ++r) { m_[rt][r] = -INFINITY; ls_[rt][r] = 0.f; }
    int myKt = (q0 + 31) >> 6;                  // last kt for this wave (mask there)
    int nkt = ((2047 - 32 * j) >> 6) + 1;       // = hi-tile myKt + 1
    // staging: 512 threads stage 64 rows x 128B per buffer (1 GLD each of K,V)
    int srow = t >> 3;                          // 0..63
    int scol = 8 * ((t & 7) ^ (srow & 7));      // pre-swizzled source column (elems)
    const unsigned short* kg = kb + (size_t)hk * S_LEN * 64;
    const unsigned short* vg = vt + (size_t)hk * 64 * S_LEN;
    char* Pb = Pl[wv];
    {   // stage kt=0
        GLD(kg + (size_t)srow * 64 + scol, Kl[0] + wv * 1024);
        GLD(vg + (size_t)srow * S_LEN + scol, Vl[0] + wv * 1024);
    }
    for (int kt = 0; kt < nkt; ++kt) {
        __syncthreads();   // buf[kt&1] staged; prior reads of buf[(kt+1)&1] done
        if (kt + 1 < nkt) {
            int k0n = (kt + 1) * 64;
            char* dK = Kl[(kt + 1) & 1] + wv * 1024;
            char* dV = Vl[(kt + 1) & 1] + wv * 1024;
            GLD(kg + (size_t)(k0n + srow) * 64 + scol, dK);
            GLD(vg + (size_t)srow * S_LEN + k0n + scol, dV);
        }
        if (kt <= myKt) {
            int k0 = kt * 64;
            bool domask = (kt == myKt);
            const char* Kb = Kl[kt & 1];
            const char* Vb = Vl[kt & 1];
            // ---- QK^T ----
            f32x4 sc[2][4] = {};
#pragma unroll
            for (int ct = 0; ct < 4; ++ct) {
                int krow = ct * 16 + lr;
#pragma unroll
                for (int hf = 0; hf < 2; ++hf) {
                    bf16x8 bk = *(const bf16x8*)(Kb + krow * 128 + ((hf * 64 + lg * 16) ^ SWZ(krow)));
#pragma unroll
                    for (int rt = 0; rt < 2; ++rt)
                        sc[rt][ct] = __builtin_amdgcn_mfma_f32_16x16x32_bf16(aq[rt][hf], bk, sc[rt][ct], 0, 0, 0);
                }
            }
            // ---- online softmax + packed P write ----
#pragma unroll
            for (int rt = 0; rt < 2; ++rt) {
#pragma unroll
                for (int r = 0; r < 4; ++r) {
                    int q = q0 + rt * 16 + lg * 4 + r;
                    float pv[4], vmax = -INFINITY;
#pragma unroll
                    for (int ct = 0; ct < 4; ++ct) {
                        float val = sc[rt][ct][r] + gs * gate[k0 + ct * 16 + lr];
                        if (domask && (k0 + ct * 16 + lr > q)) val -= 1e9f;
                        pv[ct] = val;
                        vmax = fmaxf(vmax, val);
                    }
                    vmax = fmaxf(vmax, __shfl_xor(vmax, 1));
                    vmax = fmaxf(vmax, __shfl_xor(vmax, 2));
                    vmax = fmaxf(vmax, __shfl_xor(vmax, 4));
                    vmax = fmaxf(vmax, __shfl_xor(vmax, 8));
                    float mn = m_[rt][r];
                    if (!__all(vmax <= mn + 8.f)) {   // defer-max (T13)
                        mn = fmaxf(mn, vmax);
                        float scl = __expf(m_[rt][r] - mn);
                        ls_[rt][r] *= scl;
#pragma unroll
                        for (int dt = 0; dt < 4; ++dt) o[rt][dt][r] *= scl;
                        m_[rt][r] = mn;
                    }
                    float rs = 0.f;
#pragma unroll
                    for (int ct = 0; ct < 4; ++ct) {
                        float p = __expf(pv[ct] - mn);
                        pv[ct] = p; rs += p;
                    }
                    rs += __shfl_xor(rs, 1); rs += __shfl_xor(rs, 2);
                    rs += __shfl_xor(rs, 4); rs += __shfl_xor(rs, 8);
                    ls_[rt][r] += rs;
                    // packed bf16 pairs: P positions 2lr,2lr+1 (ct0,1) and 32+2lr,+1 (ct2,3)
                    unsigned pk01, pk23;
                    asm("v_cvt_pk_bf16_f32 %0, %1, %2" : "=v"(pk01) : "v"(pv[0]), "v"(pv[1]));
                    asm("v_cvt_pk_bf16_f32 %0, %1, %2" : "=v"(pk23) : "v"(pv[2]), "v"(pv[3]));
                    int qloc = rt * 16 + lg * 4 + r;
                    *(unsigned*)(Pb + qloc * 128 + ((4 * lr) ^ SWZ(qloc))) = pk01;
                    *(unsigned*)(Pb + qloc * 128 + ((64 + 4 * lr) ^ SWZ(qloc))) = pk23;
                }
            }
            // ---- PV: P (pi-ordered) x V^T (pi-ordered cols) ----
#pragma unroll
            for (int ks = 0; ks < 2; ++ks) {
                bf16x8 pa[2];
#pragma unroll
                for (int rt = 0; rt < 2; ++rt) {
                    int qrow = rt * 16 + lr;
                    pa[rt] = *(const bf16x8*)(Pb + qrow * 128 + ((ks * 64 + lg * 16) ^ SWZ(qrow)));
                }
#pragma unroll
                for (int dt = 0; dt < 4; ++dt) {
                    int vrow = dt * 16 + lr;
                    bf16x8 bv = *(const bf16x8*)(Vb + vrow * 128 + ((ks * 64 + lg * 16) ^ SWZ(vrow)));
#pragma unroll
                    for (int rt = 0; rt < 2; ++rt)
                        o[rt][dt] = __builtin_amdgcn_mfma_f32_16x16x32_bf16(pa[rt], bv, o[rt][dt], 0, 0, 0);
                }
            }
        }
    }
    // epilogue
#pragma unroll
    for (int rt = 0; rt < 2; ++rt)
#pragma unroll
        for (int r = 0; r < 4; ++r) {
            float inv = 1.f / ls_[rt][r];
            unsigned short* orow = attnout + (size_t)(q0 + rt * 16 + lg * 4 + r) * 2048 + h * 64;
#pragma unroll
            for (int dt = 0; dt < 4; ++dt) orow[dt * 16 + lr] = f2bf(o[rt][dt][r] * inv);
        }
}

extern "C" void kernel_launch(void* const* d_in, const int* in_sizes, int n_in,
                              void* d_out, int out_size, void* d_ws, size_t ws_size,
                              hipStream_t stream) {
    const float* h    = (const float*)d_in[0];
    const float* cosT = (const float*)d_in[2];
    const float* sinT = (const float*)d_in[3];
    const float* Wf   = (const float*)d_in[4];
    const float* W1   = (const float*)d_in[5];
    const float* b1   = (const float*)d_in[6];
    const float* W2   = (const float*)d_in[7];
    const float* b2   = (const float*)d_in[8];
    const float* gs   = (const float*)d_in[9];
    const float* Wq   = (const float*)d_in[10];
    const float* Wk   = (const float*)d_in[11];
    const float* Wv   = (const float*)d_in[12];
    const float* Wo   = (const float*)d_in[13];
    float* out = (float*)d_out;

    char* ws = (char*)d_ws;
    unsigned short* hb    = (unsigned short*)(ws);                 // 0 .. 8 MiB            [dead after gemm1]
    unsigned short* bt    = (unsigned short*)(ws + 8388608);       // 8388608 .. 21495808   [dead after gemm1]
    float*          qkv   = (float*)(ws + 21495808);               // 21495808 .. 47710208  [dead after rope/vtrans/fuse]
    float*          field = (float*)(ws + 47710208);
    float*          gate  = (float*)(ws + 47718400);
    unsigned short* qbuf    = (unsigned short*)(ws + 8388608);     // over bt
    unsigned short* kbuf    = (unsigned short*)(ws + 16777216);
    unsigned short* vt      = (unsigned short*)(ws + 18874368);
    unsigned short* wot     = (unsigned short*)(ws + 21495808);    // over qkv head
    unsigned short* attnout = (unsigned short*)(ws);               // over hb

    k_cvt_h<<<dim3(4096), dim3(256), 0, stream>>>(h, hb);
    k_transpose<<<dim3(32, 32), dim3(256), 0, stream>>>(Wq, bt, 2048);
    k_transpose<<<dim3(32, 8),  dim3(256), 0, stream>>>(Wk, bt + (size_t)2048 * 2048, 512);
    k_transpose<<<dim3(32, 8),  dim3(256), 0, stream>>>(Wv, bt + (size_t)2560 * 2048, 512);
    k_transpose16<<<dim3(32), dim3(256), 0, stream>>>(Wf, bt + (size_t)3072 * 2048);
    k_transpose<<<dim3(32, 1),  dim3(256), 0, stream>>>(W1, bt + (size_t)3088 * 2048, 64);
    hipMemsetAsync(ws + 8388608 + (size_t)3152 * 4096, 0, (size_t)48 * 4096, stream);
    k_gemm<<<dim3(25, 16), dim3(256), 0, stream>>>(hb, bt, qkv, 2048, NBT, 2048);
    k_rope<<<dim3(2048), dim3(256), 0, stream>>>(qkv, cosT, sinT, qbuf, kbuf);
    k_vtrans<<<dim3(32, 8), dim3(256), 0, stream>>>(qkv, vt);
    k_fuse<<<dim3(512), dim3(256), 0, stream>>>(qkv, W1, b1, W2, b2, field);
    k_gate<<<dim3(1), dim3(256), 0, stream>>>(field, gate);
    k_transpose<<<dim3(32, 32), dim3(256), 0, stream>>>(Wo, wot, 2048);
    k_attn<<<dim3(32, 8), dim3(512), 0, stream>>>(qbuf, kbuf, vt, gate, gs, attnout);
    k_gemm<<<dim3(16, 16), dim3(256), 0, stream>>>(attnout, wot, out, 2048, 2048, 2048);
}

// Round 7
// 265.764 us; speedup vs baseline: 1.4839x; 1.1646x over previous
//
#include <hip/hip_runtime.h>

#define S_LEN 2048
#define D_DIM 2048
#define NHEAD 32
#define NKVH  8
#define HDIM  64
#define NBT   3200   // 2048 q + 512 k + 512 v + 16 fiber + 64 w1h + 48 pad

typedef __attribute__((ext_vector_type(4))) float f32x4;
typedef __attribute__((ext_vector_type(8))) short bf16x8;

__device__ __forceinline__ unsigned short f2bf(float x) {
    union { float f; unsigned u; } v; v.f = x;
    unsigned r = v.u + 0x7FFFu + ((v.u >> 16) & 1u);
    return (unsigned short)(r >> 16);
}

// async global->LDS 16B: dest = wave-uniform base + lane*16
#define GLD(gsrc, ldst) __builtin_amdgcn_global_load_lds( \
    (const __attribute__((address_space(1))) unsigned int*)(const void*)(gsrc), \
    (__attribute__((address_space(3))) unsigned int*)(void*)(ldst), 16, 0, 0)

#define SWZ(r) (((r) & 7) << 4)

// ---------------- h -> bf16 ----------------
__global__ void k_cvt_h(const float* __restrict__ h, unsigned short* __restrict__ hb) {
    int i = (blockIdx.x * 256 + threadIdx.x) * 4;
    float4 v = *(const float4*)(h + i);
    ushort4 o;
    o.x = f2bf(v.x); o.y = f2bf(v.y); o.z = f2bf(v.z); o.w = f2bf(v.w);
    *(ushort4*)(hb + i) = o;
}

// ------------- transpose W [2048][N] f32 -> WT [N][2048] bf16 -------------
__global__ void k_transpose(const float* __restrict__ W, unsigned short* __restrict__ WT, int N) {
    __shared__ unsigned short L[64][65];
    int k0 = blockIdx.x * 64, n0 = blockIdx.y * 64;
    int t = threadIdx.x;
    for (int it = 0; it < 16; ++it) {
        int e = it * 256 + t;
        int r = e >> 6, c = e & 63;
        L[c][r] = f2bf(W[(size_t)(k0 + r) * N + n0 + c]);
    }
    __syncthreads();
    for (int it = 0; it < 16; ++it) {
        int e = it * 256 + t;
        int n = e >> 6, kk = e & 63;
        WT[(size_t)(n0 + n) * 2048 + k0 + kk] = L[n][kk];
    }
}

// ------------- transpose Wf [2048][16] f32 -> WT [16][2048] bf16 -------------
__global__ void k_transpose16(const float* __restrict__ W, unsigned short* __restrict__ WT) {
    __shared__ unsigned short L[16][65];
    int k0 = blockIdx.x * 64;
    int t = threadIdx.x;
    for (int it = 0; it < 4; ++it) {
        int e = it * 256 + t;
        int r = e >> 4, c = e & 15;
        L[c][r] = f2bf(W[(size_t)(k0 + r) * 16 + c]);
    }
    __syncthreads();
    for (int it = 0; it < 4; ++it) {
        int e = it * 256 + t;
        int c = e >> 6, kk = e & 63;
        WT[(size_t)c * 2048 + k0 + kk] = L[c][kk];
    }
}

// ---- transpose V slice of qkv -> vt [NKVH][64][S] bf16, k-pair-permuted ----
// pos(kk) = 2*(kk&15) | ((kk>>4)&1) | 32*(kk>>5) : pairs P-columns for cvt_pk packing
// (verified R5: P elem-space == V elem-space, hardware k-slot order cancels)
__global__ void k_vtrans(const float* __restrict__ qkv, unsigned short* __restrict__ vt) {
    __shared__ unsigned short L[64][65];
    int s0 = blockIdx.x * 64, hk = blockIdx.y;
    int t = threadIdx.x;
    for (int it = 0; it < 16; ++it) {
        int e = it * 256 + t;
        int r = e >> 6, c = e & 63;
        L[c][r] = f2bf(qkv[(size_t)(s0 + r) * NBT + 2560 + hk * 64 + c]);
    }
    __syncthreads();
    for (int it = 0; it < 16; ++it) {
        int e = it * 256 + t;
        int c = e >> 6, kk = e & 63;
        int pos = ((kk & 15) << 1) | ((kk >> 4) & 1) | ((kk >> 5) << 5);
        vt[((size_t)hk * 64 + c) * S_LEN + s0 + pos] = L[c][kk];
    }
}

// ---- fuse: field[s] from fused GEMM cols (fiber 3072..3087, w1h 3088..3151) ----
__global__ __launch_bounds__(256) void k_fuse(const float* __restrict__ qkv,
                        const float* __restrict__ W1, const float* __restrict__ b1,
                        const float* __restrict__ W2, const float* __restrict__ b2,
                        float* __restrict__ field) {
    int wv = threadIdx.x >> 6, l = threadIdx.x & 63;
    int s = blockIdx.x * 4 + wv;
    const float* row = qkv + (size_t)s * NBT;
    float x = row[3088 + l] + b1[l];
#pragma unroll
    for (int f = 0; f < 16; ++f) x += row[3072 + f] * W1[(size_t)(2048 + f) * 64 + l];
    float hm = 0.5f * x * (1.f + erff(x * 0.70710678118654752f));
    float p = hm * W2[l];
    for (int m = 32; m; m >>= 1) p += __shfl_xor(p, m);
    if (l == 0) field[s] = 0.005f * (p + b2[0]);
}

// ---------------- gate = (field - mean)/(std_ddof1 + 1e-6) ----------------
__global__ void k_gate(const float* __restrict__ field, float* __restrict__ gate) {
    __shared__ float red[256];
    int t = threadIdx.x;
    float s = 0.f;
    for (int i = t; i < S_LEN; i += 256) s += field[i];
    red[t] = s; __syncthreads();
    for (int w = 128; w; w >>= 1) { if (t < w) red[t] += red[t + w]; __syncthreads(); }
    float mean = red[0] / (float)S_LEN;
    __syncthreads();
    float v = 0.f;
    for (int i = t; i < S_LEN; i += 256) { float d = field[i] - mean; v += d * d; }
    red[t] = v; __syncthreads();
    for (int w = 128; w; w >>= 1) { if (t < w) red[t] += red[t + w]; __syncthreads(); }
    float stdv = sqrtf(red[0] / (float)(S_LEN - 1)) + 1e-6f;
    for (int i = t; i < S_LEN; i += 256) gate[i] = (field[i] - mean) / stdv;
}

// ------- bf16 MFMA GEMM (m97 structure): C[M][N] = A[M][K] * BT[N][K]^T -------
__global__ __launch_bounds__(256) void k_gemm(const unsigned short* __restrict__ A,
                                              const unsigned short* __restrict__ BT,
                                              float* __restrict__ C, int M, int N, int K) {
    __shared__ __align__(16) char As[8192];
    __shared__ __align__(16) char Bs[8192];
    int m0 = blockIdx.y * 128, n0 = blockIdx.x * 128;
    int t = threadIdx.x;
    int wv = t >> 6, ln = t & 63;
    int wr = (wv >> 1) * 64, wc = (wv & 1) * 64;
    int lr = ln & 15, lkb = (ln >> 4) * 16;
    f32x4 acc[4][4] = {};
    const unsigned short* Ap = A + (size_t)(m0 + (t >> 2)) * K + (t & 3) * 8;
    const unsigned short* Bp = BT + (size_t)(n0 + (t >> 2)) * K + (t & 3) * 8;
    char* lA = As + wv * 1024;
    char* lB = Bs + wv * 1024;
    int nk = K / 32;
    GLD(Ap, lA); GLD(Ap + (size_t)64 * K, lA + 4096);
    GLD(Bp, lB); GLD(Bp + (size_t)64 * K, lB + 4096);
    for (int kt = 0; kt < nk; ++kt) {
        __syncthreads();
        bf16x8 af[4], bfv[4];
#pragma unroll
        for (int i = 0; i < 4; ++i) af[i]  = *(const bf16x8*)(As + (wr + i * 16 + lr) * 64 + lkb);
#pragma unroll
        for (int j = 0; j < 4; ++j) bfv[j] = *(const bf16x8*)(Bs + (wc + j * 16 + lr) * 64 + lkb);
#pragma unroll
        for (int i = 0; i < 4; ++i)
#pragma unroll
            for (int j = 0; j < 4; ++j)
                acc[i][j] = __builtin_amdgcn_mfma_f32_16x16x32_bf16(af[i], bfv[j], acc[i][j], 0, 0, 0);
        __syncthreads();
        if (kt + 1 < nk) {
            const unsigned short* Ak = Ap + (size_t)(kt + 1) * 32;
            const unsigned short* Bk = Bp + (size_t)(kt + 1) * 32;
            GLD(Ak, lA); GLD(Ak + (size_t)64 * K, lA + 4096);
            GLD(Bk, lB); GLD(Bk + (size_t)64 * K, lB + 4096);
        }
    }
    int orow = (ln >> 4) * 4;
#pragma unroll
    for (int i = 0; i < 4; ++i)
#pragma unroll
        for (int j = 0; j < 4; ++j) {
            float* Cp = C + (size_t)(m0 + wr + i * 16 + orow) * N + n0 + wc + j * 16 + lr;
            for (int r = 0; r < 4; ++r) Cp[(size_t)r * N] = acc[i][j][r];
        }
}

// ---------------- RoPE for q,k only (q prescaled by 1/8) ----------------
__global__ void k_rope(const float* __restrict__ qkv, const float* __restrict__ cs,
                       const float* __restrict__ sn,
                       unsigned short* __restrict__ qb, unsigned short* __restrict__ kb) {
    int s = blockIdx.x;
    const float* row = qkv + (size_t)s * NBT;
    int t = threadIdx.x;
    for (int e = t; e < 2560; e += 256) {
        int d = e & 63;
        float val = row[e];
        float c = cs[s * 64 + d], si = sn[s * 64 + d];
        float partner = (d < 32) ? -row[e + 32] : row[e - 32];
        float out = val * c + partner * si;
        if (e < 2048) {
            qb[((size_t)(e >> 6) * S_LEN + s) * 64 + d] = f2bf(out * 0.125f);
        } else {
            kb[((size_t)((e - 2048) >> 6) * S_LEN + s) * 64 + d] = f2bf(out);
        }
    }
}

// ------- flash attention: R3 skeleton (4 waves x 32 q-rows, KVBLK=64, dbuf GLD)
//         + R5-verified softmax: diag-only mask, defer-max, packed P-writes -------
__global__ __launch_bounds__(256, 2) void k_attn(const unsigned short* __restrict__ qb,
                                                 const unsigned short* __restrict__ kb,
                                                 const unsigned short* __restrict__ vt,
                                                 const float* __restrict__ gate,
                                                 const float* __restrict__ gs_p,
                                                 unsigned short* __restrict__ attnout) {
    __shared__ __align__(16) char Kl[2][8192];   // [buf][64 k rows x 128B], read-swizzled
    __shared__ __align__(16) char Vl[2][8192];   // [buf][64 d rows x 128B] (pos-permuted k)
    __shared__ __align__(16) char Pl[4][4096];   // per-wave [32 q x 128B]
    int qbi = 15 - blockIdx.x;                   // descending: big blocks first
    int h = blockIdx.y, hk = h >> 2;
    int t = threadIdx.x, wv = t >> 6, l = t & 63;
    int lr = l & 15, lg = l >> 4;
    float gs = gs_p[0];
    int q0 = qbi * 128 + wv * 32;
    const unsigned short* qbase = qb + ((size_t)h * S_LEN + q0) * 64;
    bf16x8 aq[2][2];
#pragma unroll
    for (int rt = 0; rt < 2; ++rt)
#pragma unroll
        for (int hf = 0; hf < 2; ++hf)
            aq[rt][hf] = *(const bf16x8*)(qbase + (rt * 16 + lr) * 64 + hf * 32 + lg * 8);
    f32x4 o[2][4] = {};
    float m_[2][4], ls_[2][4];
#pragma unroll
    for (int rt = 0; rt < 2; ++rt)
        for (int r = 0; r < 4; ++r) { m_[rt][r] = -INFINITY; ls_[rt][r] = 0.f; }
    int nkt = 2 * qbi + 2;
    int myKt = (q0 + 31) >> 6;
    int srow = t >> 3;
    int scol = 8 * ((t & 7) ^ (srow & 7));       // pre-swizzled source column (elems)
    const unsigned short* kg = kb + (size_t)hk * S_LEN * 64;
    const unsigned short* vg = vt + (size_t)hk * 64 * S_LEN;
    char* lKb0 = Kl[0] + wv * 1024; char* lKb1 = Kl[1] + wv * 1024;
    char* lVb0 = Vl[0] + wv * 1024; char* lVb1 = Vl[1] + wv * 1024;
    {   // stage kt=0
        GLD(kg + (size_t)srow * 64 + scol, lKb0);
        GLD(kg + (size_t)(32 + srow) * 64 + scol, lKb0 + 4096);
        GLD(vg + (size_t)srow * S_LEN + scol, lVb0);
        GLD(vg + (size_t)(32 + srow) * S_LEN + scol, lVb0 + 4096);
    }
    for (int kt = 0; kt < nkt; ++kt) {
        __syncthreads();   // buf[kt&1] staged; prior reads of buf[(kt+1)&1] done
        if (kt + 1 < nkt) {
            int k0n = (kt + 1) * 64;
            char* dK = ((kt + 1) & 1) ? lKb1 : lKb0;
            char* dV = ((kt + 1) & 1) ? lVb1 : lVb0;
            GLD(kg + (size_t)(k0n + srow) * 64 + scol, dK);
            GLD(kg + (size_t)(k0n + 32 + srow) * 64 + scol, dK + 4096);
            GLD(vg + (size_t)srow * S_LEN + k0n + scol, dV);
            GLD(vg + (size_t)(32 + srow) * S_LEN + k0n + scol, dV + 4096);
        }
        if (kt <= myKt) {
            int k0 = kt * 64;
            bool domask = (kt == myKt);
            const char* Kb = Kl[kt & 1];
            const char* Vb = Vl[kt & 1];
            char* Pb = Pl[wv];
            // ---- QK^T ----
            f32x4 sc[2][4] = {};
#pragma unroll
            for (int ct = 0; ct < 4; ++ct) {
                int krow = ct * 16 + lr;
#pragma unroll
                for (int hf = 0; hf < 2; ++hf) {
                    bf16x8 bk = *(const bf16x8*)(Kb + krow * 128 + ((hf * 64 + lg * 16) ^ SWZ(krow)));
#pragma unroll
                    for (int rt = 0; rt < 2; ++rt)
                        sc[rt][ct] = __builtin_amdgcn_mfma_f32_16x16x32_bf16(aq[rt][hf], bk, sc[rt][ct], 0, 0, 0);
                }
            }
            float gb[4];
#pragma unroll
            for (int ct = 0; ct < 4; ++ct) gb[ct] = gs * gate[k0 + ct * 16 + lr];
            // ---- online softmax (diag-only mask + defer-max) + packed P write ----
#pragma unroll
            for (int rt = 0; rt < 2; ++rt) {
#pragma unroll
                for (int r = 0; r < 4; ++r) {
                    int q = q0 + rt * 16 + lg * 4 + r;
                    float pv[4], vmax = -INFINITY;
#pragma unroll
                    for (int ct = 0; ct < 4; ++ct) {
                        float val = sc[rt][ct][r] + gb[ct];
                        if (domask && (k0 + ct * 16 + lr > q)) val -= 1e9f;
                        pv[ct] = val;
                        vmax = fmaxf(vmax, val);
                    }
                    vmax = fmaxf(vmax, __shfl_xor(vmax, 1));
                    vmax = fmaxf(vmax, __shfl_xor(vmax, 2));
                    vmax = fmaxf(vmax, __shfl_xor(vmax, 4));
                    vmax = fmaxf(vmax, __shfl_xor(vmax, 8));
                    float mn = m_[rt][r];
                    if (!__all(vmax <= mn + 8.f)) {   // defer-max (T13, verified R5)
                        mn = fmaxf(mn, vmax);
                        float scl = __expf(m_[rt][r] - mn);
                        ls_[rt][r] *= scl;
#pragma unroll
                        for (int dt = 0; dt < 4; ++dt) o[rt][dt][r] *= scl;
                        m_[rt][r] = mn;
                    }
                    float rs = 0.f;
#pragma unroll
                    for (int ct = 0; ct < 4; ++ct) {
                        float p = __expf(pv[ct] - mn);
                        pv[ct] = p; rs += p;
                    }
                    rs += __shfl_xor(rs, 1); rs += __shfl_xor(rs, 2);
                    rs += __shfl_xor(rs, 4); rs += __shfl_xor(rs, 8);
                    ls_[rt][r] += rs;
                    // packed bf16 pairs at elems {2lr,2lr+1} (ct0,1), {32+2lr,+1} (ct2,3)
                    unsigned pk01, pk23;
                    asm("v_cvt_pk_bf16_f32 %0, %1, %2" : "=v"(pk01) : "v"(pv[0]), "v"(pv[1]));
                    asm("v_cvt_pk_bf16_f32 %0, %1, %2" : "=v"(pk23) : "v"(pv[2]), "v"(pv[3]));
                    int qloc = rt * 16 + lg * 4 + r;
                    *(unsigned*)(Pb + qloc * 128 + ((4 * lr) ^ SWZ(qloc))) = pk01;
                    *(unsigned*)(Pb + qloc * 128 + ((64 + 4 * lr) ^ SWZ(qloc))) = pk23;
                }
            }
            // ---- PV: P (pos-ordered) x V^T (pos-ordered cols); same-wave LDS ordering ----
#pragma unroll
            for (int ks = 0; ks < 2; ++ks) {
                bf16x8 pa[2];
#pragma unroll
                for (int rt = 0; rt < 2; ++rt) {
                    int qrow = rt * 16 + lr;
                    pa[rt] = *(const bf16x8*)(Pb + qrow * 128 + ((ks * 64 + lg * 16) ^ SWZ(qrow)));
                }
#pragma unroll
                for (int dt = 0; dt < 4; ++dt) {
                    int vrow = dt * 16 + lr;
                    bf16x8 bv = *(const bf16x8*)(Vb + vrow * 128 + ((ks * 64 + lg * 16) ^ SWZ(vrow)));
#pragma unroll
                    for (int rt = 0; rt < 2; ++rt)
                        o[rt][dt] = __builtin_amdgcn_mfma_f32_16x16x32_bf16(pa[rt], bv, o[rt][dt], 0, 0, 0);
                }
            }
        }
    }
    // epilogue
#pragma unroll
    for (int rt = 0; rt < 2; ++rt)
#pragma unroll
        for (int r = 0; r < 4; ++r) {
            float inv = 1.f / ls_[rt][r];
            unsigned short* orow = attnout + (size_t)(q0 + rt * 16 + lg * 4 + r) * 2048 + h * 64;
#pragma unroll
            for (int dt = 0; dt < 4; ++dt) orow[dt * 16 + lr] = f2bf(o[rt][dt][r] * inv);
        }
}

extern "C" void kernel_launch(void* const* d_in, const int* in_sizes, int n_in,
                              void* d_out, int out_size, void* d_ws, size_t ws_size,
                              hipStream_t stream) {
    const float* h    = (const float*)d_in[0];
    const float* cosT = (const float*)d_in[2];
    const float* sinT = (const float*)d_in[3];
    const float* Wf   = (const float*)d_in[4];
    const float* W1   = (const float*)d_in[5];
    const float* b1   = (const float*)d_in[6];
    const float* W2   = (const float*)d_in[7];
    const float* b2   = (const float*)d_in[8];
    const float* gs   = (const float*)d_in[9];
    const float* Wq   = (const float*)d_in[10];
    const float* Wk   = (const float*)d_in[11];
    const float* Wv   = (const float*)d_in[12];
    const float* Wo   = (const float*)d_in[13];
    float* out = (float*)d_out;

    char* ws = (char*)d_ws;
    unsigned short* hb    = (unsigned short*)(ws);                 // 0 .. 8 MiB            [dead after gemm1]
    unsigned short* bt    = (unsigned short*)(ws + 8388608);       // 8388608 .. 21495808   [dead after gemm1]
    float*          qkv   = (float*)(ws + 21495808);               // 21495808 .. 47710208  [dead after rope/vtrans/fuse]
    float*          field = (float*)(ws + 47710208);
    float*          gate  = (float*)(ws + 47718400);
    unsigned short* qbuf    = (unsigned short*)(ws + 8388608);     // over bt
    unsigned short* kbuf    = (unsigned short*)(ws + 16777216);
    unsigned short* vt      = (unsigned short*)(ws + 18874368);
    unsigned short* wot     = (unsigned short*)(ws + 21495808);    // over qkv head
    unsigned short* attnout = (unsigned short*)(ws);               // over hb

    k_cvt_h<<<dim3(4096), dim3(256), 0, stream>>>(h, hb);
    k_transpose<<<dim3(32, 32), dim3(256), 0, stream>>>(Wq, bt, 2048);
    k_transpose<<<dim3(32, 8),  dim3(256), 0, stream>>>(Wk, bt + (size_t)2048 * 2048, 512);
    k_transpose<<<dim3(32, 8),  dim3(256), 0, stream>>>(Wv, bt + (size_t)2560 * 2048, 512);
    k_transpose16<<<dim3(32), dim3(256), 0, stream>>>(Wf, bt + (size_t)3072 * 2048);
    k_transpose<<<dim3(32, 1),  dim3(256), 0, stream>>>(W1, bt + (size_t)3088 * 2048, 64);
    hipMemsetAsync(ws + 8388608 + (size_t)3152 * 4096, 0, (size_t)48 * 4096, stream);
    k_gemm<<<dim3(25, 16), dim3(256), 0, stream>>>(hb, bt, qkv, 2048, NBT, 2048);
    k_rope<<<dim3(2048), dim3(256), 0, stream>>>(qkv, cosT, sinT, qbuf, kbuf);
    k_vtrans<<<dim3(32, 8), dim3(256), 0, stream>>>(qkv, vt);
    k_fuse<<<dim3(512), dim3(256), 0, stream>>>(qkv, W1, b1, W2, b2, field);
    k_gate<<<dim3(1), dim3(256), 0, stream>>>(field, gate);
    k_transpose<<<dim3(32, 32), dim3(256), 0, stream>>>(Wo, wot, 2048);
    k_attn<<<dim3(16, 32), dim3(256), 0, stream>>>(qbuf, kbuf, vt, gate, gs, attnout);
    k_gemm<<<dim3(16, 16), dim3(256), 0, stream>>>(attnout, wot, out, 2048, 2048, 2048);
}

// Round 11
// 255.603 us; speedup vs baseline: 1.5429x; 1.0398x over previous
//
#include <hip/hip_runtime.h>

#define S_LEN 2048
#define D_DIM 2048
#define NHEAD 32
#define NKVH  8
#define HDIM  64
#define NBT   3200   // 2048 q + 512 k + 512 v + 16 fiber + 64 w1h + 48 pad

typedef __attribute__((ext_vector_type(4))) float f32x4;
typedef __attribute__((ext_vector_type(8))) short bf16x8;

__device__ __forceinline__ unsigned short f2bf(float x) {
    union { float f; unsigned u; } v; v.f = x;
    unsigned r = v.u + 0x7FFFu + ((v.u >> 16) & 1u);
    return (unsigned short)(r >> 16);
}

// async global->LDS 16B: dest = wave-uniform base + lane*16
#define GLD(gsrc, ldst) __builtin_amdgcn_global_load_lds( \
    (const __attribute__((address_space(1))) unsigned int*)(const void*)(gsrc), \
    (__attribute__((address_space(3))) unsigned int*)(void*)(ldst), 16, 0, 0)

#define SWZ(r) (((r) & 7) << 4)

// ---------------- h -> bf16 ----------------
__global__ void k_cvt_h(const float* __restrict__ h, unsigned short* __restrict__ hb) {
    int i = (blockIdx.x * 256 + threadIdx.x) * 4;
    float4 v = *(const float4*)(h + i);
    ushort4 o;
    o.x = f2bf(v.x); o.y = f2bf(v.y); o.z = f2bf(v.z); o.w = f2bf(v.w);
    *(ushort4*)(hb + i) = o;
}

// ------------- transpose W [2048][N] f32 -> WT [N][2048] bf16 -------------
__global__ void k_transpose(const float* __restrict__ W, unsigned short* __restrict__ WT, int N) {
    __shared__ unsigned short L[64][65];
    int k0 = blockIdx.x * 64, n0 = blockIdx.y * 64;
    int t = threadIdx.x;
    for (int it = 0; it < 16; ++it) {
        int e = it * 256 + t;
        int r = e >> 6, c = e & 63;
        L[c][r] = f2bf(W[(size_t)(k0 + r) * N + n0 + c]);
    }
    __syncthreads();
    for (int it = 0; it < 16; ++it) {
        int e = it * 256 + t;
        int n = e >> 6, kk = e & 63;
        WT[(size_t)(n0 + n) * 2048 + k0 + kk] = L[n][kk];
    }
}

// ------------- transpose Wf [2048][16] f32 -> WT [16][2048] bf16 -------------
__global__ void k_transpose16(const float* __restrict__ W, unsigned short* __restrict__ WT) {
    __shared__ unsigned short L[16][65];
    int k0 = blockIdx.x * 64;
    int t = threadIdx.x;
    for (int it = 0; it < 4; ++it) {
        int e = it * 256 + t;
        int r = e >> 4, c = e & 15;
        L[c][r] = f2bf(W[(size_t)(k0 + r) * 16 + c]);
    }
    __syncthreads();
    for (int it = 0; it < 4; ++it) {
        int e = it * 256 + t;
        int c = e >> 6, kk = e & 63;
        WT[(size_t)c * 2048 + k0 + kk] = L[c][kk];
    }
}

// ---- transpose V slice of qkv -> vt [NKVH][64][S] bf16, k-pair-permuted ----
// pos(kk) = 2*(kk&15) | ((kk>>4)&1) | 32*(kk>>5) : pairs P-columns for cvt_pk packing
// (verified R5/R7: P elem-space == V elem-space, hardware k-slot order cancels)
__global__ void k_vtrans(const float* __restrict__ qkv, unsigned short* __restrict__ vt) {
    __shared__ unsigned short L[64][65];
    int s0 = blockIdx.x * 64, hk = blockIdx.y;
    int t = threadIdx.x;
    for (int it = 0; it < 16; ++it) {
        int e = it * 256 + t;
        int r = e >> 6, c = e & 63;
        L[c][r] = f2bf(qkv[(size_t)(s0 + r) * NBT + 2560 + hk * 64 + c]);
    }
    __syncthreads();
    for (int it = 0; it < 16; ++it) {
        int e = it * 256 + t;
        int c = e >> 6, kk = e & 63;
        int pos = ((kk & 15) << 1) | ((kk >> 4) & 1) | ((kk >> 5) << 5);
        vt[((size_t)hk * 64 + c) * S_LEN + s0 + pos] = L[c][kk];
    }
}

// ---- fuse: field[s] from fused GEMM cols (fiber 3072..3087, w1h 3088..3151) ----
__global__ __launch_bounds__(256) void k_fuse(const float* __restrict__ qkv,
                        const float* __restrict__ W1, const float* __restrict__ b1,
                        const float* __restrict__ W2, const float* __restrict__ b2,
                        float* __restrict__ field) {
    int wv = threadIdx.x >> 6, l = threadIdx.x & 63;
    int s = blockIdx.x * 4 + wv;
    const float* row = qkv + (size_t)s * NBT;
    float x = row[3088 + l] + b1[l];
#pragma unroll
    for (int f = 0; f < 16; ++f) x += row[3072 + f] * W1[(size_t)(2048 + f) * 64 + l];
    float hm = 0.5f * x * (1.f + erff(x * 0.70710678118654752f));
    float p = hm * W2[l];
    for (int m = 32; m; m >>= 1) p += __shfl_xor(p, m);
    if (l == 0) field[s] = 0.005f * (p + b2[0]);
}

// ---------------- gate = (field - mean)/(std_ddof1 + 1e-6) ----------------
__global__ void k_gate(const float* __restrict__ field, float* __restrict__ gate) {
    __shared__ float red[256];
    int t = threadIdx.x;
    float s = 0.f;
    for (int i = t; i < S_LEN; i += 256) s += field[i];
    red[t] = s; __syncthreads();
    for (int w = 128; w; w >>= 1) { if (t < w) red[t] += red[t + w]; __syncthreads(); }
    float mean = red[0] / (float)S_LEN;
    __syncthreads();
    float v = 0.f;
    for (int i = t; i < S_LEN; i += 256) { float d = field[i] - mean; v += d * d; }
    red[t] = v; __syncthreads();
    for (int w = 128; w; w >>= 1) { if (t < w) red[t] += red[t + w]; __syncthreads(); }
    float stdv = sqrtf(red[0] / (float)(S_LEN - 1)) + 1e-6f;
    for (int i = t; i < S_LEN; i += 256) gate[i] = (field[i] - mean) / stdv;
}

// ------- bf16 MFMA GEMM (m97 structure): C[M][N] = A[M][K] * BT[N][K]^T -------
__global__ __launch_bounds__(256) void k_gemm(const unsigned short* __restrict__ A,
                                              const unsigned short* __restrict__ BT,
                                              float* __restrict__ C, int M, int N, int K) {
    __shared__ __align__(16) char As[8192];
    __shared__ __align__(16) char Bs[8192];
    int m0 = blockIdx.y * 128, n0 = blockIdx.x * 128;
    int t = threadIdx.x;
    int wv = t >> 6, ln = t & 63;
    int wr = (wv >> 1) * 64, wc = (wv & 1) * 64;
    int lr = ln & 15, lkb = (ln >> 4) * 16;
    f32x4 acc[4][4] = {};
    const unsigned short* Ap = A + (size_t)(m0 + (t >> 2)) * K + (t & 3) * 8;
    const unsigned short* Bp = BT + (size_t)(n0 + (t >> 2)) * K + (t & 3) * 8;
    char* lA = As + wv * 1024;
    char* lB = Bs + wv * 1024;
    int nk = K / 32;
    GLD(Ap, lA); GLD(Ap + (size_t)64 * K, lA + 4096);
    GLD(Bp, lB); GLD(Bp + (size_t)64 * K, lB + 4096);
    for (int kt = 0; kt < nk; ++kt) {
        __syncthreads();
        bf16x8 af[4], bfv[4];
#pragma unroll
        for (int i = 0; i < 4; ++i) af[i]  = *(const bf16x8*)(As + (wr + i * 16 + lr) * 64 + lkb);
#pragma unroll
        for (int j = 0; j < 4; ++j) bfv[j] = *(const bf16x8*)(Bs + (wc + j * 16 + lr) * 64 + lkb);
#pragma unroll
        for (int i = 0; i < 4; ++i)
#pragma unroll
            for (int j = 0; j < 4; ++j)
                acc[i][j] = __builtin_amdgcn_mfma_f32_16x16x32_bf16(af[i], bfv[j], acc[i][j], 0, 0, 0);
        __syncthreads();
        if (kt + 1 < nk) {
            const unsigned short* Ak = Ap + (size_t)(kt + 1) * 32;
            const unsigned short* Bk = Bp + (size_t)(kt + 1) * 32;
            GLD(Ak, lA); GLD(Ak + (size_t)64 * K, lA + 4096);
            GLD(Bk, lB); GLD(Bk + (size_t)64 * K, lB + 4096);
        }
    }
    int orow = (ln >> 4) * 4;
#pragma unroll
    for (int i = 0; i < 4; ++i)
#pragma unroll
        for (int j = 0; j < 4; ++j) {
            float* Cp = C + (size_t)(m0 + wr + i * 16 + orow) * N + n0 + wc + j * 16 + lr;
            for (int r = 0; r < 4; ++r) Cp[(size_t)r * N] = acc[i][j][r];
        }
}

// ---------------- RoPE for q,k only (q prescaled by 1/8) ----------------
__global__ void k_rope(const float* __restrict__ qkv, const float* __restrict__ cs,
                       const float* __restrict__ sn,
                       unsigned short* __restrict__ qb, unsigned short* __restrict__ kb) {
    int s = blockIdx.x;
    const float* row = qkv + (size_t)s * NBT;
    int t = threadIdx.x;
    for (int e = t; e < 2560; e += 256) {
        int d = e & 63;
        float val = row[e];
        float c = cs[s * 64 + d], si = sn[s * 64 + d];
        float partner = (d < 32) ? -row[e + 32] : row[e - 32];
        float out = val * c + partner * si;
        if (e < 2048) {
            qb[((size_t)(e >> 6) * S_LEN + s) * 64 + d] = f2bf(out * 0.125f);
        } else {
            kb[((size_t)((e - 2048) >> 6) * S_LEN + s) * 64 + d] = f2bf(out);
        }
    }
}

// ------- flash attention: R7-proven structure (4 waves x 32 q-rows, KVBLK=64,
//         dbuf GLD staging, diag-only mask, defer-max, packed P-writes).
//         R11 change (ONLY): complementary qbi pairing for CU load balance —
//         blocks bid and bid+256 (same CU under mod-256 round-robin) get qbi
//         summing to 15, flattening per-CU work 4..64 -> ~34 kt-iters. -------
__global__ __launch_bounds__(256, 2) void k_attn(const unsigned short* __restrict__ qb,
                                                 const unsigned short* __restrict__ kb,
                                                 const unsigned short* __restrict__ vt,
                                                 const float* __restrict__ gate,
                                                 const float* __restrict__ gs_p,
                                                 unsigned short* __restrict__ attnout) {
    __shared__ __align__(16) char Kl[2][8192];   // [buf][64 k rows x 128B], read-swizzled
    __shared__ __align__(16) char Vl[2][8192];   // [buf][64 d rows x 128B] (pos-permuted k)
    __shared__ __align__(16) char Pl[4][4096];   // per-wave [32 q x 128B]
    int h = blockIdx.y, hk = h >> 2;
    int qbi = (h < 16) ? (15 - blockIdx.x) : blockIdx.x;   // complementary pairing
    int t = threadIdx.x, wv = t >> 6, l = t & 63;
    int lr = l & 15, lg = l >> 4;
    float gs = gs_p[0];
    int q0 = qbi * 128 + wv * 32;
    const unsigned short* qbase = qb + ((size_t)h * S_LEN + q0) * 64;
    bf16x8 aq[2][2];
#pragma unroll
    for (int rt = 0; rt < 2; ++rt)
#pragma unroll
        for (int hf = 0; hf < 2; ++hf)
            aq[rt][hf] = *(const bf16x8*)(qbase + (rt * 16 + lr) * 64 + hf * 32 + lg * 8);
    f32x4 o[2][4] = {};
    float m_[2][4], ls_[2][4];
#pragma unroll
    for (int rt = 0; rt < 2; ++rt)
        for (int r = 0; r < 4; ++r) { m_[rt][r] = -INFINITY; ls_[rt][r] = 0.f; }
    int nkt = 2 * qbi + 2;
    int myKt = (q0 + 31) >> 6;
    int srow = t >> 3;
    int scol = 8 * ((t & 7) ^ (srow & 7));       // pre-swizzled source column (elems)
    const unsigned short* kg = kb + (size_t)hk * S_LEN * 64;
    const unsigned short* vg = vt + (size_t)hk * 64 * S_LEN;
    char* lKb0 = Kl[0] + wv * 1024; char* lKb1 = Kl[1] + wv * 1024;
    char* lVb0 = Vl[0] + wv * 1024; char* lVb1 = Vl[1] + wv * 1024;
    {   // stage kt=0
        GLD(kg + (size_t)srow * 64 + scol, lKb0);
        GLD(kg + (size_t)(32 + srow) * 64 + scol, lKb0 + 4096);
        GLD(vg + (size_t)srow * S_LEN + scol, lVb0);
        GLD(vg + (size_t)(32 + srow) * S_LEN + scol, lVb0 + 4096);
    }
    for (int kt = 0; kt < nkt; ++kt) {
        __syncthreads();   // buf[kt&1] staged; prior reads of buf[(kt+1)&1] done
        if (kt + 1 < nkt) {
            int k0n = (kt + 1) * 64;
            char* dK = ((kt + 1) & 1) ? lKb1 : lKb0;
            char* dV = ((kt + 1) & 1) ? lVb1 : lVb0;
            GLD(kg + (size_t)(k0n + srow) * 64 + scol, dK);
            GLD(kg + (size_t)(k0n + 32 + srow) * 64 + scol, dK + 4096);
            GLD(vg + (size_t)srow * S_LEN + k0n + scol, dV);
            GLD(vg + (size_t)(32 + srow) * S_LEN + k0n + scol, dV + 4096);
        }
        if (kt <= myKt) {
            int k0 = kt * 64;
            bool domask = (kt == myKt);
            const char* Kb = Kl[kt & 1];
            const char* Vb = Vl[kt & 1];
            char* Pb = Pl[wv];
            // ---- QK^T ----
            f32x4 sc[2][4] = {};
#pragma unroll
            for (int ct = 0; ct < 4; ++ct) {
                int krow = ct * 16 + lr;
#pragma unroll
                for (int hf = 0; hf < 2; ++hf) {
                    bf16x8 bk = *(const bf16x8*)(Kb + krow * 128 + ((hf * 64 + lg * 16) ^ SWZ(krow)));
#pragma unroll
                    for (int rt = 0; rt < 2; ++rt)
                        sc[rt][ct] = __builtin_amdgcn_mfma_f32_16x16x32_bf16(aq[rt][hf], bk, sc[rt][ct], 0, 0, 0);
                }
            }
            float gb[4];
#pragma unroll
            for (int ct = 0; ct < 4; ++ct) gb[ct] = gs * gate[k0 + ct * 16 + lr];
            // ---- online softmax (diag-only mask + defer-max) + packed P write ----
#pragma unroll
            for (int rt = 0; rt < 2; ++rt) {
#pragma unroll
                for (int r = 0; r < 4; ++r) {
                    int q = q0 + rt * 16 + lg * 4 + r;
                    float pv[4], vmax = -INFINITY;
#pragma unroll
                    for (int ct = 0; ct < 4; ++ct) {
                        float val = sc[rt][ct][r] + gb[ct];
                        if (domask && (k0 + ct * 16 + lr > q)) val -= 1e9f;
                        pv[ct] = val;
                        vmax = fmaxf(vmax, val);
                    }
                    vmax = fmaxf(vmax, __shfl_xor(vmax, 1));
                    vmax = fmaxf(vmax, __shfl_xor(vmax, 2));
                    vmax = fmaxf(vmax, __shfl_xor(vmax, 4));
                    vmax = fmaxf(vmax, __shfl_xor(vmax, 8));
                    float mn = m_[rt][r];
                    if (!__all(vmax <= mn + 8.f)) {   // defer-max (T13, verified R5)
                        mn = fmaxf(mn, vmax);
                        float scl = __expf(m_[rt][r] - mn);
                        ls_[rt][r] *= scl;
#pragma unroll
                        for (int dt = 0; dt < 4; ++dt) o[rt][dt][r] *= scl;
                        m_[rt][r] = mn;
                    }
                    float rs = 0.f;
#pragma unroll
                    for (int ct = 0; ct < 4; ++ct) {
                        float p = __expf(pv[ct] - mn);
                        pv[ct] = p; rs += p;
                    }
                    rs += __shfl_xor(rs, 1); rs += __shfl_xor(rs, 2);
                    rs += __shfl_xor(rs, 4); rs += __shfl_xor(rs, 8);
                    ls_[rt][r] += rs;
                    // packed bf16 pairs at elems {2lr,2lr+1} (ct0,1), {32+2lr,+1} (ct2,3)
                    unsigned pk01, pk23;
                    asm("v_cvt_pk_bf16_f32 %0, %1, %2" : "=v"(pk01) : "v"(pv[0]), "v"(pv[1]));
                    asm("v_cvt_pk_bf16_f32 %0, %1, %2" : "=v"(pk23) : "v"(pv[2]), "v"(pv[3]));
                    int qloc = rt * 16 + lg * 4 + r;
                    *(unsigned*)(Pb + qloc * 128 + ((4 * lr) ^ SWZ(qloc))) = pk01;
                    *(unsigned*)(Pb + qloc * 128 + ((64 + 4 * lr) ^ SWZ(qloc))) = pk23;
                }
            }
            // ---- PV: P (pos-ordered) x V^T (pos-ordered cols); same-wave LDS ordering ----
#pragma unroll
            for (int ks = 0; ks < 2; ++ks) {
                bf16x8 pa[2];
#pragma unroll
                for (int rt = 0; rt < 2; ++rt) {
                    int qrow = rt * 16 + lr;
                    pa[rt] = *(const bf16x8*)(Pb + qrow * 128 + ((ks * 64 + lg * 16) ^ SWZ(qrow)));
                }
#pragma unroll
                for (int dt = 0; dt < 4; ++dt) {
                    int vrow = dt * 16 + lr;
                    bf16x8 bv = *(const bf16x8*)(Vb + vrow * 128 + ((ks * 64 + lg * 16) ^ SWZ(vrow)));
#pragma unroll
                    for (int rt = 0; rt < 2; ++rt)
                        o[rt][dt] = __builtin_amdgcn_mfma_f32_16x16x32_bf16(pa[rt], bv, o[rt][dt], 0, 0, 0);
                }
            }
        }
    }
    // epilogue
#pragma unroll
    for (int rt = 0; rt < 2; ++rt)
#pragma unroll
        for (int r = 0; r < 4; ++r) {
            float inv = 1.f / ls_[rt][r];
            unsigned short* orow = attnout + (size_t)(q0 + rt * 16 + lg * 4 + r) * 2048 + h * 64;
#pragma unroll
            for (int dt = 0; dt < 4; ++dt) orow[dt * 16 + lr] = f2bf(o[rt][dt][r] * inv);
        }
}

extern "C" void kernel_launch(void* const* d_in, const int* in_sizes, int n_in,
                              void* d_out, int out_size, void* d_ws, size_t ws_size,
                              hipStream_t stream) {
    const float* h    = (const float*)d_in[0];
    const float* cosT = (const float*)d_in[2];
    const float* sinT = (const float*)d_in[3];
    const float* Wf   = (const float*)d_in[4];
    const float* W1   = (const float*)d_in[5];
    const float* b1   = (const float*)d_in[6];
    const float* W2   = (const float*)d_in[7];
    const float* b2   = (const float*)d_in[8];
    const float* gs   = (const float*)d_in[9];
    const float* Wq   = (const float*)d_in[10];
    const float* Wk   = (const float*)d_in[11];
    const float* Wv   = (const float*)d_in[12];
    const float* Wo   = (const float*)d_in[13];
    float* out = (float*)d_out;

    char* ws = (char*)d_ws;
    unsigned short* hb    = (unsigned short*)(ws);                 // 0 .. 8 MiB            [dead after gemm1]
    unsigned short* bt    = (unsigned short*)(ws + 8388608);       // 8388608 .. 21495808   [dead after gemm1]
    float*          qkv   = (float*)(ws + 21495808);               // 21495808 .. 47710208  [dead after rope/vtrans/fuse]
    float*          field = (float*)(ws + 47710208);
    float*          gate  = (float*)(ws + 47718400);
    unsigned short* qbuf    = (unsigned short*)(ws + 8388608);     // over bt
    unsigned short* kbuf    = (unsigned short*)(ws + 16777216);
    unsigned short* vt      = (unsigned short*)(ws + 18874368);
    unsigned short* wot     = (unsigned short*)(ws + 21495808);    // over qkv head
    unsigned short* attnout = (unsigned short*)(ws);               // over hb

    k_cvt_h<<<dim3(4096), dim3(256), 0, stream>>>(h, hb);
    k_transpose<<<dim3(32, 32), dim3(256), 0, stream>>>(Wq, bt, 2048);
    k_transpose<<<dim3(32, 8),  dim3(256), 0, stream>>>(Wk, bt + (size_t)2048 * 2048, 512);
    k_transpose<<<dim3(32, 8),  dim3(256), 0, stream>>>(Wv, bt + (size_t)2560 * 2048, 512);
    k_transpose16<<<dim3(32), dim3(256), 0, stream>>>(Wf, bt + (size_t)3072 * 2048);
    k_transpose<<<dim3(32, 1),  dim3(256), 0, stream>>>(W1, bt + (size_t)3088 * 2048, 64);
    hipMemsetAsync(ws + 8388608 + (size_t)3152 * 4096, 0, (size_t)48 * 4096, stream);
    k_gemm<<<dim3(25, 16), dim3(256), 0, stream>>>(hb, bt, qkv, 2048, NBT, 2048);
    k_rope<<<dim3(2048), dim3(256), 0, stream>>>(qkv, cosT, sinT, qbuf, kbuf);
    k_vtrans<<<dim3(32, 8), dim3(256), 0, stream>>>(qkv, vt);
    k_fuse<<<dim3(512), dim3(256), 0, stream>>>(qkv, W1, b1, W2, b2, field);
    k_gate<<<dim3(1), dim3(256), 0, stream>>>(field, gate);
    k_transpose<<<dim3(32, 32), dim3(256), 0, stream>>>(Wo, wot, 2048);
    k_attn<<<dim3(16, 32), dim3(256), 0, stream>>>(qbuf, kbuf, vt, gate, gs, attnout);
    k_gemm<<<dim3(16, 16), dim3(256), 0, stream>>>(attnout, wot, out, 2048, 2048, 2048);
}

// Round 12
// 239.769 us; speedup vs baseline: 1.6448x; 1.0660x over previous
//
#include <hip/hip_runtime.h>

#define S_LEN 2048
#define D_DIM 2048
#define NHEAD 32
#define NKVH  8
#define HDIM  64
#define NBT   3200   // 2048 q + 512 k + 512 v + 16 fiber + 64 w1h + 48 pad

typedef __attribute__((ext_vector_type(4))) float f32x4;
typedef __attribute__((ext_vector_type(8))) short bf16x8;

__device__ __forceinline__ unsigned short f2bf(float x) {
    union { float f; unsigned u; } v; v.f = x;
    unsigned r = v.u + 0x7FFFu + ((v.u >> 16) & 1u);
    return (unsigned short)(r >> 16);
}

// async global->LDS 16B: dest = wave-uniform base + lane*16
#define GLD(gsrc, ldst) __builtin_amdgcn_global_load_lds( \
    (const __attribute__((address_space(1))) unsigned int*)(const void*)(gsrc), \
    (__attribute__((address_space(3))) unsigned int*)(void*)(ldst), 16, 0, 0)

#define SWZ(r) (((r) & 7) << 4)

// ---------------- h -> bf16 ----------------
__global__ void k_cvt_h(const float* __restrict__ h, unsigned short* __restrict__ hb) {
    int i = (blockIdx.x * 256 + threadIdx.x) * 4;
    float4 v = *(const float4*)(h + i);
    ushort4 o;
    o.x = f2bf(v.x); o.y = f2bf(v.y); o.z = f2bf(v.z); o.w = f2bf(v.w);
    *(ushort4*)(hb + i) = o;
}

// ------------- transpose W [2048][N] f32 -> WT [N][2048] bf16 -------------
__global__ void k_transpose(const float* __restrict__ W, unsigned short* __restrict__ WT, int N) {
    __shared__ unsigned short L[64][65];
    int k0 = blockIdx.x * 64, n0 = blockIdx.y * 64;
    int t = threadIdx.x;
    for (int it = 0; it < 16; ++it) {
        int e = it * 256 + t;
        int r = e >> 6, c = e & 63;
        L[c][r] = f2bf(W[(size_t)(k0 + r) * N + n0 + c]);
    }
    __syncthreads();
    for (int it = 0; it < 16; ++it) {
        int e = it * 256 + t;
        int n = e >> 6, kk = e & 63;
        WT[(size_t)(n0 + n) * 2048 + k0 + kk] = L[n][kk];
    }
}

// ------------- transpose Wf [2048][16] f32 -> WT [16][2048] bf16 -------------
__global__ void k_transpose16(const float* __restrict__ W, unsigned short* __restrict__ WT) {
    __shared__ unsigned short L[16][65];
    int k0 = blockIdx.x * 64;
    int t = threadIdx.x;
    for (int it = 0; it < 4; ++it) {
        int e = it * 256 + t;
        int r = e >> 4, c = e & 15;
        L[c][r] = f2bf(W[(size_t)(k0 + r) * 16 + c]);
    }
    __syncthreads();
    for (int it = 0; it < 4; ++it) {
        int e = it * 256 + t;
        int c = e >> 6, kk = e & 63;
        WT[(size_t)c * 2048 + k0 + kk] = L[c][kk];
    }
}

// ---- transpose vrow [S][512] bf16 -> vt [NKVH][64][S] bf16, k-pair-permuted ----
// pos(kk) = 2*(kk&15) | ((kk>>4)&1) | 32*(kk>>5)  (verified R5/R7)
__global__ void k_vtrans(const unsigned short* __restrict__ vrow, unsigned short* __restrict__ vt) {
    __shared__ unsigned short L[64][65];
    int s0 = blockIdx.x * 64, hk = blockIdx.y;
    int t = threadIdx.x;
    for (int it = 0; it < 16; ++it) {
        int e = it * 256 + t;
        int r = e >> 6, c = e & 63;
        L[c][r] = vrow[(size_t)(s0 + r) * 512 + hk * 64 + c];
    }
    __syncthreads();
    for (int it = 0; it < 16; ++it) {
        int e = it * 256 + t;
        int c = e >> 6, kk = e & 63;
        int pos = ((kk & 15) << 1) | ((kk >> 4) & 1) | ((kk >> 5) << 5);
        vt[((size_t)hk * 64 + c) * S_LEN + s0 + pos] = L[c][kk];
    }
}

// ---- fuse: field[s] from adapter cols (fiber 0..15, w1h 16..79 of adcols[S][128]) ----
__global__ __launch_bounds__(256) void k_fuse(const float* __restrict__ adcols,
                        const float* __restrict__ W1, const float* __restrict__ b1,
                        const float* __restrict__ W2, const float* __restrict__ b2,
                        float* __restrict__ field) {
    int wv = threadIdx.x >> 6, l = threadIdx.x & 63;
    int s = blockIdx.x * 4 + wv;
    const float* row = adcols + (size_t)s * 128;
    float x = row[16 + l] + b1[l];
#pragma unroll
    for (int f = 0; f < 16; ++f) x += row[f] * W1[(size_t)(2048 + f) * 64 + l];
    float hm = 0.5f * x * (1.f + erff(x * 0.70710678118654752f));
    float p = hm * W2[l];
    for (int m = 32; m; m >>= 1) p += __shfl_xor(p, m);
    if (l == 0) field[s] = 0.005f * (p + b2[0]);
}

// ---------------- gate = (field - mean)/(std_ddof1 + 1e-6) ----------------
__global__ void k_gate(const float* __restrict__ field, float* __restrict__ gate) {
    __shared__ float red[256];
    int t = threadIdx.x;
    float s = 0.f;
    for (int i = t; i < S_LEN; i += 256) s += field[i];
    red[t] = s; __syncthreads();
    for (int w = 128; w; w >>= 1) { if (t < w) red[t] += red[t + w]; __syncthreads(); }
    float mean = red[0] / (float)S_LEN;
    __syncthreads();
    float v = 0.f;
    for (int i = t; i < S_LEN; i += 256) { float d = field[i] - mean; v += d * d; }
    red[t] = v; __syncthreads();
    for (int w = 128; w; w >>= 1) { if (t < w) red[t] += red[t + w]; __syncthreads(); }
    float stdv = sqrtf(red[0] / (float)(S_LEN - 1)) + 1e-6f;
    for (int i = t; i < S_LEN; i += 256) gate[i] = (field[i] - mean) / stdv;
}

// ------- GEMM1: hb[2048][2048] x bt[3200][2048]^T with fused RoPE epilogue -------
// n-tile ranges (all 64-aligned): [0,2048) q -> qb; [2048,2560) k -> kbuf;
// [2560,3072) v -> vrow bf16; [3072,3200) adapter -> adcols f32.
// RoPE partner of col d is d^32 = acc[i][j^2] in the SAME thread.
__global__ __launch_bounds__(256) void k_gemm_qkv(const unsigned short* __restrict__ A,
                                                  const unsigned short* __restrict__ BT,
                                                  const float* __restrict__ cs,
                                                  const float* __restrict__ sn,
                                                  unsigned short* __restrict__ qb,
                                                  unsigned short* __restrict__ kbuf,
                                                  unsigned short* __restrict__ vrow,
                                                  float* __restrict__ adcols) {
    __shared__ __align__(16) char As[8192];
    __shared__ __align__(16) char Bs[8192];
    const int K = 2048;
    // XCD-aware swizzle (bijective: nwg = 25*16 = 400, 400 % 8 == 0)
    int flat = blockIdx.y * gridDim.x + blockIdx.x;
    int cpx = (gridDim.x * gridDim.y) >> 3;
    int swz = (flat & 7) * cpx + (flat >> 3);
    int m0 = (swz / gridDim.x) * 128, n0 = (swz % gridDim.x) * 128;
    int t = threadIdx.x;
    int wv = t >> 6, ln = t & 63;
    int wr = (wv >> 1) * 64, wc = (wv & 1) * 64;
    int lr = ln & 15, lkb = (ln >> 4) * 16;
    f32x4 acc[4][4] = {};
    const unsigned short* Ap = A + (size_t)(m0 + (t >> 2)) * K + (t & 3) * 8;
    const unsigned short* Bp = BT + (size_t)(n0 + (t >> 2)) * K + (t & 3) * 8;
    char* lA = As + wv * 1024;
    char* lB = Bs + wv * 1024;
    int nk = K / 32;
    GLD(Ap, lA); GLD(Ap + (size_t)64 * K, lA + 4096);
    GLD(Bp, lB); GLD(Bp + (size_t)64 * K, lB + 4096);
    for (int kt = 0; kt < nk; ++kt) {
        __syncthreads();
        bf16x8 af[4], bfv[4];
#pragma unroll
        for (int i = 0; i < 4; ++i) af[i]  = *(const bf16x8*)(As + (wr + i * 16 + lr) * 64 + lkb);
#pragma unroll
        for (int j = 0; j < 4; ++j) bfv[j] = *(const bf16x8*)(Bs + (wc + j * 16 + lr) * 64 + lkb);
#pragma unroll
        for (int i = 0; i < 4; ++i)
#pragma unroll
            for (int j = 0; j < 4; ++j)
                acc[i][j] = __builtin_amdgcn_mfma_f32_16x16x32_bf16(af[i], bfv[j], acc[i][j], 0, 0, 0);
        __syncthreads();
        if (kt + 1 < nk) {
            const unsigned short* Ak = Ap + (size_t)(kt + 1) * 32;
            const unsigned short* Bk = Bp + (size_t)(kt + 1) * 32;
            GLD(Ak, lA); GLD(Ak + (size_t)64 * K, lA + 4096);
            GLD(Bk, lB); GLD(Bk + (size_t)64 * K, lB + 4096);
        }
    }
    int orow = (ln >> 4) * 4;
    int col0 = n0 + wc;                 // multiple of 64; branch is wave-uniform
    if (col0 < 2560) {
        // q or k: RoPE rotate in-register, write bf16
        bool isq = (col0 < 2048);
        unsigned short* dst = isq ? qb : kbuf;
        int hh = (isq ? col0 : col0 - 2048) >> 6;
        float qscale = isq ? 0.125f : 1.0f;
#pragma unroll
        for (int i = 0; i < 4; ++i)
#pragma unroll
            for (int r = 0; r < 4; ++r) {
                int s = m0 + wr + i * 16 + orow + r;
#pragma unroll
                for (int j = 0; j < 4; ++j) {
                    int d = j * 16 + lr;
                    float c = cs[s * 64 + d], si = sn[s * 64 + d];
                    float val = acc[i][j][r];
                    float prt = acc[i][j ^ 2][r];
                    float out = val * c + ((j < 2) ? -prt : prt) * si;
                    dst[((size_t)hh * S_LEN + s) * 64 + d] = f2bf(out * qscale);
                }
            }
    } else if (col0 < 3072) {
        // v: write bf16 rows [S][512]
        int vc0 = col0 - 2560;
#pragma unroll
        for (int i = 0; i < 4; ++i)
#pragma unroll
            for (int j = 0; j < 4; ++j) {
                unsigned short* vp = vrow + (size_t)(m0 + wr + i * 16 + orow) * 512 + vc0 + j * 16 + lr;
                for (int r = 0; r < 4; ++r) vp[(size_t)r * 512] = f2bf(acc[i][j][r]);
            }
    } else {
        // adapter cols: f32 [S][128]
        int ac0 = col0 - 3072;
#pragma unroll
        for (int i = 0; i < 4; ++i)
#pragma unroll
            for (int j = 0; j < 4; ++j) {
                float* ap = adcols + (size_t)(m0 + wr + i * 16 + orow) * 128 + ac0 + j * 16 + lr;
                for (int r = 0; r < 4; ++r) ap[(size_t)r * 128] = acc[i][j][r];
            }
    }
}

// ------- generic bf16 MFMA GEMM (m97 + XCD swizzle): C = A * BT^T -------
__global__ __launch_bounds__(256) void k_gemm(const unsigned short* __restrict__ A,
                                              const unsigned short* __restrict__ BT,
                                              float* __restrict__ C, int M, int N, int K) {
    __shared__ __align__(16) char As[8192];
    __shared__ __align__(16) char Bs[8192];
    int flat = blockIdx.y * gridDim.x + blockIdx.x;
    int cpx = (gridDim.x * gridDim.y) >> 3;      // requires nwg % 8 == 0
    int swz = (flat & 7) * cpx + (flat >> 3);
    int m0 = (swz / gridDim.x) * 128, n0 = (swz % gridDim.x) * 128;
    int t = threadIdx.x;
    int wv = t >> 6, ln = t & 63;
    int wr = (wv >> 1) * 64, wc = (wv & 1) * 64;
    int lr = ln & 15, lkb = (ln >> 4) * 16;
    f32x4 acc[4][4] = {};
    const unsigned short* Ap = A + (size_t)(m0 + (t >> 2)) * K + (t & 3) * 8;
    const unsigned short* Bp = BT + (size_t)(n0 + (t >> 2)) * K + (t & 3) * 8;
    char* lA = As + wv * 1024;
    char* lB = Bs + wv * 1024;
    int nk = K / 32;
    GLD(Ap, lA); GLD(Ap + (size_t)64 * K, lA + 4096);
    GLD(Bp, lB); GLD(Bp + (size_t)64 * K, lB + 4096);
    for (int kt = 0; kt < nk; ++kt) {
        __syncthreads();
        bf16x8 af[4], bfv[4];
#pragma unroll
        for (int i = 0; i < 4; ++i) af[i]  = *(const bf16x8*)(As + (wr + i * 16 + lr) * 64 + lkb);
#pragma unroll
        for (int j = 0; j < 4; ++j) bfv[j] = *(const bf16x8*)(Bs + (wc + j * 16 + lr) * 64 + lkb);
#pragma unroll
        for (int i = 0; i < 4; ++i)
#pragma unroll
            for (int j = 0; j < 4; ++j)
                acc[i][j] = __builtin_amdgcn_mfma_f32_16x16x32_bf16(af[i], bfv[j], acc[i][j], 0, 0, 0);
        __syncthreads();
        if (kt + 1 < nk) {
            const unsigned short* Ak = Ap + (size_t)(kt + 1) * 32;
            const unsigned short* Bk = Bp + (size_t)(kt + 1) * 32;
            GLD(Ak, lA); GLD(Ak + (size_t)64 * K, lA + 4096);
            GLD(Bk, lB); GLD(Bk + (size_t)64 * K, lB + 4096);
        }
    }
    int orow = (ln >> 4) * 4;
#pragma unroll
    for (int i = 0; i < 4; ++i)
#pragma unroll
        for (int j = 0; j < 4; ++j) {
            float* Cp = C + (size_t)(m0 + wr + i * 16 + orow) * N + n0 + wc + j * 16 + lr;
            for (int r = 0; r < 4; ++r) Cp[(size_t)r * N] = acc[i][j][r];
        }
}

// ------- flash attention: R7/R11-proven (4 waves x 32 q-rows, KVBLK=64, dbuf GLD,
//         diag-only mask, defer-max, packed P-writes, complementary qbi pairing) -------
__global__ __launch_bounds__(256, 2) void k_attn(const unsigned short* __restrict__ qb,
                                                 const unsigned short* __restrict__ kb,
                                                 const unsigned short* __restrict__ vt,
                                                 const float* __restrict__ gate,
                                                 const float* __restrict__ gs_p,
                                                 unsigned short* __restrict__ attnout) {
    __shared__ __align__(16) char Kl[2][8192];
    __shared__ __align__(16) char Vl[2][8192];
    __shared__ __align__(16) char Pl[4][4096];
    int h = blockIdx.y, hk = h >> 2;
    int qbi = (h < 16) ? (15 - blockIdx.x) : blockIdx.x;   // complementary pairing
    int t = threadIdx.x, wv = t >> 6, l = t & 63;
    int lr = l & 15, lg = l >> 4;
    float gs = gs_p[0];
    int q0 = qbi * 128 + wv * 32;
    const unsigned short* qbase = qb + ((size_t)h * S_LEN + q0) * 64;
    bf16x8 aq[2][2];
#pragma unroll
    for (int rt = 0; rt < 2; ++rt)
#pragma unroll
        for (int hf = 0; hf < 2; ++hf)
            aq[rt][hf] = *(const bf16x8*)(qbase + (rt * 16 + lr) * 64 + hf * 32 + lg * 8);
    f32x4 o[2][4] = {};
    float m_[2][4], ls_[2][4];
#pragma unroll
    for (int rt = 0; rt < 2; ++rt)
        for (int r = 0; r < 4; ++r) { m_[rt][r] = -INFINITY; ls_[rt][r] = 0.f; }
    int nkt = 2 * qbi + 2;
    int myKt = (q0 + 31) >> 6;
    int srow = t >> 3;
    int scol = 8 * ((t & 7) ^ (srow & 7));
    const unsigned short* kg = kb + (size_t)hk * S_LEN * 64;
    const unsigned short* vg = vt + (size_t)hk * 64 * S_LEN;
    char* lKb0 = Kl[0] + wv * 1024; char* lKb1 = Kl[1] + wv * 1024;
    char* lVb0 = Vl[0] + wv * 1024; char* lVb1 = Vl[1] + wv * 1024;
    {
        GLD(kg + (size_t)srow * 64 + scol, lKb0);
        GLD(kg + (size_t)(32 + srow) * 64 + scol, lKb0 + 4096);
        GLD(vg + (size_t)srow * S_LEN + scol, lVb0);
        GLD(vg + (size_t)(32 + srow) * S_LEN + scol, lVb0 + 4096);
    }
    for (int kt = 0; kt < nkt; ++kt) {
        __syncthreads();
        if (kt + 1 < nkt) {
            int k0n = (kt + 1) * 64;
            char* dK = ((kt + 1) & 1) ? lKb1 : lKb0;
            char* dV = ((kt + 1) & 1) ? lVb1 : lVb0;
            GLD(kg + (size_t)(k0n + srow) * 64 + scol, dK);
            GLD(kg + (size_t)(k0n + 32 + srow) * 64 + scol, dK + 4096);
            GLD(vg + (size_t)srow * S_LEN + k0n + scol, dV);
            GLD(vg + (size_t)(32 + srow) * S_LEN + k0n + scol, dV + 4096);
        }
        if (kt <= myKt) {
            int k0 = kt * 64;
            bool domask = (kt == myKt);
            const char* Kb = Kl[kt & 1];
            const char* Vb = Vl[kt & 1];
            char* Pb = Pl[wv];
            f32x4 sc[2][4] = {};
#pragma unroll
            for (int ct = 0; ct < 4; ++ct) {
                int krow = ct * 16 + lr;
#pragma unroll
                for (int hf = 0; hf < 2; ++hf) {
                    bf16x8 bk = *(const bf16x8*)(Kb + krow * 128 + ((hf * 64 + lg * 16) ^ SWZ(krow)));
#pragma unroll
                    for (int rt = 0; rt < 2; ++rt)
                        sc[rt][ct] = __builtin_amdgcn_mfma_f32_16x16x32_bf16(aq[rt][hf], bk, sc[rt][ct], 0, 0, 0);
                }
            }
            float gb[4];
#pragma unroll
            for (int ct = 0; ct < 4; ++ct) gb[ct] = gs * gate[k0 + ct * 16 + lr];
#pragma unroll
            for (int rt = 0; rt < 2; ++rt) {
#pragma unroll
                for (int r = 0; r < 4; ++r) {
                    int q = q0 + rt * 16 + lg * 4 + r;
                    float pv[4], vmax = -INFINITY;
#pragma unroll
                    for (int ct = 0; ct < 4; ++ct) {
                        float val = sc[rt][ct][r] + gb[ct];
                        if (domask && (k0 + ct * 16 + lr > q)) val -= 1e9f;
                        pv[ct] = val;
                        vmax = fmaxf(vmax, val);
                    }
                    vmax = fmaxf(vmax, __shfl_xor(vmax, 1));
                    vmax = fmaxf(vmax, __shfl_xor(vmax, 2));
                    vmax = fmaxf(vmax, __shfl_xor(vmax, 4));
                    vmax = fmaxf(vmax, __shfl_xor(vmax, 8));
                    float mn = m_[rt][r];
                    if (!__all(vmax <= mn + 8.f)) {
                        mn = fmaxf(mn, vmax);
                        float scl = __expf(m_[rt][r] - mn);
                        ls_[rt][r] *= scl;
#pragma unroll
                        for (int dt = 0; dt < 4; ++dt) o[rt][dt][r] *= scl;
                        m_[rt][r] = mn;
                    }
                    float rs = 0.f;
#pragma unroll
                    for (int ct = 0; ct < 4; ++ct) {
                        float p = __expf(pv[ct] - mn);
                        pv[ct] = p; rs += p;
                    }
                    rs += __shfl_xor(rs, 1); rs += __shfl_xor(rs, 2);
                    rs += __shfl_xor(rs, 4); rs += __shfl_xor(rs, 8);
                    ls_[rt][r] += rs;
                    unsigned pk01, pk23;
                    asm("v_cvt_pk_bf16_f32 %0, %1, %2" : "=v"(pk01) : "v"(pv[0]), "v"(pv[1]));
                    asm("v_cvt_pk_bf16_f32 %0, %1, %2" : "=v"(pk23) : "v"(pv[2]), "v"(pv[3]));
                    int qloc = rt * 16 + lg * 4 + r;
                    *(unsigned*)(Pb + qloc * 128 + ((4 * lr) ^ SWZ(qloc))) = pk01;
                    *(unsigned*)(Pb + qloc * 128 + ((64 + 4 * lr) ^ SWZ(qloc))) = pk23;
                }
            }
#pragma unroll
            for (int ks = 0; ks < 2; ++ks) {
                bf16x8 pa[2];
#pragma unroll
                for (int rt = 0; rt < 2; ++rt) {
                    int qrow = rt * 16 + lr;
                    pa[rt] = *(const bf16x8*)(Pb + qrow * 128 + ((ks * 64 + lg * 16) ^ SWZ(qrow)));
                }
#pragma unroll
                for (int dt = 0; dt < 4; ++dt) {
                    int vrow_ = dt * 16 + lr;
                    bf16x8 bv = *(const bf16x8*)(Vb + vrow_ * 128 + ((ks * 64 + lg * 16) ^ SWZ(vrow_)));
#pragma unroll
                    for (int rt = 0; rt < 2; ++rt)
                        o[rt][dt] = __builtin_amdgcn_mfma_f32_16x16x32_bf16(pa[rt], bv, o[rt][dt], 0, 0, 0);
                }
            }
        }
    }
#pragma unroll
    for (int rt = 0; rt < 2; ++rt)
#pragma unroll
        for (int r = 0; r < 4; ++r) {
            float inv = 1.f / ls_[rt][r];
            unsigned short* orow = attnout + (size_t)(q0 + rt * 16 + lg * 4 + r) * 2048 + h * 64;
#pragma unroll
            for (int dt = 0; dt < 4; ++dt) orow[dt * 16 + lr] = f2bf(o[rt][dt][r] * inv);
        }
}

extern "C" void kernel_launch(void* const* d_in, const int* in_sizes, int n_in,
                              void* d_out, int out_size, void* d_ws, size_t ws_size,
                              hipStream_t stream) {
    const float* h    = (const float*)d_in[0];
    const float* cosT = (const float*)d_in[2];
    const float* sinT = (const float*)d_in[3];
    const float* Wf   = (const float*)d_in[4];
    const float* W1   = (const float*)d_in[5];
    const float* b1   = (const float*)d_in[6];
    const float* W2   = (const float*)d_in[7];
    const float* b2   = (const float*)d_in[8];
    const float* gs   = (const float*)d_in[9];
    const float* Wq   = (const float*)d_in[10];
    const float* Wk   = (const float*)d_in[11];
    const float* Wv   = (const float*)d_in[12];
    const float* Wo   = (const float*)d_in[13];
    float* out = (float*)d_out;

    char* ws = (char*)d_ws;
    // layout (bytes):
    unsigned short* hb     = (unsigned short*)(ws);                // 0..8M        [dead after gemm1]
    unsigned short* bt     = (unsigned short*)(ws + 8388608);      // 8M..21.5M    [dead after gemm1]
    unsigned short* qbuf   = (unsigned short*)(ws + 21495808);     // 8M  (live from gemm1)
    unsigned short* kbuf   = (unsigned short*)(ws + 29884416);     // 2M
    unsigned short* vrow   = (unsigned short*)(ws + 31981568);     // 2M
    float*          adcols = (float*)(ws + 34078720);              // 1M
    float*          field  = (float*)(ws + 35127296);              // 8K
    float*          gate   = (float*)(ws + 35135488);              // 8K
    // aliases over dead regions (after gemm1):
    unsigned short* wot     = (unsigned short*)(ws + 8388608);     // 8M over bt
    unsigned short* vt      = (unsigned short*)(ws + 16777216);    // 2M over bt tail
    unsigned short* attnout = (unsigned short*)(ws);               // 8M over hb

    k_cvt_h<<<dim3(4096), dim3(256), 0, stream>>>(h, hb);
    k_transpose<<<dim3(32, 32), dim3(256), 0, stream>>>(Wq, bt, 2048);
    k_transpose<<<dim3(32, 8),  dim3(256), 0, stream>>>(Wk, bt + (size_t)2048 * 2048, 512);
    k_transpose<<<dim3(32, 8),  dim3(256), 0, stream>>>(Wv, bt + (size_t)2560 * 2048, 512);
    k_transpose16<<<dim3(32), dim3(256), 0, stream>>>(Wf, bt + (size_t)3072 * 2048);
    k_transpose<<<dim3(32, 1),  dim3(256), 0, stream>>>(W1, bt + (size_t)3088 * 2048, 64);
    hipMemsetAsync(ws + 8388608 + (size_t)3152 * 4096, 0, (size_t)48 * 4096, stream);
    k_gemm_qkv<<<dim3(25, 16), dim3(256), 0, stream>>>(hb, bt, cosT, sinT, qbuf, kbuf, vrow, adcols);
    k_fuse<<<dim3(512), dim3(256), 0, stream>>>(adcols, W1, b1, W2, b2, field);
    k_gate<<<dim3(1), dim3(256), 0, stream>>>(field, gate);
    k_vtrans<<<dim3(32, 8), dim3(256), 0, stream>>>(vrow, vt);
    k_transpose<<<dim3(32, 32), dim3(256), 0, stream>>>(Wo, wot, 2048);
    k_attn<<<dim3(16, 32), dim3(256), 0, stream>>>(qbuf, kbuf, vt, gate, gs, attnout);
    k_gemm<<<dim3(16, 16), dim3(256), 0, stream>>>(attnout, wot, out, 2048, 2048, 2048);
}

// Round 13
// 212.107 us; speedup vs baseline: 1.8593x; 1.1304x over previous
//
#include <hip/hip_runtime.h>

#define S_LEN 2048
#define D_DIM 2048
#define NHEAD 32
#define NKVH  8
#define HDIM  64
#define NBT   3200   // 2048 q + 512 k + 512 v + 16 fiber + 64 w1h + 48 pad

typedef __attribute__((ext_vector_type(4))) float f32x4;
typedef __attribute__((ext_vector_type(8))) short bf16x8;

__device__ __forceinline__ unsigned short f2bf(float x) {
    union { float f; unsigned u; } v; v.f = x;
    unsigned r = v.u + 0x7FFFu + ((v.u >> 16) & 1u);
    return (unsigned short)(r >> 16);
}

// async global->LDS 16B: dest = wave-uniform base + lane*16
#define GLD(gsrc, ldst) __builtin_amdgcn_global_load_lds( \
    (const __attribute__((address_space(1))) unsigned int*)(const void*)(gsrc), \
    (__attribute__((address_space(3))) unsigned int*)(void*)(ldst), 16, 0, 0)

#define SWZ(r) (((r) & 7) << 4)

// k-permutation: QK^T C-layout (lane holds k=lg*4+r per 16-tile) -> PV B-frag
// consumption (k-pos = lg*8+e). bits [b5][b4][b3][b2][b1][b0] -> [b5][b3][b2][b4][b1][b0]
#define KPERM(kk) (((kk) & 32) | (((kk) & 12) << 1) | (((kk) & 16) >> 2) | ((kk) & 3))

// ---------------- h -> bf16 ----------------
__global__ void k_cvt_h(const float* __restrict__ h, unsigned short* __restrict__ hb) {
    int i = (blockIdx.x * 256 + threadIdx.x) * 4;
    float4 v = *(const float4*)(h + i);
    ushort4 o;
    o.x = f2bf(v.x); o.y = f2bf(v.y); o.z = f2bf(v.z); o.w = f2bf(v.w);
    *(ushort4*)(hb + i) = o;
}

// ------------- transpose W [2048][N] f32 -> WT [N][2048] bf16 -------------
__global__ void k_transpose(const float* __restrict__ W, unsigned short* __restrict__ WT, int N) {
    __shared__ unsigned short L[64][65];
    int k0 = blockIdx.x * 64, n0 = blockIdx.y * 64;
    int t = threadIdx.x;
    for (int it = 0; it < 16; ++it) {
        int e = it * 256 + t;
        int r = e >> 6, c = e & 63;
        L[c][r] = f2bf(W[(size_t)(k0 + r) * N + n0 + c]);
    }
    __syncthreads();
    for (int it = 0; it < 16; ++it) {
        int e = it * 256 + t;
        int n = e >> 6, kk = e & 63;
        WT[(size_t)(n0 + n) * 2048 + k0 + kk] = L[n][kk];
    }
}

// ------------- transpose Wf [2048][16] f32 -> WT [16][2048] bf16 -------------
__global__ void k_transpose16(const float* __restrict__ W, unsigned short* __restrict__ WT) {
    __shared__ unsigned short L[16][65];
    int k0 = blockIdx.x * 64;
    int t = threadIdx.x;
    for (int it = 0; it < 4; ++it) {
        int e = it * 256 + t;
        int r = e >> 4, c = e & 15;
        L[c][r] = f2bf(W[(size_t)(k0 + r) * 16 + c]);
    }
    __syncthreads();
    for (int it = 0; it < 4; ++it) {
        int e = it * 256 + t;
        int c = e >> 6, kk = e & 63;
        WT[(size_t)c * 2048 + k0 + kk] = L[c][kk];
    }
}

// ---- transpose vrow [S][512] bf16 -> vt [NKVH][64][S] bf16, KPERM k-permuted ----
__global__ void k_vtrans(const unsigned short* __restrict__ vrow, unsigned short* __restrict__ vt) {
    __shared__ unsigned short L[64][65];
    int s0 = blockIdx.x * 64, hk = blockIdx.y;
    int t = threadIdx.x;
    for (int it = 0; it < 16; ++it) {
        int e = it * 256 + t;
        int r = e >> 6, c = e & 63;
        L[c][r] = vrow[(size_t)(s0 + r) * 512 + hk * 64 + c];
    }
    __syncthreads();
    for (int it = 0; it < 16; ++it) {
        int e = it * 256 + t;
        int c = e >> 6, kk = e & 63;
        vt[((size_t)hk * 64 + c) * S_LEN + s0 + KPERM(kk)] = L[c][kk];
    }
}

// ---- fuse: field[s] from adapter cols (fiber 0..15, w1h 16..79 of adcols[S][128]) ----
__global__ __launch_bounds__(256) void k_fuse(const float* __restrict__ adcols,
                        const float* __restrict__ W1, const float* __restrict__ b1,
                        const float* __restrict__ W2, const float* __restrict__ b2,
                        float* __restrict__ field) {
    int wv = threadIdx.x >> 6, l = threadIdx.x & 63;
    int s = blockIdx.x * 4 + wv;
    const float* row = adcols + (size_t)s * 128;
    float x = row[16 + l] + b1[l];
#pragma unroll
    for (int f = 0; f < 16; ++f) x += row[f] * W1[(size_t)(2048 + f) * 64 + l];
    float hm = 0.5f * x * (1.f + erff(x * 0.70710678118654752f));
    float p = hm * W2[l];
    for (int m = 32; m; m >>= 1) p += __shfl_xor(p, m);
    if (l == 0) field[s] = 0.005f * (p + b2[0]);
}

// ---------------- gate = (field - mean)/(std_ddof1 + 1e-6) ----------------
__global__ void k_gate(const float* __restrict__ field, float* __restrict__ gate) {
    __shared__ float red[256];
    int t = threadIdx.x;
    float s = 0.f;
    for (int i = t; i < S_LEN; i += 256) s += field[i];
    red[t] = s; __syncthreads();
    for (int w = 128; w; w >>= 1) { if (t < w) red[t] += red[t + w]; __syncthreads(); }
    float mean = red[0] / (float)S_LEN;
    __syncthreads();
    float v = 0.f;
    for (int i = t; i < S_LEN; i += 256) { float d = field[i] - mean; v += d * d; }
    red[t] = v; __syncthreads();
    for (int w = 128; w; w >>= 1) { if (t < w) red[t] += red[t + w]; __syncthreads(); }
    float stdv = sqrtf(red[0] / (float)(S_LEN - 1)) + 1e-6f;
    for (int i = t; i < S_LEN; i += 256) gate[i] = (field[i] - mean) / stdv;
}

// ------- GEMM1: hb[2048][2048] x bt[3200][2048]^T with fused RoPE epilogue -------
__global__ __launch_bounds__(256) void k_gemm_qkv(const unsigned short* __restrict__ A,
                                                  const unsigned short* __restrict__ BT,
                                                  const float* __restrict__ cs,
                                                  const float* __restrict__ sn,
                                                  unsigned short* __restrict__ qb,
                                                  unsigned short* __restrict__ kbuf,
                                                  unsigned short* __restrict__ vrow,
                                                  float* __restrict__ adcols) {
    __shared__ __align__(16) char As[8192];
    __shared__ __align__(16) char Bs[8192];
    const int K = 2048;
    int flat = blockIdx.y * gridDim.x + blockIdx.x;
    int cpx = (gridDim.x * gridDim.y) >> 3;
    int swz = (flat & 7) * cpx + (flat >> 3);
    int m0 = (swz / gridDim.x) * 128, n0 = (swz % gridDim.x) * 128;
    int t = threadIdx.x;
    int wv = t >> 6, ln = t & 63;
    int wr = (wv >> 1) * 64, wc = (wv & 1) * 64;
    int lr = ln & 15, lkb = (ln >> 4) * 16;
    f32x4 acc[4][4] = {};
    const unsigned short* Ap = A + (size_t)(m0 + (t >> 2)) * K + (t & 3) * 8;
    const unsigned short* Bp = BT + (size_t)(n0 + (t >> 2)) * K + (t & 3) * 8;
    char* lA = As + wv * 1024;
    char* lB = Bs + wv * 1024;
    int nk = K / 32;
    GLD(Ap, lA); GLD(Ap + (size_t)64 * K, lA + 4096);
    GLD(Bp, lB); GLD(Bp + (size_t)64 * K, lB + 4096);
    for (int kt = 0; kt < nk; ++kt) {
        __syncthreads();
        bf16x8 af[4], bfv[4];
#pragma unroll
        for (int i = 0; i < 4; ++i) af[i]  = *(const bf16x8*)(As + (wr + i * 16 + lr) * 64 + lkb);
#pragma unroll
        for (int j = 0; j < 4; ++j) bfv[j] = *(const bf16x8*)(Bs + (wc + j * 16 + lr) * 64 + lkb);
#pragma unroll
        for (int i = 0; i < 4; ++i)
#pragma unroll
            for (int j = 0; j < 4; ++j)
                acc[i][j] = __builtin_amdgcn_mfma_f32_16x16x32_bf16(af[i], bfv[j], acc[i][j], 0, 0, 0);
        __syncthreads();
        if (kt + 1 < nk) {
            const unsigned short* Ak = Ap + (size_t)(kt + 1) * 32;
            const unsigned short* Bk = Bp + (size_t)(kt + 1) * 32;
            GLD(Ak, lA); GLD(Ak + (size_t)64 * K, lA + 4096);
            GLD(Bk, lB); GLD(Bk + (size_t)64 * K, lB + 4096);
        }
    }
    int orow = (ln >> 4) * 4;
    int col0 = n0 + wc;
    if (col0 < 2560) {
        bool isq = (col0 < 2048);
        unsigned short* dst = isq ? qb : kbuf;
        int hh = (isq ? col0 : col0 - 2048) >> 6;
        float qscale = isq ? 0.125f : 1.0f;
#pragma unroll
        for (int i = 0; i < 4; ++i)
#pragma unroll
            for (int r = 0; r < 4; ++r) {
                int s = m0 + wr + i * 16 + orow + r;
#pragma unroll
                for (int j = 0; j < 4; ++j) {
                    int d = j * 16 + lr;
                    float c = cs[s * 64 + d], si = sn[s * 64 + d];
                    float val = acc[i][j][r];
                    float prt = acc[i][j ^ 2][r];
                    float out = val * c + ((j < 2) ? -prt : prt) * si;
                    dst[((size_t)hh * S_LEN + s) * 64 + d] = f2bf(out * qscale);
                }
            }
    } else if (col0 < 3072) {
        int vc0 = col0 - 2560;
#pragma unroll
        for (int i = 0; i < 4; ++i)
#pragma unroll
            for (int j = 0; j < 4; ++j) {
                unsigned short* vp = vrow + (size_t)(m0 + wr + i * 16 + orow) * 512 + vc0 + j * 16 + lr;
                for (int r = 0; r < 4; ++r) vp[(size_t)r * 512] = f2bf(acc[i][j][r]);
            }
    } else {
        int ac0 = col0 - 3072;
#pragma unroll
        for (int i = 0; i < 4; ++i)
#pragma unroll
            for (int j = 0; j < 4; ++j) {
                float* ap = adcols + (size_t)(m0 + wr + i * 16 + orow) * 128 + ac0 + j * 16 + lr;
                for (int r = 0; r < 4; ++r) ap[(size_t)r * 128] = acc[i][j][r];
            }
    }
}

// ------- generic bf16 MFMA GEMM (m97 + XCD swizzle): C = A * BT^T -------
__global__ __launch_bounds__(256) void k_gemm(const unsigned short* __restrict__ A,
                                              const unsigned short* __restrict__ BT,
                                              float* __restrict__ C, int M, int N, int K) {
    __shared__ __align__(16) char As[8192];
    __shared__ __align__(16) char Bs[8192];
    int flat = blockIdx.y * gridDim.x + blockIdx.x;
    int cpx = (gridDim.x * gridDim.y) >> 3;
    int swz = (flat & 7) * cpx + (flat >> 3);
    int m0 = (swz / gridDim.x) * 128, n0 = (swz % gridDim.x) * 128;
    int t = threadIdx.x;
    int wv = t >> 6, ln = t & 63;
    int wr = (wv >> 1) * 64, wc = (wv & 1) * 64;
    int lr = ln & 15, lkb = (ln >> 4) * 16;
    f32x4 acc[4][4] = {};
    const unsigned short* Ap = A + (size_t)(m0 + (t >> 2)) * K + (t & 3) * 8;
    const unsigned short* Bp = BT + (size_t)(n0 + (t >> 2)) * K + (t & 3) * 8;
    char* lA = As + wv * 1024;
    char* lB = Bs + wv * 1024;
    int nk = K / 32;
    GLD(Ap, lA); GLD(Ap + (size_t)64 * K, lA + 4096);
    GLD(Bp, lB); GLD(Bp + (size_t)64 * K, lB + 4096);
    for (int kt = 0; kt < nk; ++kt) {
        __syncthreads();
        bf16x8 af[4], bfv[4];
#pragma unroll
        for (int i = 0; i < 4; ++i) af[i]  = *(const bf16x8*)(As + (wr + i * 16 + lr) * 64 + lkb);
#pragma unroll
        for (int j = 0; j < 4; ++j) bfv[j] = *(const bf16x8*)(Bs + (wc + j * 16 + lr) * 64 + lkb);
#pragma unroll
        for (int i = 0; i < 4; ++i)
#pragma unroll
            for (int j = 0; j < 4; ++j)
                acc[i][j] = __builtin_amdgcn_mfma_f32_16x16x32_bf16(af[i], bfv[j], acc[i][j], 0, 0, 0);
        __syncthreads();
        if (kt + 1 < nk) {
            const unsigned short* Ak = Ap + (size_t)(kt + 1) * 32;
            const unsigned short* Bk = Bp + (size_t)(kt + 1) * 32;
            GLD(Ak, lA); GLD(Ak + (size_t)64 * K, lA + 4096);
            GLD(Bk, lB); GLD(Bk + (size_t)64 * K, lB + 4096);
        }
    }
    int orow = (ln >> 4) * 4;
#pragma unroll
    for (int i = 0; i < 4; ++i)
#pragma unroll
        for (int j = 0; j < 4; ++j) {
            float* Cp = C + (size_t)(m0 + wr + i * 16 + orow) * N + n0 + wc + j * 16 + lr;
            for (int r = 0; r < 4; ++r) Cp[(size_t)r * N] = acc[i][j][r];
        }
}

__device__ __forceinline__ bf16x8 packP(const f32x4& a, const f32x4& b) {
    union { unsigned u[4]; bf16x8 v; } pk;
    asm("v_cvt_pk_bf16_f32 %0, %1, %2" : "=v"(pk.u[0]) : "v"(a[0]), "v"(a[1]));
    asm("v_cvt_pk_bf16_f32 %0, %1, %2" : "=v"(pk.u[1]) : "v"(a[2]), "v"(a[3]));
    asm("v_cvt_pk_bf16_f32 %0, %1, %2" : "=v"(pk.u[2]) : "v"(b[0]), "v"(b[1]));
    asm("v_cvt_pk_bf16_f32 %0, %1, %2" : "=v"(pk.u[3]) : "v"(b[2]), "v"(b[3]));
    return pk.v;
}

// ------- flash attention: swapped QK^T (C[k][q]) + fully in-register P.
//   All fragment layouts HW-validated by the R12-passing kernel:
//   A[m=l&15][k=lg*8+e], B[k=lg*8+e][n=l&15], D[m=lg*4+r][n=l&15], cvt_pk lo=src0.
//   mfma(bk, aq) -> lane owns q-col lq; k rows lg*4+r per 16-tile.
//   PV: O^T = mfma(V^T-as-A, packedP-as-B) with KPERM baked into vt.
//   4 waves x 32 q-rows, KVBLK=64, dbuf GLD staging, complementary qbi pairing. -------
__global__ __launch_bounds__(256, 2) void k_attn(const unsigned short* __restrict__ qb,
                                                 const unsigned short* __restrict__ kb,
                                                 const unsigned short* __restrict__ vt,
                                                 const float* __restrict__ gate,
                                                 const float* __restrict__ gs_p,
                                                 unsigned short* __restrict__ attnout) {
    __shared__ __align__(16) char Kl[2][8192];   // [buf][64 k rows x 128B], read-swizzled
    __shared__ __align__(16) char Vl[2][8192];   // [buf][64 d rows x 128B] (KPERM k-pos)
    int h = blockIdx.y, hk = h >> 2;
    int qbi = (h < 16) ? (15 - blockIdx.x) : blockIdx.x;   // complementary pairing
    int t = threadIdx.x, wv = t >> 6, l = t & 63;
    int lq = l & 15, lg = l >> 4;
    float gs = gs_p[0];
    int q0 = qbi * 128 + wv * 32;
    const unsigned short* qbase = qb + ((size_t)h * S_LEN + q0) * 64;
    bf16x8 aq[2][2];
#pragma unroll
    for (int qf = 0; qf < 2; ++qf)
#pragma unroll
        for (int hf = 0; hf < 2; ++hf)
            aq[qf][hf] = *(const bf16x8*)(qbase + (qf * 16 + lq) * 64 + hf * 32 + lg * 8);
    f32x4 o[2][4] = {};
    float m_[2] = { -INFINITY, -INFINITY };
    float ls_[2] = { 0.f, 0.f };
    int nkt = 2 * qbi + 2;
    int myKt = (q0 + 31) >> 6;
    int srow = t >> 3;
    int scol = 8 * ((t & 7) ^ (srow & 7));       // pre-swizzled source column (elems)
    const unsigned short* kg = kb + (size_t)hk * S_LEN * 64;
    const unsigned short* vg = vt + (size_t)hk * 64 * S_LEN;
    char* lKb0 = Kl[0] + wv * 1024; char* lKb1 = Kl[1] + wv * 1024;
    char* lVb0 = Vl[0] + wv * 1024; char* lVb1 = Vl[1] + wv * 1024;
    {   // stage kt=0
        GLD(kg + (size_t)srow * 64 + scol, lKb0);
        GLD(kg + (size_t)(32 + srow) * 64 + scol, lKb0 + 4096);
        GLD(vg + (size_t)srow * S_LEN + scol, lVb0);
        GLD(vg + (size_t)(32 + srow) * S_LEN + scol, lVb0 + 4096);
    }
    for (int kt = 0; kt < nkt; ++kt) {
        __syncthreads();   // buf[kt&1] staged; prior reads of buf[(kt+1)&1] done
        if (kt + 1 < nkt) {
            int k0n = (kt + 1) * 64;
            char* dK = ((kt + 1) & 1) ? lKb1 : lKb0;
            char* dV = ((kt + 1) & 1) ? lVb1 : lVb0;
            GLD(kg + (size_t)(k0n + srow) * 64 + scol, dK);
            GLD(kg + (size_t)(k0n + 32 + srow) * 64 + scol, dK + 4096);
            GLD(vg + (size_t)srow * S_LEN + k0n + scol, dV);
            GLD(vg + (size_t)(32 + srow) * S_LEN + k0n + scol, dV + 4096);
        }
        if (kt <= myKt) {
            int k0 = kt * 64;
            bool diag = (kt == myKt);
            const char* Kb = Kl[kt & 1];
            const char* Vb = Vl[kt & 1];
            // ---- QK^T swapped: sc[qf][ct] = S[k=ct*16+lg*4+r][q=lq] ----
            f32x4 sc[2][4] = {};
#pragma unroll
            for (int ct = 0; ct < 4; ++ct) {
                int krow = ct * 16 + lq;
#pragma unroll
                for (int hf = 0; hf < 2; ++hf) {
                    bf16x8 bk = *(const bf16x8*)(Kb + krow * 128 + ((hf * 64 + lg * 16) ^ SWZ(krow)));
#pragma unroll
                    for (int qf = 0; qf < 2; ++qf)
                        sc[qf][ct] = __builtin_amdgcn_mfma_f32_16x16x32_bf16(bk, aq[qf][hf], sc[qf][ct], 0, 0, 0);
                }
            }
            // ---- gate bias + mask + per-lane max ----
            float vmax[2] = { -INFINITY, -INFINITY };
#pragma unroll
            for (int ct = 0; ct < 4; ++ct) {
                f32x4 g4 = *(const f32x4*)(gate + k0 + ct * 16 + lg * 4);
#pragma unroll
                for (int qf = 0; qf < 2; ++qf) {
                    int q = q0 + qf * 16 + lq;
#pragma unroll
                    for (int r = 0; r < 4; ++r) {
                        float val = sc[qf][ct][r] + gs * g4[r];
                        if (diag && (k0 + ct * 16 + lg * 4 + r > q)) val = -1e9f;
                        sc[qf][ct][r] = val;
                        vmax[qf] = fmaxf(vmax[qf], val);
                    }
                }
            }
#pragma unroll
            for (int qf = 0; qf < 2; ++qf) {
                vmax[qf] = fmaxf(vmax[qf], __shfl_xor(vmax[qf], 16));
                vmax[qf] = fmaxf(vmax[qf], __shfl_xor(vmax[qf], 32));
            }
            bool cond = (vmax[0] <= m_[0] + 8.f) && (vmax[1] <= m_[1] + 8.f);
            if (!__all(cond)) {   // rescale (rare after first tiles)
#pragma unroll
                for (int qf = 0; qf < 2; ++qf) {
                    float mn = fmaxf(m_[qf], vmax[qf]);
                    float scl = __expf(m_[qf] - mn);
                    ls_[qf] *= scl;
#pragma unroll
                    for (int dt = 0; dt < 4; ++dt) o[qf][dt] *= scl;
                    m_[qf] = mn;
                }
            }
#pragma unroll
            for (int qf = 0; qf < 2; ++qf)
#pragma unroll
                for (int ct = 0; ct < 4; ++ct)
#pragma unroll
                    for (int r = 0; r < 4; ++r) {
                        float p = __expf(sc[qf][ct][r] - m_[qf]);
                        sc[qf][ct][r] = p;
                        ls_[qf] += p;
                    }
            // ---- PV: O^T[d][q] += V^T-as-A x packedP-as-B ----
#pragma unroll
            for (int ks = 0; ks < 2; ++ks) {
                bf16x8 pf0 = packP(sc[0][2 * ks], sc[0][2 * ks + 1]);
                bf16x8 pf1 = packP(sc[1][2 * ks], sc[1][2 * ks + 1]);
#pragma unroll
                for (int dt = 0; dt < 4; ++dt) {
                    int vr = dt * 16 + lq;
                    bf16x8 bv = *(const bf16x8*)(Vb + vr * 128 + ((ks * 64 + lg * 16) ^ SWZ(vr)));
                    o[0][dt] = __builtin_amdgcn_mfma_f32_16x16x32_bf16(bv, pf0, o[0][dt], 0, 0, 0);
                    o[1][dt] = __builtin_amdgcn_mfma_f32_16x16x32_bf16(bv, pf1, o[1][dt], 0, 0, 0);
                }
            }
        }
    }
    // epilogue: O[q][d] = O^T/ls; ls reduced across lg-groups (2 shfl per qf)
#pragma unroll
    for (int qf = 0; qf < 2; ++qf) {
        float s = ls_[qf];
        s += __shfl_xor(s, 16);
        s += __shfl_xor(s, 32);
        float inv = 1.f / s;
        int q = q0 + qf * 16 + lq;
        unsigned short* orow = attnout + (size_t)q * 2048 + h * 64;
#pragma unroll
        for (int dt = 0; dt < 4; ++dt) {
            ushort4 st;
            st.x = f2bf(o[qf][dt][0] * inv); st.y = f2bf(o[qf][dt][1] * inv);
            st.z = f2bf(o[qf][dt][2] * inv); st.w = f2bf(o[qf][dt][3] * inv);
            *(ushort4*)(orow + dt * 16 + lg * 4) = st;
        }
    }
}

extern "C" void kernel_launch(void* const* d_in, const int* in_sizes, int n_in,
                              void* d_out, int out_size, void* d_ws, size_t ws_size,
                              hipStream_t stream) {
    const float* h    = (const float*)d_in[0];
    const float* cosT = (const float*)d_in[2];
    const float* sinT = (const float*)d_in[3];
    const float* Wf   = (const float*)d_in[4];
    const float* W1   = (const float*)d_in[5];
    const float* b1   = (const float*)d_in[6];
    const float* W2   = (const float*)d_in[7];
    const float* b2   = (const float*)d_in[8];
    const float* gs   = (const float*)d_in[9];
    const float* Wq   = (const float*)d_in[10];
    const float* Wk   = (const float*)d_in[11];
    const float* Wv   = (const float*)d_in[12];
    const float* Wo   = (const float*)d_in[13];
    float* out = (float*)d_out;

    char* ws = (char*)d_ws;
    unsigned short* hb     = (unsigned short*)(ws);                // 0..8M        [dead after gemm1]
    unsigned short* bt     = (unsigned short*)(ws + 8388608);      // 8M..21.5M    [dead after gemm1]
    unsigned short* qbuf   = (unsigned short*)(ws + 21495808);     // 8M
    unsigned short* kbuf   = (unsigned short*)(ws + 29884416);     // 2M
    unsigned short* vrow   = (unsigned short*)(ws + 31981568);     // 2M
    float*          adcols = (float*)(ws + 34078720);              // 1M
    float*          field  = (float*)(ws + 35127296);              // 8K
    float*          gate   = (float*)(ws + 35135488);              // 8K
    unsigned short* wot     = (unsigned short*)(ws + 8388608);     // 8M over bt
    unsigned short* vt      = (unsigned short*)(ws + 16777216);    // 2M over bt tail
    unsigned short* attnout = (unsigned short*)(ws);               // 8M over hb

    k_cvt_h<<<dim3(4096), dim3(256), 0, stream>>>(h, hb);
    k_transpose<<<dim3(32, 32), dim3(256), 0, stream>>>(Wq, bt, 2048);
    k_transpose<<<dim3(32, 8),  dim3(256), 0, stream>>>(Wk, bt + (size_t)2048 * 2048, 512);
    k_transpose<<<dim3(32, 8),  dim3(256), 0, stream>>>(Wv, bt + (size_t)2560 * 2048, 512);
    k_transpose16<<<dim3(32), dim3(256), 0, stream>>>(Wf, bt + (size_t)3072 * 2048);
    k_transpose<<<dim3(32, 1),  dim3(256), 0, stream>>>(W1, bt + (size_t)3088 * 2048, 64);
    hipMemsetAsync(ws + 8388608 + (size_t)3152 * 4096, 0, (size_t)48 * 4096, stream);
    k_gemm_qkv<<<dim3(25, 16), dim3(256), 0, stream>>>(hb, bt, cosT, sinT, qbuf, kbuf, vrow, adcols);
    k_fuse<<<dim3(512), dim3(256), 0, stream>>>(adcols, W1, b1, W2, b2, field);
    k_gate<<<dim3(1), dim3(256), 0, stream>>>(field, gate);
    k_vtrans<<<dim3(32, 8), dim3(256), 0, stream>>>(vrow, vt);
    k_transpose<<<dim3(32, 32), dim3(256), 0, stream>>>(Wo, wot, 2048);
    k_attn<<<dim3(16, 32), dim3(256), 0, stream>>>(qbuf, kbuf, vt, gate, gs, attnout);
    k_gemm<<<dim3(16, 16), dim3(256), 0, stream>>>(attnout, wot, out, 2048, 2048, 2048);
}

// Round 14
// 195.056 us; speedup vs baseline: 2.0218x; 1.0874x over previous
//
#include <hip/hip_runtime.h>

#define S_LEN 2048
#define D_DIM 2048
#define NHEAD 32
#define NKVH  8
#define HDIM  64
#define NBT   3200   // 2048 q + 512 k + 512 v + 16 fiber + 64 w1h + 48 pad

typedef __attribute__((ext_vector_type(4))) float f32x4;
typedef __attribute__((ext_vector_type(8))) short bf16x8;

__device__ __forceinline__ unsigned short f2bf(float x) {
    union { float f; unsigned u; } v; v.f = x;
    unsigned r = v.u + 0x7FFFu + ((v.u >> 16) & 1u);
    return (unsigned short)(r >> 16);
}

// async global->LDS 16B: dest = wave-uniform base + lane*16
#define GLD(gsrc, ldst) __builtin_amdgcn_global_load_lds( \
    (const __attribute__((address_space(1))) unsigned int*)(const void*)(gsrc), \
    (__attribute__((address_space(3))) unsigned int*)(void*)(ldst), 16, 0, 0)

#define SWZ(r) (((r) & 7) << 4)

// k-permutation: QK^T C-layout (lane holds k=lg*4+r per 16-tile) -> PV B-frag
// consumption (k-pos = lg*8+e). bits [b5][b4][b3][b2][b1][b0] -> [b5][b3][b2][b4][b1][b0]
#define KPERM(kk) (((kk) & 32) | (((kk) & 12) << 1) | (((kk) & 16) >> 2) | ((kk) & 3))

// ---------------- h -> bf16 ----------------
__global__ void k_cvt_h(const float* __restrict__ h, unsigned short* __restrict__ hb) {
    int i = (blockIdx.x * 256 + threadIdx.x) * 4;
    float4 v = *(const float4*)(h + i);
    ushort4 o;
    o.x = f2bf(v.x); o.y = f2bf(v.y); o.z = f2bf(v.z); o.w = f2bf(v.w);
    *(ushort4*)(hb + i) = o;
}

// ------------- transpose W [2048][N] f32 -> WT [N][2048] bf16 -------------
__global__ void k_transpose(const float* __restrict__ W, unsigned short* __restrict__ WT, int N) {
    __shared__ unsigned short L[64][65];
    int k0 = blockIdx.x * 64, n0 = blockIdx.y * 64;
    int t = threadIdx.x;
    for (int it = 0; it < 16; ++it) {
        int e = it * 256 + t;
        int r = e >> 6, c = e & 63;
        L[c][r] = f2bf(W[(size_t)(k0 + r) * N + n0 + c]);
    }
    __syncthreads();
    for (int it = 0; it < 16; ++it) {
        int e = it * 256 + t;
        int n = e >> 6, kk = e & 63;
        WT[(size_t)(n0 + n) * 2048 + k0 + kk] = L[n][kk];
    }
}

// ------------- transpose Wf [2048][16] f32 -> WT [16][2048] bf16 -------------
__global__ void k_transpose16(const float* __restrict__ W, unsigned short* __restrict__ WT) {
    __shared__ unsigned short L[16][65];
    int k0 = blockIdx.x * 64;
    int t = threadIdx.x;
    for (int it = 0; it < 4; ++it) {
        int e = it * 256 + t;
        int r = e >> 4, c = e & 15;
        L[c][r] = f2bf(W[(size_t)(k0 + r) * 16 + c]);
    }
    __syncthreads();
    for (int it = 0; it < 4; ++it) {
        int e = it * 256 + t;
        int c = e >> 6, kk = e & 63;
        WT[(size_t)c * 2048 + k0 + kk] = L[c][kk];
    }
}

// ---- transpose vrow [S][512] bf16 -> vt [NKVH][64][S] bf16, KPERM k-permuted ----
__global__ void k_vtrans(const unsigned short* __restrict__ vrow, unsigned short* __restrict__ vt) {
    __shared__ unsigned short L[64][65];
    int s0 = blockIdx.x * 64, hk = blockIdx.y;
    int t = threadIdx.x;
    for (int it = 0; it < 16; ++it) {
        int e = it * 256 + t;
        int r = e >> 6, c = e & 63;
        L[c][r] = vrow[(size_t)(s0 + r) * 512 + hk * 64 + c];
    }
    __syncthreads();
    for (int it = 0; it < 16; ++it) {
        int e = it * 256 + t;
        int c = e >> 6, kk = e & 63;
        vt[((size_t)hk * 64 + c) * S_LEN + s0 + KPERM(kk)] = L[c][kk];
    }
}

// ---- fuse: field[s] from adapter cols (fiber 0..15, w1h 16..79 of adcols[S][128]) ----
__global__ __launch_bounds__(256) void k_fuse(const float* __restrict__ adcols,
                        const float* __restrict__ W1, const float* __restrict__ b1,
                        const float* __restrict__ W2, const float* __restrict__ b2,
                        float* __restrict__ field) {
    int wv = threadIdx.x >> 6, l = threadIdx.x & 63;
    int s = blockIdx.x * 4 + wv;
    const float* row = adcols + (size_t)s * 128;
    float x = row[16 + l] + b1[l];
#pragma unroll
    for (int f = 0; f < 16; ++f) x += row[f] * W1[(size_t)(2048 + f) * 64 + l];
    float hm = 0.5f * x * (1.f + erff(x * 0.70710678118654752f));
    float p = hm * W2[l];
    for (int m = 32; m; m >>= 1) p += __shfl_xor(p, m);
    if (l == 0) field[s] = 0.005f * (p + b2[0]);
}

// ---------------- gate = (field - mean)/(std_ddof1 + 1e-6) ----------------
__global__ void k_gate(const float* __restrict__ field, float* __restrict__ gate) {
    __shared__ float red[256];
    int t = threadIdx.x;
    float s = 0.f;
    for (int i = t; i < S_LEN; i += 256) s += field[i];
    red[t] = s; __syncthreads();
    for (int w = 128; w; w >>= 1) { if (t < w) red[t] += red[t + w]; __syncthreads(); }
    float mean = red[0] / (float)S_LEN;
    __syncthreads();
    float v = 0.f;
    for (int i = t; i < S_LEN; i += 256) { float d = field[i] - mean; v += d * d; }
    red[t] = v; __syncthreads();
    for (int w = 128; w; w >>= 1) { if (t < w) red[t] += red[t + w]; __syncthreads(); }
    float stdv = sqrtf(red[0] / (float)(S_LEN - 1)) + 1e-6f;
    for (int i = t; i < S_LEN; i += 256) gate[i] = (field[i] - mean) / stdv;
}

// ------- GEMM1: hb[2048][2048] x bt[3200][2048]^T with fused RoPE epilogue -------
__global__ __launch_bounds__(256) void k_gemm_qkv(const unsigned short* __restrict__ A,
                                                  const unsigned short* __restrict__ BT,
                                                  const float* __restrict__ cs,
                                                  const float* __restrict__ sn,
                                                  unsigned short* __restrict__ qb,
                                                  unsigned short* __restrict__ kbuf,
                                                  unsigned short* __restrict__ vrow,
                                                  float* __restrict__ adcols) {
    __shared__ __align__(16) char As[8192];
    __shared__ __align__(16) char Bs[8192];
    const int K = 2048;
    int flat = blockIdx.y * gridDim.x + blockIdx.x;
    int cpx = (gridDim.x * gridDim.y) >> 3;
    int swz = (flat & 7) * cpx + (flat >> 3);
    int m0 = (swz / gridDim.x) * 128, n0 = (swz % gridDim.x) * 128;
    int t = threadIdx.x;
    int wv = t >> 6, ln = t & 63;
    int wr = (wv >> 1) * 64, wc = (wv & 1) * 64;
    int lr = ln & 15, lkb = (ln >> 4) * 16;
    f32x4 acc[4][4] = {};
    const unsigned short* Ap = A + (size_t)(m0 + (t >> 2)) * K + (t & 3) * 8;
    const unsigned short* Bp = BT + (size_t)(n0 + (t >> 2)) * K + (t & 3) * 8;
    char* lA = As + wv * 1024;
    char* lB = Bs + wv * 1024;
    int nk = K / 32;
    GLD(Ap, lA); GLD(Ap + (size_t)64 * K, lA + 4096);
    GLD(Bp, lB); GLD(Bp + (size_t)64 * K, lB + 4096);
    for (int kt = 0; kt < nk; ++kt) {
        __syncthreads();
        bf16x8 af[4], bfv[4];
#pragma unroll
        for (int i = 0; i < 4; ++i) af[i]  = *(const bf16x8*)(As + (wr + i * 16 + lr) * 64 + lkb);
#pragma unroll
        for (int j = 0; j < 4; ++j) bfv[j] = *(const bf16x8*)(Bs + (wc + j * 16 + lr) * 64 + lkb);
#pragma unroll
        for (int i = 0; i < 4; ++i)
#pragma unroll
            for (int j = 0; j < 4; ++j)
                acc[i][j] = __builtin_amdgcn_mfma_f32_16x16x32_bf16(af[i], bfv[j], acc[i][j], 0, 0, 0);
        __syncthreads();
        if (kt + 1 < nk) {
            const unsigned short* Ak = Ap + (size_t)(kt + 1) * 32;
            const unsigned short* Bk = Bp + (size_t)(kt + 1) * 32;
            GLD(Ak, lA); GLD(Ak + (size_t)64 * K, lA + 4096);
            GLD(Bk, lB); GLD(Bk + (size_t)64 * K, lB + 4096);
        }
    }
    int orow = (ln >> 4) * 4;
    int col0 = n0 + wc;
    if (col0 < 2560) {
        bool isq = (col0 < 2048);
        unsigned short* dst = isq ? qb : kbuf;
        int hh = (isq ? col0 : col0 - 2048) >> 6;
        float qscale = isq ? 0.125f : 1.0f;
#pragma unroll
        for (int i = 0; i < 4; ++i)
#pragma unroll
            for (int r = 0; r < 4; ++r) {
                int s = m0 + wr + i * 16 + orow + r;
#pragma unroll
                for (int j = 0; j < 4; ++j) {
                    int d = j * 16 + lr;
                    float c = cs[s * 64 + d], si = sn[s * 64 + d];
                    float val = acc[i][j][r];
                    float prt = acc[i][j ^ 2][r];
                    float out = val * c + ((j < 2) ? -prt : prt) * si;
                    dst[((size_t)hh * S_LEN + s) * 64 + d] = f2bf(out * qscale);
                }
            }
    } else if (col0 < 3072) {
        int vc0 = col0 - 2560;
#pragma unroll
        for (int i = 0; i < 4; ++i)
#pragma unroll
            for (int j = 0; j < 4; ++j) {
                unsigned short* vp = vrow + (size_t)(m0 + wr + i * 16 + orow) * 512 + vc0 + j * 16 + lr;
                for (int r = 0; r < 4; ++r) vp[(size_t)r * 512] = f2bf(acc[i][j][r]);
            }
    } else {
        int ac0 = col0 - 3072;
#pragma unroll
        for (int i = 0; i < 4; ++i)
#pragma unroll
            for (int j = 0; j < 4; ++j) {
                float* ap = adcols + (size_t)(m0 + wr + i * 16 + orow) * 128 + ac0 + j * 16 + lr;
                for (int r = 0; r < 4; ++r) ap[(size_t)r * 128] = acc[i][j][r];
            }
    }
}

// ------- generic bf16 MFMA GEMM (m97 + XCD swizzle): C = A * BT^T -------
__global__ __launch_bounds__(256) void k_gemm(const unsigned short* __restrict__ A,
                                              const unsigned short* __restrict__ BT,
                                              float* __restrict__ C, int M, int N, int K) {
    __shared__ __align__(16) char As[8192];
    __shared__ __align__(16) char Bs[8192];
    int flat = blockIdx.y * gridDim.x + blockIdx.x;
    int cpx = (gridDim.x * gridDim.y) >> 3;
    int swz = (flat & 7) * cpx + (flat >> 3);
    int m0 = (swz / gridDim.x) * 128, n0 = (swz % gridDim.x) * 128;
    int t = threadIdx.x;
    int wv = t >> 6, ln = t & 63;
    int wr = (wv >> 1) * 64, wc = (wv & 1) * 64;
    int lr = ln & 15, lkb = (ln >> 4) * 16;
    f32x4 acc[4][4] = {};
    const unsigned short* Ap = A + (size_t)(m0 + (t >> 2)) * K + (t & 3) * 8;
    const unsigned short* Bp = BT + (size_t)(n0 + (t >> 2)) * K + (t & 3) * 8;
    char* lA = As + wv * 1024;
    char* lB = Bs + wv * 1024;
    int nk = K / 32;
    GLD(Ap, lA); GLD(Ap + (size_t)64 * K, lA + 4096);
    GLD(Bp, lB); GLD(Bp + (size_t)64 * K, lB + 4096);
    for (int kt = 0; kt < nk; ++kt) {
        __syncthreads();
        bf16x8 af[4], bfv[4];
#pragma unroll
        for (int i = 0; i < 4; ++i) af[i]  = *(const bf16x8*)(As + (wr + i * 16 + lr) * 64 + lkb);
#pragma unroll
        for (int j = 0; j < 4; ++j) bfv[j] = *(const bf16x8*)(Bs + (wc + j * 16 + lr) * 64 + lkb);
#pragma unroll
        for (int i = 0; i < 4; ++i)
#pragma unroll
            for (int j = 0; j < 4; ++j)
                acc[i][j] = __builtin_amdgcn_mfma_f32_16x16x32_bf16(af[i], bfv[j], acc[i][j], 0, 0, 0);
        __syncthreads();
        if (kt + 1 < nk) {
            const unsigned short* Ak = Ap + (size_t)(kt + 1) * 32;
            const unsigned short* Bk = Bp + (size_t)(kt + 1) * 32;
            GLD(Ak, lA); GLD(Ak + (size_t)64 * K, lA + 4096);
            GLD(Bk, lB); GLD(Bk + (size_t)64 * K, lB + 4096);
        }
    }
    int orow = (ln >> 4) * 4;
#pragma unroll
    for (int i = 0; i < 4; ++i)
#pragma unroll
        for (int j = 0; j < 4; ++j) {
            float* Cp = C + (size_t)(m0 + wr + i * 16 + orow) * N + n0 + wc + j * 16 + lr;
            for (int r = 0; r < 4; ++r) Cp[(size_t)r * N] = acc[i][j][r];
        }
}

__device__ __forceinline__ bf16x8 packP(const f32x4& a, const f32x4& b) {
    union { unsigned u[4]; bf16x8 v; } pk;
    asm("v_cvt_pk_bf16_f32 %0, %1, %2" : "=v"(pk.u[0]) : "v"(a[0]), "v"(a[1]));
    asm("v_cvt_pk_bf16_f32 %0, %1, %2" : "=v"(pk.u[1]) : "v"(a[2]), "v"(a[3]));
    asm("v_cvt_pk_bf16_f32 %0, %1, %2" : "=v"(pk.u[2]) : "v"(b[0]), "v"(b[1]));
    asm("v_cvt_pk_bf16_f32 %0, %1, %2" : "=v"(pk.u[3]) : "v"(b[2]), "v"(b[3]));
    return pk.v;
}

// ------- flash attention: swapped QK^T + in-register P (R13-proven math).
//   R14 change (ONLY): 2-wave blocks (64 q-rows), grid 32x32 = 1024 blocks
//   -> 4 independent blocks/CU (was 2), 2-wave barrier groups (was 4).
//   Pairing: same-CU residues get heads {y0,y0+8,y0+16,y0+24} (two <16, two >=16),
//   qt = (h<16) ? 31-x : x  ->  per-CU work = 2(32-x)+2(x+1) = 66 const. -------
__global__ __launch_bounds__(128, 2) void k_attn(const unsigned short* __restrict__ qb,
                                                 const unsigned short* __restrict__ kb,
                                                 const unsigned short* __restrict__ vt,
                                                 const float* __restrict__ gate,
                                                 const float* __restrict__ gs_p,
                                                 unsigned short* __restrict__ attnout) {
    __shared__ __align__(16) char Kl[2][8192];   // [buf][64 k rows x 128B], read-swizzled
    __shared__ __align__(16) char Vl[2][8192];   // [buf][64 d rows x 128B] (KPERM k-pos)
    int h = blockIdx.y, hk = h >> 2;
    int qt = (h < 16) ? (31 - blockIdx.x) : blockIdx.x;
    int t = threadIdx.x, wv = t >> 6, l = t & 63;
    int lq = l & 15, lg = l >> 4;
    float gs = gs_p[0];
    int q0 = qt * 64 + wv * 32;
    const unsigned short* qbase = qb + ((size_t)h * S_LEN + q0) * 64;
    bf16x8 aq[2][2];
#pragma unroll
    for (int qf = 0; qf < 2; ++qf)
#pragma unroll
        for (int hf = 0; hf < 2; ++hf)
            aq[qf][hf] = *(const bf16x8*)(qbase + (qf * 16 + lq) * 64 + hf * 32 + lg * 8);
    f32x4 o[2][4] = {};
    float m_[2] = { -INFINITY, -INFINITY };
    float ls_[2] = { 0.f, 0.f };
    int nkt = qt + 1;                            // both waves' diag tile is nkt-1
    int srow = t >> 3;                           // 0..15
    int scol = 8 * ((t & 7) ^ (srow & 7));       // pre-swizzled source column (elems)
    const unsigned short* kg = kb + (size_t)hk * S_LEN * 64;
    const unsigned short* vg = vt + (size_t)hk * 64 * S_LEN;
    char* lKb0 = Kl[0] + wv * 1024; char* lKb1 = Kl[1] + wv * 1024;
    char* lVb0 = Vl[0] + wv * 1024; char* lVb1 = Vl[1] + wv * 1024;
    // stage: 128 threads x 4 GLDs per operand; rows srow + {0,16,32,48}
    // (row+16 keeps (row&7) -> swizzle consistent with SWZ reads)
#define STAGE_KV(K0, DK, DV) do { \
        GLD(kg + (size_t)((K0) + srow) * 64 + scol, (DK)); \
        GLD(kg + (size_t)((K0) + 16 + srow) * 64 + scol, (DK) + 2048); \
        GLD(kg + (size_t)((K0) + 32 + srow) * 64 + scol, (DK) + 4096); \
        GLD(kg + (size_t)((K0) + 48 + srow) * 64 + scol, (DK) + 6144); \
        GLD(vg + (size_t)srow * S_LEN + (K0) + scol, (DV)); \
        GLD(vg + (size_t)(16 + srow) * S_LEN + (K0) + scol, (DV) + 2048); \
        GLD(vg + (size_t)(32 + srow) * S_LEN + (K0) + scol, (DV) + 4096); \
        GLD(vg + (size_t)(48 + srow) * S_LEN + (K0) + scol, (DV) + 6144); \
    } while (0)
    STAGE_KV(0, lKb0, lVb0);
    for (int kt = 0; kt < nkt; ++kt) {
        __syncthreads();   // buf[kt&1] staged; prior reads of buf[(kt+1)&1] done
        if (kt + 1 < nkt) {
            int k0n = (kt + 1) * 64;
            char* dK = ((kt + 1) & 1) ? lKb1 : lKb0;
            char* dV = ((kt + 1) & 1) ? lVb1 : lVb0;
            STAGE_KV(k0n, dK, dV);
        }
        int k0 = kt * 64;
        bool diag = (kt == nkt - 1);
        const char* Kb = Kl[kt & 1];
        const char* Vb = Vl[kt & 1];
        // ---- QK^T swapped: sc[qf][ct] = S[k=ct*16+lg*4+r][q=lq] ----
        f32x4 sc[2][4] = {};
#pragma unroll
        for (int ct = 0; ct < 4; ++ct) {
            int krow = ct * 16 + lq;
#pragma unroll
            for (int hf = 0; hf < 2; ++hf) {
                bf16x8 bk = *(const bf16x8*)(Kb + krow * 128 + ((hf * 64 + lg * 16) ^ SWZ(krow)));
#pragma unroll
                for (int qf = 0; qf < 2; ++qf)
                    sc[qf][ct] = __builtin_amdgcn_mfma_f32_16x16x32_bf16(bk, aq[qf][hf], sc[qf][ct], 0, 0, 0);
            }
        }
        // ---- gate bias + mask + per-lane max ----
        float vmax[2] = { -INFINITY, -INFINITY };
#pragma unroll
        for (int ct = 0; ct < 4; ++ct) {
            f32x4 g4 = *(const f32x4*)(gate + k0 + ct * 16 + lg * 4);
#pragma unroll
            for (int qf = 0; qf < 2; ++qf) {
                int q = q0 + qf * 16 + lq;
#pragma unroll
                for (int r = 0; r < 4; ++r) {
                    float val = sc[qf][ct][r] + gs * g4[r];
                    if (diag && (k0 + ct * 16 + lg * 4 + r > q)) val = -1e9f;
                    sc[qf][ct][r] = val;
                    vmax[qf] = fmaxf(vmax[qf], val);
                }
            }
        }
#pragma unroll
        for (int qf = 0; qf < 2; ++qf) {
            vmax[qf] = fmaxf(vmax[qf], __shfl_xor(vmax[qf], 16));
            vmax[qf] = fmaxf(vmax[qf], __shfl_xor(vmax[qf], 32));
        }
        bool cond = (vmax[0] <= m_[0] + 8.f) && (vmax[1] <= m_[1] + 8.f);
        if (!__all(cond)) {   // rescale (rare after first tiles)
#pragma unroll
            for (int qf = 0; qf < 2; ++qf) {
                float mn = fmaxf(m_[qf], vmax[qf]);
                float scl = __expf(m_[qf] - mn);
                ls_[qf] *= scl;
#pragma unroll
                for (int dt = 0; dt < 4; ++dt) o[qf][dt] *= scl;
                m_[qf] = mn;
            }
        }
#pragma unroll
        for (int qf = 0; qf < 2; ++qf)
#pragma unroll
            for (int ct = 0; ct < 4; ++ct)
#pragma unroll
                for (int r = 0; r < 4; ++r) {
                    float p = __expf(sc[qf][ct][r] - m_[qf]);
                    sc[qf][ct][r] = p;
                    ls_[qf] += p;
                }
        // ---- PV: O^T[d][q] += V^T-as-A x packedP-as-B ----
#pragma unroll
        for (int ks = 0; ks < 2; ++ks) {
            bf16x8 pf0 = packP(sc[0][2 * ks], sc[0][2 * ks + 1]);
            bf16x8 pf1 = packP(sc[1][2 * ks], sc[1][2 * ks + 1]);
#pragma unroll
            for (int dt = 0; dt < 4; ++dt) {
                int vr = dt * 16 + lq;
                bf16x8 bv = *(const bf16x8*)(Vb + vr * 128 + ((ks * 64 + lg * 16) ^ SWZ(vr)));
                o[0][dt] = __builtin_amdgcn_mfma_f32_16x16x32_bf16(bv, pf0, o[0][dt], 0, 0, 0);
                o[1][dt] = __builtin_amdgcn_mfma_f32_16x16x32_bf16(bv, pf1, o[1][dt], 0, 0, 0);
            }
        }
    }
#undef STAGE_KV
    // epilogue: O[q][d] = O^T/ls; ls reduced across lg-groups (2 shfl per qf)
#pragma unroll
    for (int qf = 0; qf < 2; ++qf) {
        float s = ls_[qf];
        s += __shfl_xor(s, 16);
        s += __shfl_xor(s, 32);
        float inv = 1.f / s;
        int q = q0 + qf * 16 + lq;
        unsigned short* orow = attnout + (size_t)q * 2048 + h * 64;
#pragma unroll
        for (int dt = 0; dt < 4; ++dt) {
            ushort4 st;
            st.x = f2bf(o[qf][dt][0] * inv); st.y = f2bf(o[qf][dt][1] * inv);
            st.z = f2bf(o[qf][dt][2] * inv); st.w = f2bf(o[qf][dt][3] * inv);
            *(ushort4*)(orow + dt * 16 + lg * 4) = st;
        }
    }
}

extern "C" void kernel_launch(void* const* d_in, const int* in_sizes, int n_in,
                              void* d_out, int out_size, void* d_ws, size_t ws_size,
                              hipStream_t stream) {
    const float* h    = (const float*)d_in[0];
    const float* cosT = (const float*)d_in[2];
    const float* sinT = (const float*)d_in[3];
    const float* Wf   = (const float*)d_in[4];
    const float* W1   = (const float*)d_in[5];
    const float* b1   = (const float*)d_in[6];
    const float* W2   = (const float*)d_in[7];
    const float* b2   = (const float*)d_in[8];
    const float* gs   = (const float*)d_in[9];
    const float* Wq   = (const float*)d_in[10];
    const float* Wk   = (const float*)d_in[11];
    const float* Wv   = (const float*)d_in[12];
    const float* Wo   = (const float*)d_in[13];
    float* out = (float*)d_out;

    char* ws = (char*)d_ws;
    unsigned short* hb     = (unsigned short*)(ws);                // 0..8M        [dead after gemm1]
    unsigned short* bt     = (unsigned short*)(ws + 8388608);      // 8M..21.5M    [dead after gemm1]
    unsigned short* qbuf   = (unsigned short*)(ws + 21495808);     // 8M
    unsigned short* kbuf   = (unsigned short*)(ws + 29884416);     // 2M
    unsigned short* vrow   = (unsigned short*)(ws + 31981568);     // 2M
    float*          adcols = (float*)(ws + 34078720);              // 1M
    float*          field  = (float*)(ws + 35127296);              // 8K
    float*          gate   = (float*)(ws + 35135488);              // 8K
    unsigned short* wot     = (unsigned short*)(ws + 8388608);     // 8M over bt
    unsigned short* vt      = (unsigned short*)(ws + 16777216);    // 2M over bt tail
    unsigned short* attnout = (unsigned short*)(ws);               // 8M over hb

    k_cvt_h<<<dim3(4096), dim3(256), 0, stream>>>(h, hb);
    k_transpose<<<dim3(32, 32), dim3(256), 0, stream>>>(Wq, bt, 2048);
    k_transpose<<<dim3(32, 8),  dim3(256), 0, stream>>>(Wk, bt + (size_t)2048 * 2048, 512);
    k_transpose<<<dim3(32, 8),  dim3(256), 0, stream>>>(Wv, bt + (size_t)2560 * 2048, 512);
    k_transpose16<<<dim3(32), dim3(256), 0, stream>>>(Wf, bt + (size_t)3072 * 2048);
    k_transpose<<<dim3(32, 1),  dim3(256), 0, stream>>>(W1, bt + (size_t)3088 * 2048, 64);
    hipMemsetAsync(ws + 8388608 + (size_t)3152 * 4096, 0, (size_t)48 * 4096, stream);
    k_gemm_qkv<<<dim3(25, 16), dim3(256), 0, stream>>>(hb, bt, cosT, sinT, qbuf, kbuf, vrow, adcols);
    k_fuse<<<dim3(512), dim3(256), 0, stream>>>(adcols, W1, b1, W2, b2, field);
    k_gate<<<dim3(1), dim3(256), 0, stream>>>(field, gate);
    k_vtrans<<<dim3(32, 8), dim3(256), 0, stream>>>(vrow, vt);
    k_transpose<<<dim3(32, 32), dim3(256), 0, stream>>>(Wo, wot, 2048);
    k_attn<<<dim3(32, 32), dim3(128), 0, stream>>>(qbuf, kbuf, vt, gate, gs, attnout);
    k_gemm<<<dim3(16, 16), dim3(256), 0, stream>>>(attnout, wot, out, 2048, 2048, 2048);
}

// Round 15
// 167.978 us; speedup vs baseline: 2.3477x; 1.1612x over previous
//
#include <hip/hip_runtime.h>

#define S_LEN 2048
#define D_DIM 2048
#define NHEAD 32
#define NKVH  8
#define HDIM  64
#define NBT   3200   // 2048 q + 512 k + 512 v + 16 fiber + 64 w1h + 48 pad

typedef __attribute__((ext_vector_type(4))) float f32x4;
typedef __attribute__((ext_vector_type(8))) short bf16x8;

__device__ __forceinline__ unsigned short f2bf(float x) {
    union { float f; unsigned u; } v; v.f = x;
    unsigned r = v.u + 0x7FFFu + ((v.u >> 16) & 1u);
    return (unsigned short)(r >> 16);
}

// async global->LDS 16B: dest = wave-uniform base + lane*16
#define GLD(gsrc, ldst) __builtin_amdgcn_global_load_lds( \
    (const __attribute__((address_space(1))) unsigned int*)(const void*)(gsrc), \
    (__attribute__((address_space(3))) unsigned int*)(void*)(ldst), 16, 0, 0)

#define SWZ(r) (((r) & 7) << 4)

// k-permutation: QK^T C-layout -> PV B-frag consumption (verified R13)
#define KPERM(kk) (((kk) & 32) | (((kk) & 12) << 1) | (((kk) & 16) >> 2) | ((kk) & 3))

// ---- generic 64x64 f32->bf16 transpose tile (into row-stride-2048 dest) ----
__device__ __forceinline__ void dev_trans(const float* __restrict__ W, unsigned short* __restrict__ WT,
                                          int N, int k0, int n0, int t, unsigned short L[64][65]) {
    for (int it = 0; it < 16; ++it) {
        int e = it * 256 + t;
        int r = e >> 6, c = e & 63;
        L[c][r] = f2bf(W[(size_t)(k0 + r) * N + n0 + c]);
    }
    __syncthreads();
    for (int it = 0; it < 16; ++it) {
        int e = it * 256 + t;
        int n = e >> 6, kk = e & 63;
        WT[(size_t)(n0 + n) * 2048 + k0 + kk] = L[n][kk];
    }
}

// ---- merged prep: cvt_h + Wq/Wk/Wv/Wo/Wf/W1 transposes + pad zero ----
__global__ __launch_bounds__(256) void k_prep(const float* __restrict__ h, unsigned short* __restrict__ hb,
        const float* __restrict__ Wq, const float* __restrict__ Wk, const float* __restrict__ Wv,
        const float* __restrict__ Wo, const float* __restrict__ Wf, const float* __restrict__ W1,
        unsigned short* __restrict__ bt, unsigned short* __restrict__ wot) {
    __shared__ unsigned short L[64][65];
    int b = blockIdx.x, t = threadIdx.x;
    if (b < 4096) {                       // h -> bf16
        int i = (b * 256 + t) * 4;
        float4 v = *(const float4*)(h + i);
        ushort4 o;
        o.x = f2bf(v.x); o.y = f2bf(v.y); o.z = f2bf(v.z); o.w = f2bf(v.w);
        *(ushort4*)(hb + i) = o;
    } else if (b < 5120) {                // Wq [2048][2048] -> bt rows 0..2047
        int bb = b - 4096;
        dev_trans(Wq, bt, 2048, (bb & 31) * 64, (bb >> 5) * 64, t, L);
    } else if (b < 5376) {                // Wk [2048][512] -> bt rows 2048..2559
        int bb = b - 5120;
        dev_trans(Wk, bt + (size_t)2048 * 2048, 512, (bb & 31) * 64, (bb >> 5) * 64, t, L);
    } else if (b < 5632) {                // Wv [2048][512] -> bt rows 2560..3071
        int bb = b - 5376;
        dev_trans(Wv, bt + (size_t)2560 * 2048, 512, (bb & 31) * 64, (bb >> 5) * 64, t, L);
    } else if (b < 6656) {                // Wo [2048][2048] -> wot
        int bb = b - 5632;
        dev_trans(Wo, wot, 2048, (bb & 31) * 64, (bb >> 5) * 64, t, L);
    } else if (b < 6688) {                // Wf [2048][16] -> bt rows 3072..3087
        int k0 = (b - 6656) * 64;
        for (int it = 0; it < 4; ++it) {
            int e = it * 256 + t;
            int r = e >> 4, c = e & 15;
            L[c][r] = f2bf(Wf[(size_t)(k0 + r) * 16 + c]);
        }
        __syncthreads();
        unsigned short* dst = bt + (size_t)3072 * 2048;
        for (int it = 0; it < 4; ++it) {
            int e = it * 256 + t;
            int c = e >> 6, kk = e & 63;
            dst[(size_t)c * 2048 + k0 + kk] = L[c][kk];
        }
    } else if (b < 6720) {                // W1[:2048] [2048][64] -> bt rows 3088..3151
        int k0 = (b - 6688) * 64;
        dev_trans(W1, bt + (size_t)3088 * 2048, 64, k0, 0, t, L);
    } else {                              // zero pad rows 3152..3199
        int bb = b - 6720;                // 0..191
        unsigned* p = (unsigned*)(bt + (size_t)3152 * 2048);
        p[bb * 256 + t] = 0u;
    }
}

// ---- merged: fuse (field) + vtrans (vt) ----
__global__ __launch_bounds__(256) void k_fuse_vtrans(const float* __restrict__ adcols,
                        const float* __restrict__ W1, const float* __restrict__ b1,
                        const float* __restrict__ W2, const float* __restrict__ b2,
                        float* __restrict__ field,
                        const unsigned short* __restrict__ vrow, unsigned short* __restrict__ vt) {
    __shared__ unsigned short L[64][65];
    int b = blockIdx.x, t = threadIdx.x;
    if (b < 512) {
        int wv = t >> 6, l = t & 63;
        int s = b * 4 + wv;
        const float* row = adcols + (size_t)s * 128;
        float x = row[16 + l] + b1[l];
#pragma unroll
        for (int f = 0; f < 16; ++f) x += row[f] * W1[(size_t)(2048 + f) * 64 + l];
        float hm = 0.5f * x * (1.f + erff(x * 0.70710678118654752f));
        float p = hm * W2[l];
        for (int m = 32; m; m >>= 1) p += __shfl_xor(p, m);
        if (l == 0) field[s] = 0.005f * (p + b2[0]);
    } else {
        int bb = b - 512;
        int s0 = (bb & 31) * 64, hk = bb >> 5;
        for (int it = 0; it < 16; ++it) {
            int e = it * 256 + t;
            int r = e >> 6, c = e & 63;
            L[c][r] = vrow[(size_t)(s0 + r) * 512 + hk * 64 + c];
        }
        __syncthreads();
        for (int it = 0; it < 16; ++it) {
            int e = it * 256 + t;
            int c = e >> 6, kk = e & 63;
            vt[((size_t)hk * 64 + c) * S_LEN + s0 + KPERM(kk)] = L[c][kk];
        }
    }
}

// ---------------- gate = (field - mean)/(std_ddof1 + 1e-6) ----------------
__global__ void k_gate(const float* __restrict__ field, float* __restrict__ gate) {
    __shared__ float red[256];
    int t = threadIdx.x;
    float s = 0.f;
    for (int i = t; i < S_LEN; i += 256) s += field[i];
    red[t] = s; __syncthreads();
    for (int w = 128; w; w >>= 1) { if (t < w) red[t] += red[t + w]; __syncthreads(); }
    float mean = red[0] / (float)S_LEN;
    __syncthreads();
    float v = 0.f;
    for (int i = t; i < S_LEN; i += 256) { float d = field[i] - mean; v += d * d; }
    red[t] = v; __syncthreads();
    for (int w = 128; w; w >>= 1) { if (t < w) red[t] += red[t + w]; __syncthreads(); }
    float stdv = sqrtf(red[0] / (float)(S_LEN - 1)) + 1e-6f;
    for (int i = t; i < S_LEN; i += 256) gate[i] = (field[i] - mean) / stdv;
}

// ------- GEMM1 (64x128 tile, 800 blocks): hb x bt^T + fused RoPE epilogue -------
__global__ __launch_bounds__(256) void k_gemm_qkv(const unsigned short* __restrict__ A,
                                                  const unsigned short* __restrict__ BT,
                                                  const float* __restrict__ cs,
                                                  const float* __restrict__ sn,
                                                  unsigned short* __restrict__ qb,
                                                  unsigned short* __restrict__ kbuf,
                                                  unsigned short* __restrict__ vrow,
                                                  float* __restrict__ adcols) {
    __shared__ __align__(16) char As[4096];
    __shared__ __align__(16) char Bs[8192];
    const int K = 2048;
    int flat = blockIdx.y * gridDim.x + blockIdx.x;
    int cpx = (gridDim.x * gridDim.y) >> 3;      // 800/8 = 100
    int swz = (flat & 7) * cpx + (flat >> 3);
    int m0 = (swz / gridDim.x) * 64, n0 = (swz % gridDim.x) * 128;
    int t = threadIdx.x;
    int wv = t >> 6, ln = t & 63;
    int wr = (wv >> 1) * 32, wc = (wv & 1) * 64;
    int lr = ln & 15, lkb = (ln >> 4) * 16;
    f32x4 acc[2][4] = {};
    const unsigned short* Ap = A + (size_t)(m0 + (t >> 2)) * K + (t & 3) * 8;
    const unsigned short* Bp = BT + (size_t)(n0 + (t >> 2)) * K + (t & 3) * 8;
    char* lA = As + wv * 1024;
    char* lB = Bs + wv * 1024;
    int nk = K / 32;
    GLD(Ap, lA);
    GLD(Bp, lB); GLD(Bp + (size_t)64 * K, lB + 4096);
    for (int kt = 0; kt < nk; ++kt) {
        __syncthreads();
        bf16x8 af[2], bfv[4];
#pragma unroll
        for (int i = 0; i < 2; ++i) af[i]  = *(const bf16x8*)(As + (wr + i * 16 + lr) * 64 + lkb);
#pragma unroll
        for (int j = 0; j < 4; ++j) bfv[j] = *(const bf16x8*)(Bs + (wc + j * 16 + lr) * 64 + lkb);
#pragma unroll
        for (int i = 0; i < 2; ++i)
#pragma unroll
            for (int j = 0; j < 4; ++j)
                acc[i][j] = __builtin_amdgcn_mfma_f32_16x16x32_bf16(af[i], bfv[j], acc[i][j], 0, 0, 0);
        __syncthreads();
        if (kt + 1 < nk) {
            const unsigned short* Ak = Ap + (size_t)(kt + 1) * 32;
            const unsigned short* Bk = Bp + (size_t)(kt + 1) * 32;
            GLD(Ak, lA);
            GLD(Bk, lB); GLD(Bk + (size_t)64 * K, lB + 4096);
        }
    }
    int orow = (ln >> 4) * 4;
    int col0 = n0 + wc;
    if (col0 < 2560) {
        bool isq = (col0 < 2048);
        unsigned short* dst = isq ? qb : kbuf;
        int hh = (isq ? col0 : col0 - 2048) >> 6;
        float qscale = isq ? 0.125f : 1.0f;
#pragma unroll
        for (int i = 0; i < 2; ++i)
#pragma unroll
            for (int r = 0; r < 4; ++r) {
                int s = m0 + wr + i * 16 + orow + r;
#pragma unroll
                for (int j = 0; j < 4; ++j) {
                    int d = j * 16 + lr;
                    float c = cs[s * 64 + d], si = sn[s * 64 + d];
                    float val = acc[i][j][r];
                    float prt = acc[i][j ^ 2][r];
                    float out = val * c + ((j < 2) ? -prt : prt) * si;
                    dst[((size_t)hh * S_LEN + s) * 64 + d] = f2bf(out * qscale);
                }
            }
    } else if (col0 < 3072) {
        int vc0 = col0 - 2560;
#pragma unroll
        for (int i = 0; i < 2; ++i)
#pragma unroll
            for (int j = 0; j < 4; ++j) {
                unsigned short* vp = vrow + (size_t)(m0 + wr + i * 16 + orow) * 512 + vc0 + j * 16 + lr;
                for (int r = 0; r < 4; ++r) vp[(size_t)r * 512] = f2bf(acc[i][j][r]);
            }
    } else {
        int ac0 = col0 - 3072;
#pragma unroll
        for (int i = 0; i < 2; ++i)
#pragma unroll
            for (int j = 0; j < 4; ++j) {
                float* ap = adcols + (size_t)(m0 + wr + i * 16 + orow) * 128 + ac0 + j * 16 + lr;
                for (int r = 0; r < 4; ++r) ap[(size_t)r * 128] = acc[i][j][r];
            }
    }
}

// ------- GEMM2 (64x128 tile, 512 blocks): C[M][N] = A[M][K] x BT[N][K]^T -------
__global__ __launch_bounds__(256) void k_gemm(const unsigned short* __restrict__ A,
                                              const unsigned short* __restrict__ BT,
                                              float* __restrict__ C, int M, int N, int K) {
    __shared__ __align__(16) char As[4096];
    __shared__ __align__(16) char Bs[8192];
    int flat = blockIdx.y * gridDim.x + blockIdx.x;
    int cpx = (gridDim.x * gridDim.y) >> 3;
    int swz = (flat & 7) * cpx + (flat >> 3);
    int m0 = (swz / gridDim.x) * 64, n0 = (swz % gridDim.x) * 128;
    int t = threadIdx.x;
    int wv = t >> 6, ln = t & 63;
    int wr = (wv >> 1) * 32, wc = (wv & 1) * 64;
    int lr = ln & 15, lkb = (ln >> 4) * 16;
    f32x4 acc[2][4] = {};
    const unsigned short* Ap = A + (size_t)(m0 + (t >> 2)) * K + (t & 3) * 8;
    const unsigned short* Bp = BT + (size_t)(n0 + (t >> 2)) * K + (t & 3) * 8;
    char* lA = As + wv * 1024;
    char* lB = Bs + wv * 1024;
    int nk = K / 32;
    GLD(Ap, lA);
    GLD(Bp, lB); GLD(Bp + (size_t)64 * K, lB + 4096);
    for (int kt = 0; kt < nk; ++kt) {
        __syncthreads();
        bf16x8 af[2], bfv[4];
#pragma unroll
        for (int i = 0; i < 2; ++i) af[i]  = *(const bf16x8*)(As + (wr + i * 16 + lr) * 64 + lkb);
#pragma unroll
        for (int j = 0; j < 4; ++j) bfv[j] = *(const bf16x8*)(Bs + (wc + j * 16 + lr) * 64 + lkb);
#pragma unroll
        for (int i = 0; i < 2; ++i)
#pragma unroll
            for (int j = 0; j < 4; ++j)
                acc[i][j] = __builtin_amdgcn_mfma_f32_16x16x32_bf16(af[i], bfv[j], acc[i][j], 0, 0, 0);
        __syncthreads();
        if (kt + 1 < nk) {
            const unsigned short* Ak = Ap + (size_t)(kt + 1) * 32;
            const unsigned short* Bk = Bp + (size_t)(kt + 1) * 32;
            GLD(Ak, lA);
            GLD(Bk, lB); GLD(Bk + (size_t)64 * K, lB + 4096);
        }
    }
    int orow = (ln >> 4) * 4;
#pragma unroll
    for (int i = 0; i < 2; ++i)
#pragma unroll
        for (int j = 0; j < 4; ++j) {
            float* Cp = C + (size_t)(m0 + wr + i * 16 + orow) * N + n0 + wc + j * 16 + lr;
            for (int r = 0; r < 4; ++r) Cp[(size_t)r * N] = acc[i][j][r];
        }
}

__device__ __forceinline__ bf16x8 packP(const f32x4& a, const f32x4& b) {
    union { unsigned u[4]; bf16x8 v; } pk;
    asm("v_cvt_pk_bf16_f32 %0, %1, %2" : "=v"(pk.u[0]) : "v"(a[0]), "v"(a[1]));
    asm("v_cvt_pk_bf16_f32 %0, %1, %2" : "=v"(pk.u[1]) : "v"(a[2]), "v"(a[3]));
    asm("v_cvt_pk_bf16_f32 %0, %1, %2" : "=v"(pk.u[2]) : "v"(b[0]), "v"(b[1]));
    asm("v_cvt_pk_bf16_f32 %0, %1, %2" : "=v"(pk.u[3]) : "v"(b[2]), "v"(b[3]));
    return pk.v;
}

// ------- flash attention: R14-proven (swapped QK^T, in-register P, 2-wave blocks,
//         KVBLK=64, dbuf GLD staging, balanced qt pairing) — UNCHANGED -------
__global__ __launch_bounds__(128, 2) void k_attn(const unsigned short* __restrict__ qb,
                                                 const unsigned short* __restrict__ kb,
                                                 const unsigned short* __restrict__ vt,
                                                 const float* __restrict__ gate,
                                                 const float* __restrict__ gs_p,
                                                 unsigned short* __restrict__ attnout) {
    __shared__ __align__(16) char Kl[2][8192];
    __shared__ __align__(16) char Vl[2][8192];
    int h = blockIdx.y, hk = h >> 2;
    int qt = (h < 16) ? (31 - blockIdx.x) : blockIdx.x;
    int t = threadIdx.x, wv = t >> 6, l = t & 63;
    int lq = l & 15, lg = l >> 4;
    float gs = gs_p[0];
    int q0 = qt * 64 + wv * 32;
    const unsigned short* qbase = qb + ((size_t)h * S_LEN + q0) * 64;
    bf16x8 aq[2][2];
#pragma unroll
    for (int qf = 0; qf < 2; ++qf)
#pragma unroll
        for (int hf = 0; hf < 2; ++hf)
            aq[qf][hf] = *(const bf16x8*)(qbase + (qf * 16 + lq) * 64 + hf * 32 + lg * 8);
    f32x4 o[2][4] = {};
    float m_[2] = { -INFINITY, -INFINITY };
    float ls_[2] = { 0.f, 0.f };
    int nkt = qt + 1;
    int srow = t >> 3;
    int scol = 8 * ((t & 7) ^ (srow & 7));
    const unsigned short* kg = kb + (size_t)hk * S_LEN * 64;
    const unsigned short* vg = vt + (size_t)hk * 64 * S_LEN;
    char* lKb0 = Kl[0] + wv * 1024; char* lKb1 = Kl[1] + wv * 1024;
    char* lVb0 = Vl[0] + wv * 1024; char* lVb1 = Vl[1] + wv * 1024;
#define STAGE_KV(K0, DK, DV) do { \
        GLD(kg + (size_t)((K0) + srow) * 64 + scol, (DK)); \
        GLD(kg + (size_t)((K0) + 16 + srow) * 64 + scol, (DK) + 2048); \
        GLD(kg + (size_t)((K0) + 32 + srow) * 64 + scol, (DK) + 4096); \
        GLD(kg + (size_t)((K0) + 48 + srow) * 64 + scol, (DK) + 6144); \
        GLD(vg + (size_t)srow * S_LEN + (K0) + scol, (DV)); \
        GLD(vg + (size_t)(16 + srow) * S_LEN + (K0) + scol, (DV) + 2048); \
        GLD(vg + (size_t)(32 + srow) * S_LEN + (K0) + scol, (DV) + 4096); \
        GLD(vg + (size_t)(48 + srow) * S_LEN + (K0) + scol, (DV) + 6144); \
    } while (0)
    STAGE_KV(0, lKb0, lVb0);
    for (int kt = 0; kt < nkt; ++kt) {
        __syncthreads();
        if (kt + 1 < nkt) {
            int k0n = (kt + 1) * 64;
            char* dK = ((kt + 1) & 1) ? lKb1 : lKb0;
            char* dV = ((kt + 1) & 1) ? lVb1 : lVb0;
            STAGE_KV(k0n, dK, dV);
        }
        int k0 = kt * 64;
        bool diag = (kt == nkt - 1);
        const char* Kb = Kl[kt & 1];
        const char* Vb = Vl[kt & 1];
        f32x4 sc[2][4] = {};
#pragma unroll
        for (int ct = 0; ct < 4; ++ct) {
            int krow = ct * 16 + lq;
#pragma unroll
            for (int hf = 0; hf < 2; ++hf) {
                bf16x8 bk = *(const bf16x8*)(Kb + krow * 128 + ((hf * 64 + lg * 16) ^ SWZ(krow)));
#pragma unroll
                for (int qf = 0; qf < 2; ++qf)
                    sc[qf][ct] = __builtin_amdgcn_mfma_f32_16x16x32_bf16(bk, aq[qf][hf], sc[qf][ct], 0, 0, 0);
            }
        }
        float vmax[2] = { -INFINITY, -INFINITY };
#pragma unroll
        for (int ct = 0; ct < 4; ++ct) {
            f32x4 g4 = *(const f32x4*)(gate + k0 + ct * 16 + lg * 4);
#pragma unroll
            for (int qf = 0; qf < 2; ++qf) {
                int q = q0 + qf * 16 + lq;
#pragma unroll
                for (int r = 0; r < 4; ++r) {
                    float val = sc[qf][ct][r] + gs * g4[r];
                    if (diag && (k0 + ct * 16 + lg * 4 + r > q)) val = -1e9f;
                    sc[qf][ct][r] = val;
                    vmax[qf] = fmaxf(vmax[qf], val);
                }
            }
        }
#pragma unroll
        for (int qf = 0; qf < 2; ++qf) {
            vmax[qf] = fmaxf(vmax[qf], __shfl_xor(vmax[qf], 16));
            vmax[qf] = fmaxf(vmax[qf], __shfl_xor(vmax[qf], 32));
        }
        bool cond = (vmax[0] <= m_[0] + 8.f) && (vmax[1] <= m_[1] + 8.f);
        if (!__all(cond)) {
#pragma unroll
            for (int qf = 0; qf < 2; ++qf) {
                float mn = fmaxf(m_[qf], vmax[qf]);
                float scl = __expf(m_[qf] - mn);
                ls_[qf] *= scl;
#pragma unroll
                for (int dt = 0; dt < 4; ++dt) o[qf][dt] *= scl;
                m_[qf] = mn;
            }
        }
#pragma unroll
        for (int qf = 0; qf < 2; ++qf)
#pragma unroll
            for (int ct = 0; ct < 4; ++ct)
#pragma unroll
                for (int r = 0; r < 4; ++r) {
                    float p = __expf(sc[qf][ct][r] - m_[qf]);
                    sc[qf][ct][r] = p;
                    ls_[qf] += p;
                }
#pragma unroll
        for (int ks = 0; ks < 2; ++ks) {
            bf16x8 pf0 = packP(sc[0][2 * ks], sc[0][2 * ks + 1]);
            bf16x8 pf1 = packP(sc[1][2 * ks], sc[1][2 * ks + 1]);
#pragma unroll
            for (int dt = 0; dt < 4; ++dt) {
                int vr = dt * 16 + lq;
                bf16x8 bv = *(const bf16x8*)(Vb + vr * 128 + ((ks * 64 + lg * 16) ^ SWZ(vr)));
                o[0][dt] = __builtin_amdgcn_mfma_f32_16x16x32_bf16(bv, pf0, o[0][dt], 0, 0, 0);
                o[1][dt] = __builtin_amdgcn_mfma_f32_16x16x32_bf16(bv, pf1, o[1][dt], 0, 0, 0);
            }
        }
    }
#undef STAGE_KV
#pragma unroll
    for (int qf = 0; qf < 2; ++qf) {
        float s = ls_[qf];
        s += __shfl_xor(s, 16);
        s += __shfl_xor(s, 32);
        float inv = 1.f / s;
        int q = q0 + qf * 16 + lq;
        unsigned short* orow = attnout + (size_t)q * 2048 + h * 64;
#pragma unroll
        for (int dt = 0; dt < 4; ++dt) {
            ushort4 st;
            st.x = f2bf(o[qf][dt][0] * inv); st.y = f2bf(o[qf][dt][1] * inv);
            st.z = f2bf(o[qf][dt][2] * inv); st.w = f2bf(o[qf][dt][3] * inv);
            *(ushort4*)(orow + dt * 16 + lg * 4) = st;
        }
    }
}

extern "C" void kernel_launch(void* const* d_in, const int* in_sizes, int n_in,
                              void* d_out, int out_size, void* d_ws, size_t ws_size,
                              hipStream_t stream) {
    const float* h    = (const float*)d_in[0];
    const float* cosT = (const float*)d_in[2];
    const float* sinT = (const float*)d_in[3];
    const float* Wf   = (const float*)d_in[4];
    const float* W1   = (const float*)d_in[5];
    const float* b1   = (const float*)d_in[6];
    const float* W2   = (const float*)d_in[7];
    const float* b2   = (const float*)d_in[8];
    const float* gs   = (const float*)d_in[9];
    const float* Wq   = (const float*)d_in[10];
    const float* Wk   = (const float*)d_in[11];
    const float* Wv   = (const float*)d_in[12];
    const float* Wo   = (const float*)d_in[13];
    float* out = (float*)d_out;

    char* ws = (char*)d_ws;
    unsigned short* hb     = (unsigned short*)(ws);                // 0..8M      [dead after gemm1]
    unsigned short* bt     = (unsigned short*)(ws + 8388608);      // 8M..21.5M  [dead after gemm1]
    unsigned short* qbuf   = (unsigned short*)(ws + 21495808);     // 8M
    unsigned short* kbuf   = (unsigned short*)(ws + 29884416);     // 2M
    unsigned short* vrow   = (unsigned short*)(ws + 31981568);     // 2M
    float*          adcols = (float*)(ws + 34078720);              // 1M
    float*          field  = (float*)(ws + 35127296);              // 8K
    float*          gate   = (float*)(ws + 35135488);              // 8K
    unsigned short* wot    = (unsigned short*)(ws + 35143680);     // 8M (own slot; written pre-gemm1)
    // aliases over dead regions (after gemm1):
    unsigned short* vt      = (unsigned short*)(ws + 16777216);    // 2M over bt tail
    unsigned short* attnout = (unsigned short*)(ws);               // 8M over hb

    k_prep<<<dim3(6912), dim3(256), 0, stream>>>(h, hb, Wq, Wk, Wv, Wo, Wf, W1, bt, wot);
    k_gemm_qkv<<<dim3(25, 32), dim3(256), 0, stream>>>(hb, bt, cosT, sinT, qbuf, kbuf, vrow, adcols);
    k_fuse_vtrans<<<dim3(768), dim3(256), 0, stream>>>(adcols, W1, b1, W2, b2, field, vrow, vt);
    k_gate<<<dim3(1), dim3(256), 0, stream>>>(field, gate);
    k_attn<<<dim3(32, 32), dim3(128), 0, stream>>>(qbuf, kbuf, vt, gate, gs, attnout);
    k_gemm<<<dim3(16, 32), dim3(256), 0, stream>>>(attnout, wot, out, 2048, 2048, 2048);
}

// Round 17
// 155.852 us; speedup vs baseline: 2.5304x; 1.0778x over previous
//
#include <hip/hip_runtime.h>

#define S_LEN 2048
#define D_DIM 2048
#define NHEAD 32
#define NKVH  8
#define HDIM  64
#define NBT   3200   // 2048 q + 512 k + 512 v + 16 fiber + 64 w1h + 48 pad

typedef __attribute__((ext_vector_type(4))) float f32x4;
typedef __attribute__((ext_vector_type(8))) short bf16x8;

__device__ __forceinline__ unsigned short f2bf(float x) {
    union { float f; unsigned u; } v; v.f = x;
    unsigned r = v.u + 0x7FFFu + ((v.u >> 16) & 1u);
    return (unsigned short)(r >> 16);
}

// async global->LDS 16B: dest = wave-uniform base + lane*16
#define GLD(gsrc, ldst) __builtin_amdgcn_global_load_lds( \
    (const __attribute__((address_space(1))) unsigned int*)(const void*)(gsrc), \
    (__attribute__((address_space(3))) unsigned int*)(void*)(ldst), 16, 0, 0)

#define SWZ(r) (((r) & 7) << 4)

// k-permutation: QK^T C-layout -> PV B-frag consumption (verified R13)
#define KPERM(kk) (((kk) & 32) | (((kk) & 12) << 1) | (((kk) & 16) >> 2) | ((kk) & 3))

// ---- generic 64x64 f32->bf16 transpose tile (into row-stride-2048 dest) ----
__device__ __forceinline__ void dev_trans(const float* __restrict__ W, unsigned short* __restrict__ WT,
                                          int N, int k0, int n0, int t, unsigned short L[64][65]) {
    for (int it = 0; it < 16; ++it) {
        int e = it * 256 + t;
        int r = e >> 6, c = e & 63;
        L[c][r] = f2bf(W[(size_t)(k0 + r) * N + n0 + c]);
    }
    __syncthreads();
    for (int it = 0; it < 16; ++it) {
        int e = it * 256 + t;
        int n = e >> 6, kk = e & 63;
        WT[(size_t)(n0 + n) * 2048 + k0 + kk] = L[n][kk];
    }
}

// ---- merged prep: cvt_h + Wq/Wk/Wv/Wo/Wf/W1 transposes + pad zero ----
__global__ __launch_bounds__(256) void k_prep(const float* __restrict__ h, unsigned short* __restrict__ hb,
        const float* __restrict__ Wq, const float* __restrict__ Wk, const float* __restrict__ Wv,
        const float* __restrict__ Wo, const float* __restrict__ Wf, const float* __restrict__ W1,
        unsigned short* __restrict__ bt, unsigned short* __restrict__ wot) {
    __shared__ unsigned short L[64][65];
    int b = blockIdx.x, t = threadIdx.x;
    if (b < 4096) {
        int i = (b * 256 + t) * 4;
        float4 v = *(const float4*)(h + i);
        ushort4 o;
        o.x = f2bf(v.x); o.y = f2bf(v.y); o.z = f2bf(v.z); o.w = f2bf(v.w);
        *(ushort4*)(hb + i) = o;
    } else if (b < 5120) {
        int bb = b - 4096;
        dev_trans(Wq, bt, 2048, (bb & 31) * 64, (bb >> 5) * 64, t, L);
    } else if (b < 5376) {
        int bb = b - 5120;
        dev_trans(Wk, bt + (size_t)2048 * 2048, 512, (bb & 31) * 64, (bb >> 5) * 64, t, L);
    } else if (b < 5632) {
        int bb = b - 5376;
        dev_trans(Wv, bt + (size_t)2560 * 2048, 512, (bb & 31) * 64, (bb >> 5) * 64, t, L);
    } else if (b < 6656) {
        int bb = b - 5632;
        dev_trans(Wo, wot, 2048, (bb & 31) * 64, (bb >> 5) * 64, t, L);
    } else if (b < 6688) {
        int k0 = (b - 6656) * 64;
        for (int it = 0; it < 4; ++it) {
            int e = it * 256 + t;
            int r = e >> 4, c = e & 15;
            L[c][r] = f2bf(Wf[(size_t)(k0 + r) * 16 + c]);
        }
        __syncthreads();
        unsigned short* dst = bt + (size_t)3072 * 2048;
        for (int it = 0; it < 4; ++it) {
            int e = it * 256 + t;
            int c = e >> 6, kk = e & 63;
            dst[(size_t)c * 2048 + k0 + kk] = L[c][kk];
        }
    } else if (b < 6720) {
        int k0 = (b - 6688) * 64;
        dev_trans(W1, bt + (size_t)3088 * 2048, 64, k0, 0, t, L);
    } else {
        int bb = b - 6720;
        unsigned* p = (unsigned*)(bt + (size_t)3152 * 2048);
        p[bb * 256 + t] = 0u;
    }
}

// ---- merged: fuse (field) + vtrans (vt) ----
__global__ __launch_bounds__(256) void k_fuse_vtrans(const float* __restrict__ adcols,
                        const float* __restrict__ W1, const float* __restrict__ b1,
                        const float* __restrict__ W2, const float* __restrict__ b2,
                        float* __restrict__ field,
                        const unsigned short* __restrict__ vrow, unsigned short* __restrict__ vt) {
    __shared__ unsigned short L[64][65];
    int b = blockIdx.x, t = threadIdx.x;
    if (b < 512) {
        int wv = t >> 6, l = t & 63;
        int s = b * 4 + wv;
        const float* row = adcols + (size_t)s * 128;
        float x = row[16 + l] + b1[l];
#pragma unroll
        for (int f = 0; f < 16; ++f) x += row[f] * W1[(size_t)(2048 + f) * 64 + l];
        float hm = 0.5f * x * (1.f + erff(x * 0.70710678118654752f));
        float p = hm * W2[l];
        for (int m = 32; m; m >>= 1) p += __shfl_xor(p, m);
        if (l == 0) field[s] = 0.005f * (p + b2[0]);
    } else {
        int bb = b - 512;
        int s0 = (bb & 31) * 64, hk = bb >> 5;
        for (int it = 0; it < 16; ++it) {
            int e = it * 256 + t;
            int r = e >> 6, c = e & 63;
            L[c][r] = vrow[(size_t)(s0 + r) * 512 + hk * 64 + c];
        }
        __syncthreads();
        for (int it = 0; it < 16; ++it) {
            int e = it * 256 + t;
            int c = e >> 6, kk = e & 63;
            vt[((size_t)hk * 64 + c) * S_LEN + s0 + KPERM(kk)] = L[c][kk];
        }
    }
}

// ---------------- gate = (field - mean)/(std_ddof1 + 1e-6) ----------------
__global__ void k_gate(const float* __restrict__ field, float* __restrict__ gate) {
    __shared__ float red[256];
    int t = threadIdx.x;
    float s = 0.f;
    for (int i = t; i < S_LEN; i += 256) s += field[i];
    red[t] = s; __syncthreads();
    for (int w = 128; w; w >>= 1) { if (t < w) red[t] += red[t + w]; __syncthreads(); }
    float mean = red[0] / (float)S_LEN;
    __syncthreads();
    float v = 0.f;
    for (int i = t; i < S_LEN; i += 256) { float d = field[i] - mean; v += d * d; }
    red[t] = v; __syncthreads();
    for (int w = 128; w; w >>= 1) { if (t < w) red[t] += red[t + w]; __syncthreads(); }
    float stdv = sqrtf(red[0] / (float)(S_LEN - 1)) + 1e-6f;
    for (int i = t; i < S_LEN; i += 256) gate[i] = (field[i] - mean) / stdv;
}

// ====== shared GEMM core (function form): 64x128 tile, BK=64, swizzled LDS ======
// As: 64 rows x 128B (8KB). Bs: 128 rows x 128B (16KB). 2 barriers + 6 GLD + 16 MFMA/wave/iter.
__device__ __forceinline__ void gemm_core(const unsigned short* __restrict__ A,
                                          const unsigned short* __restrict__ BT,
                                          int K, int m0, int n0,
                                          char* As, char* Bs,
                                          int wr, int wc, int lr, int lkb,
                                          f32x4 acc[2][4]) {
    int t = threadIdx.x;
    int wv = t >> 6;
    int srow = t >> 3;
    int scol = 8 * ((t & 7) ^ (srow & 7));
    const unsigned short* Ag = A + (size_t)(m0 + srow) * K + scol;
    const unsigned short* Bg = BT + (size_t)(n0 + srow) * K + scol;
    char* lA = As + wv * 1024;
    char* lB = Bs + wv * 1024;
    int nk = K / 64;
    GLD(Ag, lA); GLD(Ag + (size_t)32 * K, lA + 4096);
    GLD(Bg, lB); GLD(Bg + (size_t)32 * K, lB + 4096);
    GLD(Bg + (size_t)64 * K, lB + 8192); GLD(Bg + (size_t)96 * K, lB + 12288);
    for (int kt = 0; kt < nk; ++kt) {
        __syncthreads();
        bf16x8 af[2][2], bfv[4][2];
#pragma unroll
        for (int i = 0; i < 2; ++i) {
            int row = wr + i * 16 + lr;
#pragma unroll
            for (int kh = 0; kh < 2; ++kh)
                af[i][kh] = *(const bf16x8*)(As + row * 128 + ((kh * 64 + lkb) ^ SWZ(row)));
        }
#pragma unroll
        for (int j = 0; j < 4; ++j) {
            int row = wc + j * 16 + lr;
#pragma unroll
            for (int kh = 0; kh < 2; ++kh)
                bfv[j][kh] = *(const bf16x8*)(Bs + row * 128 + ((kh * 64 + lkb) ^ SWZ(row)));
        }
#pragma unroll
        for (int kh = 0; kh < 2; ++kh)
#pragma unroll
            for (int i = 0; i < 2; ++i)
#pragma unroll
                for (int j = 0; j < 4; ++j)
                    acc[i][j] = __builtin_amdgcn_mfma_f32_16x16x32_bf16(af[i][kh], bfv[j][kh], acc[i][j], 0, 0, 0);
        __syncthreads();
        if (kt + 1 < nk) {
            const unsigned short* Ak = Ag + (size_t)(kt + 1) * 64;
            const unsigned short* Bk = Bg + (size_t)(kt + 1) * 64;
            GLD(Ak, lA); GLD(Ak + (size_t)32 * K, lA + 4096);
            GLD(Bk, lB); GLD(Bk + (size_t)32 * K, lB + 4096);
            GLD(Bk + (size_t)64 * K, lB + 8192); GLD(Bk + (size_t)96 * K, lB + 12288);
        }
    }
}

// ------- GEMM1 (64x128, BK=64, 800 blocks): hb x bt^T + fused RoPE epilogue -------
__global__ __launch_bounds__(256) void k_gemm_qkv(const unsigned short* __restrict__ A,
                                                  const unsigned short* __restrict__ BT,
                                                  const float* __restrict__ cs,
                                                  const float* __restrict__ sn,
                                                  unsigned short* __restrict__ qb,
                                                  unsigned short* __restrict__ kbuf,
                                                  unsigned short* __restrict__ vrow,
                                                  float* __restrict__ adcols) {
    __shared__ __align__(16) char As[8192];
    __shared__ __align__(16) char Bs[16384];
    const int K = 2048;
    int flat = blockIdx.y * gridDim.x + blockIdx.x;
    int cpx = (gridDim.x * gridDim.y) >> 3;
    int swz = (flat & 7) * cpx + (flat >> 3);
    int m0 = (swz / gridDim.x) * 64, n0 = (swz % gridDim.x) * 128;
    int t = threadIdx.x;
    int wv = t >> 6, ln = t & 63;
    int wr = (wv >> 1) * 32, wc = (wv & 1) * 64;
    int lr = ln & 15, lkb = (ln >> 4) * 16;
    f32x4 acc[2][4] = {};
    gemm_core(A, BT, K, m0, n0, As, Bs, wr, wc, lr, lkb, acc);
    int orow = (ln >> 4) * 4;
    int col0 = n0 + wc;
    if (col0 < 2560) {
        bool isq = (col0 < 2048);
        unsigned short* dst = isq ? qb : kbuf;
        int hh = (isq ? col0 : col0 - 2048) >> 6;
        float qscale = isq ? 0.125f : 1.0f;
#pragma unroll
        for (int i = 0; i < 2; ++i)
#pragma unroll
            for (int r = 0; r < 4; ++r) {
                int s = m0 + wr + i * 16 + orow + r;
#pragma unroll
                for (int j = 0; j < 4; ++j) {
                    int d = j * 16 + lr;
                    float c = cs[s * 64 + d], si = sn[s * 64 + d];
                    float val = acc[i][j][r];
                    float prt = acc[i][j ^ 2][r];
                    float out = val * c + ((j < 2) ? -prt : prt) * si;
                    dst[((size_t)hh * S_LEN + s) * 64 + d] = f2bf(out * qscale);
                }
            }
    } else if (col0 < 3072) {
        int vc0 = col0 - 2560;
#pragma unroll
        for (int i = 0; i < 2; ++i)
#pragma unroll
            for (int j = 0; j < 4; ++j) {
                unsigned short* vp = vrow + (size_t)(m0 + wr + i * 16 + orow) * 512 + vc0 + j * 16 + lr;
                for (int r = 0; r < 4; ++r) vp[(size_t)r * 512] = f2bf(acc[i][j][r]);
            }
    } else {
        int ac0 = col0 - 3072;
#pragma unroll
        for (int i = 0; i < 2; ++i)
#pragma unroll
            for (int j = 0; j < 4; ++j) {
                float* ap = adcols + (size_t)(m0 + wr + i * 16 + orow) * 128 + ac0 + j * 16 + lr;
                for (int r = 0; r < 4; ++r) ap[(size_t)r * 128] = acc[i][j][r];
            }
    }
}

// ------- GEMM2 (64x128, BK=64, 512 blocks): C = A x BT^T -------
__global__ __launch_bounds__(256) void k_gemm(const unsigned short* __restrict__ A,
                                              const unsigned short* __restrict__ BT,
                                              float* __restrict__ C, int M, int N, int K) {
    __shared__ __align__(16) char As[8192];
    __shared__ __align__(16) char Bs[16384];
    int flat = blockIdx.y * gridDim.x + blockIdx.x;
    int cpx = (gridDim.x * gridDim.y) >> 3;
    int swz = (flat & 7) * cpx + (flat >> 3);
    int m0 = (swz / gridDim.x) * 64, n0 = (swz % gridDim.x) * 128;
    int t = threadIdx.x;
    int wv = t >> 6, ln = t & 63;
    int wr = (wv >> 1) * 32, wc = (wv & 1) * 64;
    int lr = ln & 15, lkb = (ln >> 4) * 16;
    f32x4 acc[2][4] = {};
    gemm_core(A, BT, K, m0, n0, As, Bs, wr, wc, lr, lkb, acc);
    int orow = (ln >> 4) * 4;
#pragma unroll
    for (int i = 0; i < 2; ++i)
#pragma unroll
        for (int j = 0; j < 4; ++j) {
            float* Cp = C + (size_t)(m0 + wr + i * 16 + orow) * N + n0 + wc + j * 16 + lr;
            for (int r = 0; r < 4; ++r) Cp[(size_t)r * N] = acc[i][j][r];
        }
}

__device__ __forceinline__ bf16x8 packP(const f32x4& a, const f32x4& b) {
    union { unsigned u[4]; bf16x8 v; } pk;
    asm("v_cvt_pk_bf16_f32 %0, %1, %2" : "=v"(pk.u[0]) : "v"(a[0]), "v"(a[1]));
    asm("v_cvt_pk_bf16_f32 %0, %1, %2" : "=v"(pk.u[1]) : "v"(a[2]), "v"(a[3]));
    asm("v_cvt_pk_bf16_f32 %0, %1, %2" : "=v"(pk.u[2]) : "v"(b[0]), "v"(b[1]));
    asm("v_cvt_pk_bf16_f32 %0, %1, %2" : "=v"(pk.u[3]) : "v"(b[2]), "v"(b[3]));
    return pk.v;
}

// ------- flash attention: R14-proven — UNCHANGED -------
__global__ __launch_bounds__(128, 2) void k_attn(const unsigned short* __restrict__ qb,
                                                 const unsigned short* __restrict__ kb,
                                                 const unsigned short* __restrict__ vt,
                                                 const float* __restrict__ gate,
                                                 const float* __restrict__ gs_p,
                                                 unsigned short* __restrict__ attnout) {
    __shared__ __align__(16) char Kl[2][8192];
    __shared__ __align__(16) char Vl[2][8192];
    int h = blockIdx.y, hk = h >> 2;
    int qt = (h < 16) ? (31 - blockIdx.x) : blockIdx.x;
    int t = threadIdx.x, wv = t >> 6, l = t & 63;
    int lq = l & 15, lg = l >> 4;
    float gs = gs_p[0];
    int q0 = qt * 64 + wv * 32;
    const unsigned short* qbase = qb + ((size_t)h * S_LEN + q0) * 64;
    bf16x8 aq[2][2];
#pragma unroll
    for (int qf = 0; qf < 2; ++qf)
#pragma unroll
        for (int hf = 0; hf < 2; ++hf)
            aq[qf][hf] = *(const bf16x8*)(qbase + (qf * 16 + lq) * 64 + hf * 32 + lg * 8);
    f32x4 o[2][4] = {};
    float m_[2] = { -INFINITY, -INFINITY };
    float ls_[2] = { 0.f, 0.f };
    int nkt = qt + 1;
    int srow = t >> 3;
    int scol = 8 * ((t & 7) ^ (srow & 7));
    const unsigned short* kg = kb + (size_t)hk * S_LEN * 64;
    const unsigned short* vg = vt + (size_t)hk * 64 * S_LEN;
    char* lKb0 = Kl[0] + wv * 1024; char* lKb1 = Kl[1] + wv * 1024;
    char* lVb0 = Vl[0] + wv * 1024; char* lVb1 = Vl[1] + wv * 1024;
#define STAGE_KV(K0, DK, DV) do { \
        GLD(kg + (size_t)((K0) + srow) * 64 + scol, (DK)); \
        GLD(kg + (size_t)((K0) + 16 + srow) * 64 + scol, (DK) + 2048); \
        GLD(kg + (size_t)((K0) + 32 + srow) * 64 + scol, (DK) + 4096); \
        GLD(kg + (size_t)((K0) + 48 + srow) * 64 + scol, (DK) + 6144); \
        GLD(vg + (size_t)srow * S_LEN + (K0) + scol, (DV)); \
        GLD(vg + (size_t)(16 + srow) * S_LEN + (K0) + scol, (DV) + 2048); \
        GLD(vg + (size_t)(32 + srow) * S_LEN + (K0) + scol, (DV) + 4096); \
        GLD(vg + (size_t)(48 + srow) * S_LEN + (K0) + scol, (DV) + 6144); \
    } while (0)
    STAGE_KV(0, lKb0, lVb0);
    for (int kt = 0; kt < nkt; ++kt) {
        __syncthreads();
        if (kt + 1 < nkt) {
            int k0n = (kt + 1) * 64;
            char* dK = ((kt + 1) & 1) ? lKb1 : lKb0;
            char* dV = ((kt + 1) & 1) ? lVb1 : lVb0;
            STAGE_KV(k0n, dK, dV);
        }
        int k0 = kt * 64;
        bool diag = (kt == nkt - 1);
        const char* Kb = Kl[kt & 1];
        const char* Vb = Vl[kt & 1];
        f32x4 sc[2][4] = {};
#pragma unroll
        for (int ct = 0; ct < 4; ++ct) {
            int krow = ct * 16 + lq;
#pragma unroll
            for (int hf = 0; hf < 2; ++hf) {
                bf16x8 bk = *(const bf16x8*)(Kb + krow * 128 + ((hf * 64 + lg * 16) ^ SWZ(krow)));
#pragma unroll
                for (int qf = 0; qf < 2; ++qf)
                    sc[qf][ct] = __builtin_amdgcn_mfma_f32_16x16x32_bf16(bk, aq[qf][hf], sc[qf][ct], 0, 0, 0);
            }
        }
        float vmax[2] = { -INFINITY, -INFINITY };
#pragma unroll
        for (int ct = 0; ct < 4; ++ct) {
            f32x4 g4 = *(const f32x4*)(gate + k0 + ct * 16 + lg * 4);
#pragma unroll
            for (int qf = 0; qf < 2; ++qf) {
                int q = q0 + qf * 16 + lq;
#pragma unroll
                for (int r = 0; r < 4; ++r) {
                    float val = sc[qf][ct][r] + gs * g4[r];
                    if (diag && (k0 + ct * 16 + lg * 4 + r > q)) val = -1e9f;
                    sc[qf][ct][r] = val;
                    vmax[qf] = fmaxf(vmax[qf], val);
                }
            }
        }
#pragma unroll
        for (int qf = 0; qf < 2; ++qf) {
            vmax[qf] = fmaxf(vmax[qf], __shfl_xor(vmax[qf], 16));
            vmax[qf] = fmaxf(vmax[qf], __shfl_xor(vmax[qf], 32));
        }
        bool cond = (vmax[0] <= m_[0] + 8.f) && (vmax[1] <= m_[1] + 8.f);
        if (!__all(cond)) {
#pragma unroll
            for (int qf = 0; qf < 2; ++qf) {
                float mn = fmaxf(m_[qf], vmax[qf]);
                float scl = __expf(m_[qf] - mn);
                ls_[qf] *= scl;
#pragma unroll
                for (int dt = 0; dt < 4; ++dt) o[qf][dt] *= scl;
                m_[qf] = mn;
            }
        }
#pragma unroll
        for (int qf = 0; qf < 2; ++qf)
#pragma unroll
            for (int ct = 0; ct < 4; ++ct)
#pragma unroll
                for (int r = 0; r < 4; ++r) {
                    float p = __expf(sc[qf][ct][r] - m_[qf]);
                    sc[qf][ct][r] = p;
                    ls_[qf] += p;
                }
#pragma unroll
        for (int ks = 0; ks < 2; ++ks) {
            bf16x8 pf0 = packP(sc[0][2 * ks], sc[0][2 * ks + 1]);
            bf16x8 pf1 = packP(sc[1][2 * ks], sc[1][2 * ks + 1]);
#pragma unroll
            for (int dt = 0; dt < 4; ++dt) {
                int vr = dt * 16 + lq;
                bf16x8 bv = *(const bf16x8*)(Vb + vr * 128 + ((ks * 64 + lg * 16) ^ SWZ(vr)));
                o[0][dt] = __builtin_amdgcn_mfma_f32_16x16x32_bf16(bv, pf0, o[0][dt], 0, 0, 0);
                o[1][dt] = __builtin_amdgcn_mfma_f32_16x16x32_bf16(bv, pf1, o[1][dt], 0, 0, 0);
            }
        }
    }
#undef STAGE_KV
#pragma unroll
    for (int qf = 0; qf < 2; ++qf) {
        float s = ls_[qf];
        s += __shfl_xor(s, 16);
        s += __shfl_xor(s, 32);
        float inv = 1.f / s;
        int q = q0 + qf * 16 + lq;
        unsigned short* orow = attnout + (size_t)q * 2048 + h * 64;
#pragma unroll
        for (int dt = 0; dt < 4; ++dt) {
            ushort4 st;
            st.x = f2bf(o[qf][dt][0] * inv); st.y = f2bf(o[qf][dt][1] * inv);
            st.z = f2bf(o[qf][dt][2] * inv); st.w = f2bf(o[qf][dt][3] * inv);
            *(ushort4*)(orow + dt * 16 + lg * 4) = st;
        }
    }
}

extern "C" void kernel_launch(void* const* d_in, const int* in_sizes, int n_in,
                              void* d_out, int out_size, void* d_ws, size_t ws_size,
                              hipStream_t stream) {
    const float* h    = (const float*)d_in[0];
    const float* cosT = (const float*)d_in[2];
    const float* sinT = (const float*)d_in[3];
    const float* Wf   = (const float*)d_in[4];
    const float* W1   = (const float*)d_in[5];
    const float* b1   = (const float*)d_in[6];
    const float* W2   = (const float*)d_in[7];
    const float* b2   = (const float*)d_in[8];
    const float* gs   = (const float*)d_in[9];
    const float* Wq   = (const float*)d_in[10];
    const float* Wk   = (const float*)d_in[11];
    const float* Wv   = (const float*)d_in[12];
    const float* Wo   = (const float*)d_in[13];
    float* out = (float*)d_out;

    char* ws = (char*)d_ws;
    unsigned short* hb     = (unsigned short*)(ws);                // 0..8M      [dead after gemm1]
    unsigned short* bt     = (unsigned short*)(ws + 8388608);      // 8M..21.5M  [dead after gemm1]
    unsigned short* qbuf   = (unsigned short*)(ws + 21495808);     // 8M
    unsigned short* kbuf   = (unsigned short*)(ws + 29884416);     // 2M
    unsigned short* vrow   = (unsigned short*)(ws + 31981568);     // 2M
    float*          adcols = (float*)(ws + 34078720);              // 1M
    float*          field  = (float*)(ws + 35127296);              // 8K
    float*          gate   = (float*)(ws + 35135488);              // 8K
    unsigned short* wot    = (unsigned short*)(ws + 35143680);     // 8M (own slot)
    unsigned short* vt      = (unsigned short*)(ws + 16777216);    // 2M over bt tail
    unsigned short* attnout = (unsigned short*)(ws);               // 8M over hb

    k_prep<<<dim3(6912), dim3(256), 0, stream>>>(h, hb, Wq, Wk, Wv, Wo, Wf, W1, bt, wot);
    k_gemm_qkv<<<dim3(25, 32), dim3(256), 0, stream>>>(hb, bt, cosT, sinT, qbuf, kbuf, vrow, adcols);
    k_fuse_vtrans<<<dim3(768), dim3(256), 0, stream>>>(adcols, W1, b1, W2, b2, field, vrow, vt);
    k_gate<<<dim3(1), dim3(256), 0, stream>>>(field, gate);
    k_attn<<<dim3(32, 32), dim3(128), 0, stream>>>(qbuf, kbuf, vt, gate, gs, attnout);
    k_gemm<<<dim3(16, 32), dim3(256), 0, stream>>>(attnout, wot, out, 2048, 2048, 2048);
}